// Round 1
// baseline (4053.271 us; speedup 1.0000x reference)
//
#include <hip/hip_runtime.h>
#include <cstddef>

// ---------------- problem constants ----------------
#define Bq    4
#define Hh    12
#define Dd    64
#define NNtok 1280      // N = N_M + N_S
#define NMtok 256
#define DIMc  768
#define MAXK  2560      // MEM + N

// workspace offsets (in floats)
static const size_t OQ   = 0;                    // q_buf  (B,H,N,64)
static const size_t OKb  = OQ   + 3932160;       // k_buf  (B,H,N,64)  raw k
static const size_t OVb  = OKb  + 3932160;       // v_buf  (B,H,N,64)  -> rows 0..255 become v_m_id
static const size_t OXO  = OVb  + 3932160;       // xo     (B,N,768)
static const size_t OQL  = OXO  + 3932160;       // qkv_low (5120,24)
static const size_t OIDK = OQL  + 122880;        // 1+tanh(ID_K) (B*256,12)
static const size_t OIDV = OIDK + 12288;         // ID_V   (B*256,768)
static const size_t OLK  = OIDV + 786432;        // id_lowk (1024,8)
static const size_t OLV  = OLK  + 8192;          // id_lowv (1024,8)
static const size_t ORD  = OLV  + 8192;          // route dots (5120,4)
static const size_t OPL  = ORD  + 20480;         // proj low (5120,32)
static const size_t OCF  = OPL  + 163840;        // coef (5120,32)

// d_out offsets (floats)
static const size_t KMID_OFF = 3932160;
static const size_t VMID_OFF = 4718592;

__device__ __forceinline__ unsigned int f2k(float x) {
  unsigned int u = __float_as_uint(x);
  return (u & 0x80000000u) ? ~u : (u | 0x80000000u);  // monotone float->uint
}

// ---------------- small row-dot kernel: dst[row][o] = src[row] . mat[o] ----------------
__global__ __launch_bounds__(256) void dot_small(
    const float* __restrict__ src, const float* __restrict__ mat,
    float* __restrict__ dst, int nout)
{
  int wv = threadIdx.x >> 6, ln = threadIdx.x & 63;
  size_t row = (size_t)blockIdx.x * 4 + wv;
  const float* s = src + row * DIMc;
  for (int o = 0; o < nout; ++o) {
    float p = 0.f;
    const float* m = mat + (size_t)o * DIMc;
    for (int c = ln; c < DIMc; c += 64) p += s[c] * m[c];
    for (int off = 32; off; off >>= 1) p += __shfl_xor(p, off, 64);
    if (ln == 0) dst[row * nout + o] = p;
  }
}

// ---------------- ID_K: stores 1+tanh(lora1(id_total, W_idk,...)) as (B*256, 12) ----------------
__global__ __launch_bounds__(256) void idk_kernel(
    const float* __restrict__ id_tot, const float* __restrict__ W_idk,
    const float* __restrict__ b_idk, const float* __restrict__ lowk,
    const float* __restrict__ idk_B, float* __restrict__ IDK)
{
  int wv = threadIdx.x >> 6, ln = threadIdx.x & 63;
  size_t row = (size_t)blockIdx.x * 4 + wv;
  const float* s = id_tot + row * DIMc;
  for (int h = 0; h < Hh; ++h) {
    float p = 0.f;
    const float* m = W_idk + (size_t)h * DIMc;
    for (int c = ln; c < DIMc; c += 64) p += s[c] * m[c];
    for (int off = 32; off; off >>= 1) p += __shfl_xor(p, off, 64);
    if (ln == 0) {
      float lo = 0.f;
      for (int r = 0; r < 8; ++r) lo += lowk[row * 8 + r] * idk_B[h * 8 + r];
      float val = p + b_idk[h] + lo * 0.125f;
      IDK[row * Hh + h] = 1.f + tanhf(val);
    }
  }
}

// ---------------- fixup: k_m_id / v_m_id (also updates v_buf rows 0..255 in place) ----------------
__global__ __launch_bounds__(256) void fixup_kernel(
    const float* __restrict__ kb, float* __restrict__ vb,
    const float* __restrict__ IDK, const float* __restrict__ IDV,
    float* __restrict__ kmid, float* __restrict__ vmid)
{
  int e = blockIdx.x * 256 + threadIdx.x;   // flat (b,h,t,d)
  int d  = e & 63;
  int r1 = e >> 6;
  int tt = r1 & 255;
  int r2 = r1 >> 8;
  int h  = r2 % Hh;
  int b  = r2 / Hh;
  size_t src = ((size_t)(b * Hh + h) * NNtok + tt) * Dd + d;
  float km = kb[src] * IDK[(size_t)(b * 256 + tt) * Hh + h];
  kmid[e] = km;
  float vv = vb[src] + IDV[(size_t)(b * 256 + tt) * DIMc + h * 64 + d];
  vb[src] = vv;
  vmid[e] = vv;
}

// ---------------- route softmax * proj-low * (1/R) -> coef (5120,32) ----------------
__global__ __launch_bounds__(256) void coef_kernel(
    const float* __restrict__ rd, const float* __restrict__ plow,
    float* __restrict__ coef)
{
  int n = blockIdx.x * 256 + threadIdx.x;
  if (n >= Bq * NNtok) return;
  float l0 = rd[n * 4 + 0], l1 = rd[n * 4 + 1], l2 = rd[n * 4 + 2], l3 = rd[n * 4 + 3];
  float m = fmaxf(fmaxf(l0, l1), fmaxf(l2, l3));
  float e0 = expf(l0 - m), e1 = expf(l1 - m), e2 = expf(l2 - m), e3 = expf(l3 - m);
  float inv = 1.f / (e0 + e1 + e2 + e3);
  float rt[4] = { e0 * inv, e1 * inv, e2 * inv, e3 * inv };
  for (int e = 0; e < 4; ++e)
    for (int r = 0; r < 8; ++r)
      coef[(size_t)n * 32 + e * 8 + r] = rt[e] * plow[(size_t)n * 32 + e * 8 + r] * 0.125f;
}

// ---------------- tiled fp32 GEMM  C = A @ W^T (+bias +lora), mode-switched epilogue ----------------
// mode 0: qkv (N=2304): +b_qkv +qkv lora, scatter to q/k/v (B,H,N,64), q *= 0.125
// mode 1: ID_V: +b_idv + idv lora, dst row-major (M,N)
// mode 2: proj: +b_proj + sum_{e,r} coef*proj_B, dst row-major
__global__ __launch_bounds__(256) void gemm_ep(
    const float* __restrict__ A, const float* __restrict__ W,
    const float* __restrict__ bias, const float* __restrict__ low,
    const float* __restrict__ Bl, float* __restrict__ dst,
    int M, int N, int K, int mode,
    float* __restrict__ qb, float* __restrict__ kb, float* __restrict__ vb)
{
  __shared__ alignas(16) float As[16][68];
  __shared__ alignas(16) float Bs[16][68];
  const int t  = threadIdx.x;
  const int tx = t & 15, ty = t >> 4;
  const int bn = blockIdx.x * 64, bm = blockIdx.y * 64;
  const int am = t >> 2, ak = (t & 3) << 2;

  float acc[4][4] = {};
  for (int k0 = 0; k0 < K; k0 += 16) {
    float4 av = *(const float4*)(A + (size_t)(bm + am) * K + k0 + ak);
    float4 bv = *(const float4*)(W + (size_t)(bn + am) * K + k0 + ak);
    As[ak + 0][am] = av.x; As[ak + 1][am] = av.y; As[ak + 2][am] = av.z; As[ak + 3][am] = av.w;
    Bs[ak + 0][am] = bv.x; Bs[ak + 1][am] = bv.y; Bs[ak + 2][am] = bv.z; Bs[ak + 3][am] = bv.w;
    __syncthreads();
#pragma unroll
    for (int kk = 0; kk < 16; ++kk) {
      float4 a4 = *(const float4*)&As[kk][ty << 2];
      float4 b4 = *(const float4*)&Bs[kk][tx << 2];
      float ar[4] = { a4.x, a4.y, a4.z, a4.w };
      float br[4] = { b4.x, b4.y, b4.z, b4.w };
#pragma unroll
      for (int i = 0; i < 4; ++i)
#pragma unroll
        for (int j = 0; j < 4; ++j) acc[i][j] += ar[i] * br[j];
    }
    __syncthreads();
  }

#pragma unroll
  for (int i = 0; i < 4; ++i) {
    int mg = bm + (ty << 2) + i;
#pragma unroll
    for (int j = 0; j < 4; ++j) {
      int col = bn + (tx << 2) + j;
      float v = acc[i][j];
      if (mode == 0) {
        int g = col / DIMc, jj = col % DIMc;
        v += bias[col];
        const float* lw = low + (size_t)mg * 24 + g * 8;
        const float* bb = Bl + (size_t)g * DIMc * 8 + (size_t)jj * 8;
        float lo = 0.f;
#pragma unroll
        for (int r = 0; r < 8; ++r) lo += lw[r] * bb[r];
        v += lo * 0.125f;
        int b = mg / NNtok, tt = mg % NNtok;
        int h = jj >> 6, d = jj & 63;
        size_t idx = ((size_t)(b * Hh + h) * NNtok + tt) * Dd + d;
        if (g == 0)      qb[idx] = v * 0.125f;   // q * D^-0.5
        else if (g == 1) kb[idx] = v;
        else             vb[idx] = v;
      } else if (mode == 1) {
        v += bias[col];
        float lo = 0.f;
#pragma unroll
        for (int r = 0; r < 8; ++r) lo += low[(size_t)mg * 8 + r] * Bl[(size_t)col * 8 + r];
        v += lo * 0.125f;
        dst[(size_t)mg * N + col] = v;
      } else {
        v += bias[col];
        float lo = 0.f;
#pragma unroll
        for (int e = 0; e < 4; ++e)
#pragma unroll
          for (int r = 0; r < 8; ++r)
            lo += low[(size_t)mg * 32 + e * 8 + r] * Bl[(size_t)e * DIMc * 8 + (size_t)col * 8 + r];
        v += lo;   // coef already carries route * 1/R
        dst[(size_t)mg * N + col] = v;
      }
    }
  }
}

// ---------------- top-k attention: 1 block = 4 query rows of one (b,h) ----------------
// keys/values: segment0 (len L0) then segment1 (len L1); nkeys = L0+L1
__global__ __launch_bounds__(256) void attn_topk(
    const float* __restrict__ qbuf,
    const float* __restrict__ k0, const float* __restrict__ v0, int L0,
    const float* __restrict__ k1, const float* __restrict__ v1, int L1,
    int nkeys, int topk, int qrow0, int rows_per_bh,
    float* __restrict__ xo, int nofs)
{
  __shared__ float sc[4 * MAXK];          // scores -> weights, [r][key]
  __shared__ float tile[64 * 65];         // k/v staging, stride 65 (2-way banks = free)
  __shared__ float qsm[256];
  __shared__ unsigned int h4[4][256];     // per-wave histograms
  __shared__ unsigned int hist[256];      // merged + in-place suffix scan
  __shared__ float red[256];
  __shared__ float rowinv[4];
  __shared__ int sel_bin, sel_kk, s_ceq;

  const int t = threadIdx.x;
  const int w = t >> 6, l = t & 63;
  const int bpb = rows_per_bh >> 2;
  const int bh = blockIdx.x / bpb;
  const int rb = blockIdx.x % bpb;
  const int b = bh / Hh, h = bh % Hh;
  const int qbase = qrow0 + rb * 4;

  qsm[t] = qbuf[((size_t)bh * NNtok + qbase + (t >> 6)) * Dd + (t & 63)];
  __syncthreads();

  const int mykey = (w << 4) + (l & 15);
  const int dch = (l >> 4) << 4;
  float qreg[4][16];
#pragma unroll
  for (int r = 0; r < 4; ++r)
#pragma unroll
    for (int i = 0; i < 16; ++i) qreg[r][i] = qsm[r * 64 + dch + i];

  // ---- scores: S[r][j] = q_r . k_j ----
  for (int t0 = 0; t0 < nkeys; t0 += 64) {
#pragma unroll
    for (int ii = 0; ii < 4; ++ii) {
      int fi = t + ii * 256;
      int key = fi >> 4, dq = (fi & 15) << 2;
      int jg = t0 + key;
      const float* s = (jg < L0) ? (k0 + ((size_t)bh * L0 + jg) * Dd + dq)
                                 : (k1 + ((size_t)bh * L1 + (jg - L0)) * Dd + dq);
      float4 vv = *(const float4*)s;
      float* dp = &tile[key * 65 + dq];
      dp[0] = vv.x; dp[1] = vv.y; dp[2] = vv.z; dp[3] = vv.w;
    }
    __syncthreads();
    float p0 = 0, p1 = 0, p2 = 0, p3 = 0;
#pragma unroll
    for (int i = 0; i < 16; ++i) {
      float kv = tile[mykey * 65 + dch + i];
      p0 += kv * qreg[0][i]; p1 += kv * qreg[1][i];
      p2 += kv * qreg[2][i]; p3 += kv * qreg[3][i];
    }
    p0 += __shfl_xor(p0, 16, 64); p0 += __shfl_xor(p0, 32, 64);
    p1 += __shfl_xor(p1, 16, 64); p1 += __shfl_xor(p1, 32, 64);
    p2 += __shfl_xor(p2, 16, 64); p2 += __shfl_xor(p2, 32, 64);
    p3 += __shfl_xor(p3, 16, 64); p3 += __shfl_xor(p3, 32, 64);
    if (l < 16) {
      sc[0 * MAXK + t0 + mykey] = p0;
      sc[1 * MAXK + t0 + mykey] = p1;
      sc[2 * MAXK + t0 + mykey] = p2;
      sc[3 * MAXK + t0 + mykey] = p3;
    }
    __syncthreads();
  }

  // ---- per-row: exact top-k threshold (radix select) + softmax weights in place ----
  for (int r = 0; r < 4; ++r) {
    float* s = &sc[r * MAXK];
    unsigned int prefix = 0;
    int kk = topk;
    for (int p = 3; p >= 0; --p) {
#pragma unroll
      for (int z = 0; z < 4; ++z) ((unsigned int*)h4)[z * 256 + t] = 0u;
      __syncthreads();
      int sh = p * 8;
      unsigned int hi_mask = (p == 3) ? 0u : (0xFFFFFFFFu << (8 * (p + 1)));
      for (int i = t; i < nkeys; i += 256) {
        unsigned int u = f2k(s[i]);
        if ((u & hi_mask) == prefix) atomicAdd(&h4[w][(u >> sh) & 255], 1u);
      }
      __syncthreads();
      hist[t] = h4[0][t] + h4[1][t] + h4[2][t] + h4[3][t];
      __syncthreads();
      for (int off = 1; off < 256; off <<= 1) {   // in-place suffix scan
        unsigned int vv = (t + off < 256) ? hist[t + off] : 0u;
        __syncthreads();
        hist[t] += vv;
        __syncthreads();
      }
      unsigned int nx = (t == 255) ? 0u : hist[t + 1];
      if (hist[t] >= (unsigned int)kk && nx < (unsigned int)kk) {
        sel_bin = t;
        sel_kk = kk - (int)nx;
        s_ceq = (int)(hist[t] - nx);
      }
      __syncthreads();
      prefix |= ((unsigned int)sel_bin) << sh;
      kk = sel_kk;
      __syncthreads();
    }
    const unsigned int Tkey = prefix;   // key of k-th largest value
    const int need = kk;                // #equal-to-threshold elements to keep
    if (t == 0 && need < s_ceq) {       // rare: ties — keep lowest indices (jax top_k order)
      int seen = 0;
      for (int i = 0; i < nkeys; ++i)
        if (f2k(s[i]) == Tkey) { if (++seen > need) s[i] = -__builtin_inff(); }
    }
    __syncthreads();
    float mx = -__builtin_inff();
    for (int i = t; i < nkeys; i += 256) mx = fmaxf(mx, s[i]);
    red[t] = mx;
    __syncthreads();
    for (int off = 128; off; off >>= 1) { if (t < off) red[t] = fmaxf(red[t], red[t + off]); __syncthreads(); }
    float m = red[0];
    __syncthreads();
    float ls = 0.f;
    for (int i = t; i < nkeys; i += 256) {
      float x = s[i];
      float wv = (f2k(x) >= Tkey) ? __expf(x - m) : 0.f;
      s[i] = wv;
      ls += wv;
    }
    __syncthreads();
    red[t] = ls;
    __syncthreads();
    for (int off = 128; off; off >>= 1) { if (t < off) red[t] += red[t + off]; __syncthreads(); }
    if (t == 0) rowinv[r] = 1.f / red[0];
    __syncthreads();
  }

  // ---- PV: out[r][d] = sum_j w[r][j] * v[j][d] ----
  float a0 = 0, a1 = 0, a2 = 0, a3 = 0;
  for (int t0 = 0; t0 < nkeys; t0 += 64) {
#pragma unroll
    for (int ii = 0; ii < 4; ++ii) {
      int fi = t + ii * 256;
      int key = fi >> 4, dq = (fi & 15) << 2;
      int jg = t0 + key;
      const float* s = (jg < L0) ? (v0 + ((size_t)bh * L0 + jg) * Dd + dq)
                                 : (v1 + ((size_t)bh * L1 + (jg - L0)) * Dd + dq);
      float4 vv = *(const float4*)s;
      float* dp = &tile[key * 65 + dq];
      dp[0] = vv.x; dp[1] = vv.y; dp[2] = vv.z; dp[3] = vv.w;
    }
    __syncthreads();
#pragma unroll
    for (int i = 0; i < 16; ++i) {
      int j = (w << 4) + i;
      float vv = tile[j * 65 + l];
      int jg = t0 + j;
      a0 += vv * sc[0 * MAXK + jg];
      a1 += vv * sc[1 * MAXK + jg];
      a2 += vv * sc[2 * MAXK + jg];
      a3 += vv * sc[3 * MAXK + jg];
    }
    __syncthreads();
  }
  float accs[4] = { a0, a1, a2, a3 };
  for (int r = 0; r < 4; ++r) {
    red[(w << 6) + l] = accs[r];
    __syncthreads();
    if (t < 64) {
      float sres = red[t] + red[64 + t] + red[128 + t] + red[192 + t];
      int n = nofs + rb * 4 + r;
      xo[((size_t)b * NNtok + n) * DIMc + h * 64 + t] = sres * rowinv[r];
    }
    __syncthreads();
  }
}

// ---------------- host ----------------
extern "C" void kernel_launch(void* const* d_in, const int* in_sizes, int n_in,
                              void* d_out, int out_size, void* d_ws, size_t ws_size,
                              hipStream_t stream)
{
  const float* x       = (const float*)d_in[0];
  const float* id_tot  = (const float*)d_in[1];
  const float* mem_k   = (const float*)d_in[2];
  const float* mem_v   = (const float*)d_in[3];
  const float* W_qkv   = (const float*)d_in[4];
  const float* b_qkv   = (const float*)d_in[5];
  const float* qkv_A   = (const float*)d_in[6];
  const float* qkv_B   = (const float*)d_in[7];
  const float* W_proj  = (const float*)d_in[8];
  const float* b_proj  = (const float*)d_in[9];
  const float* route_W = (const float*)d_in[10];
  const float* proj_A  = (const float*)d_in[11];
  const float* proj_B  = (const float*)d_in[12];
  const float* W_idk   = (const float*)d_in[13];
  const float* b_idk   = (const float*)d_in[14];
  const float* idk_A   = (const float*)d_in[15];
  const float* idk_B   = (const float*)d_in[16];
  const float* W_idv   = (const float*)d_in[17];
  const float* b_idv   = (const float*)d_in[18];
  const float* idv_A   = (const float*)d_in[19];
  const float* idv_B   = (const float*)d_in[20];

  float* ws   = (float*)d_ws;
  float* qb   = ws + OQ;
  float* kb   = ws + OKb;
  float* vb   = ws + OVb;
  float* xo   = ws + OXO;
  float* qlow = ws + OQL;
  float* IDK  = ws + OIDK;
  float* IDV  = ws + OIDV;
  float* lowk = ws + OLK;
  float* lowv = ws + OLV;
  float* rd   = ws + ORD;
  float* plow = ws + OPL;
  float* coef = ws + OCF;

  float* out  = (float*)d_out;
  float* kmid = out + KMID_OFF;
  float* vmid = out + VMID_OFF;

  // LoRA "down" projections
  dot_small<<<1280, 256, 0, stream>>>(x, qkv_A, qlow, 24);          // (5120,24)
  dot_small<<<256,  256, 0, stream>>>(id_tot, idk_A, lowk, 8);      // (1024,8)
  dot_small<<<256,  256, 0, stream>>>(id_tot, idv_A, lowv, 8);      // (1024,8)

  // QKV projection (+bias +lora), scatter to q/k/v; q pre-scaled by D^-0.5
  gemm_ep<<<dim3(36, 80), 256, 0, stream>>>(x, W_qkv, b_qkv, qlow, qkv_B, nullptr,
                                            5120, 2304, 768, 0, qb, kb, vb);
  // ID_V = lora1(id_total, W_idv, ...)
  gemm_ep<<<dim3(12, 16), 256, 0, stream>>>(id_tot, W_idv, b_idv, lowv, idv_B, IDV,
                                            1024, 768, 768, 1, nullptr, nullptr, nullptr);
  // 1 + tanh(ID_K)
  idk_kernel<<<256, 256, 0, stream>>>(id_tot, W_idk, b_idk, lowk, idk_B, IDK);
  // k_m_id / v_m_id outputs; v_buf rows 0..255 updated in place
  fixup_kernel<<<3072, 256, 0, stream>>>(kb, vb, IDK, IDV, kmid, vmid);

  // attention over memory tokens: 256 keys, top-128
  attn_topk<<<3072, 256, 0, stream>>>(qb, kmid, vmid, 256,
                                      nullptr, nullptr, 0,
                                      256, 128, 0, 256, xo, 0);
  // attention over sequence tokens: mem(1280) + raw k(1280) keys, top-640
  attn_topk<<<12288, 256, 0, stream>>>(qb, mem_k, mem_v, 1280,
                                       kb, vb, 1280,
                                       2560, 640, 256, 1024, xo, 256);

  // routed output projection
  dot_small<<<1280, 256, 0, stream>>>(xo, route_W, rd, 4);
  dot_small<<<1280, 256, 0, stream>>>(xo, proj_A, plow, 32);
  coef_kernel<<<20, 256, 0, stream>>>(rd, plow, coef);
  gemm_ep<<<dim3(12, 80), 256, 0, stream>>>(xo, W_proj, b_proj, coef, proj_B, out,
                                            5120, 768, 768, 2, nullptr, nullptr, nullptr);
}

// Round 2
// 3808.804 us; speedup vs baseline: 1.0642x; 1.0642x over previous
//
#include <hip/hip_runtime.h>
#include <cstddef>

// ---------------- problem constants ----------------
#define Bq    4
#define Hh    12
#define Dd    64
#define NNtok 1280      // N = N_M + N_S
#define NMtok 256
#define DIMc  768

// workspace offsets (in floats)
static const size_t OQ   = 0;                    // q_buf  (B,H,N,64)
static const size_t OKb  = OQ   + 3932160;       // k_buf  (B,H,N,64)  raw k
static const size_t OVb  = OKb  + 3932160;       // v_buf  (B,H,N,64)  -> rows 0..255 become v_m_id
static const size_t OXO  = OVb  + 3932160;       // xo     (B,N,768)
static const size_t OQL  = OXO  + 3932160;       // qkv_low (5120,24)
static const size_t OIDK = OQL  + 122880;        // 1+tanh(ID_K) (B*256,12)
static const size_t OIDV = OIDK + 12288;         // ID_V   (B*256,768)
static const size_t OLK  = OIDV + 786432;        // id_lowk (1024,8)
static const size_t OLV  = OLK  + 8192;          // id_lowv (1024,8)
static const size_t ORD  = OLV  + 8192;          // route dots (5120,4)
static const size_t OPL  = ORD  + 20480;         // proj low (5120,32)
static const size_t OCF  = OPL  + 163840;        // coef (5120,32)

// d_out offsets (floats)
static const size_t KMID_OFF = 3932160;
static const size_t VMID_OFF = 4718592;

__device__ __forceinline__ unsigned int f2k(float x) {
  unsigned int u = __float_as_uint(x);
  return (u & 0x80000000u) ? ~u : (u | 0x80000000u);  // monotone float->uint
}

// ---------------- small row-dot kernel ----------------
__global__ __launch_bounds__(256) void dot_small(
    const float* __restrict__ src, const float* __restrict__ mat,
    float* __restrict__ dst, int nout)
{
  int wv = threadIdx.x >> 6, ln = threadIdx.x & 63;
  size_t row = (size_t)blockIdx.x * 4 + wv;
  const float* s = src + row * DIMc;
  for (int o = 0; o < nout; ++o) {
    float p = 0.f;
    const float* m = mat + (size_t)o * DIMc;
    for (int c = ln; c < DIMc; c += 64) p += s[c] * m[c];
    for (int off = 32; off; off >>= 1) p += __shfl_xor(p, off, 64);
    if (ln == 0) dst[row * nout + o] = p;
  }
}

// ---------------- ID_K: 1+tanh(lora1(id_total, W_idk,...)) as (B*256, 12) ----------------
__global__ __launch_bounds__(256) void idk_kernel(
    const float* __restrict__ id_tot, const float* __restrict__ W_idk,
    const float* __restrict__ b_idk, const float* __restrict__ lowk,
    const float* __restrict__ idk_B, float* __restrict__ IDK)
{
  int wv = threadIdx.x >> 6, ln = threadIdx.x & 63;
  size_t row = (size_t)blockIdx.x * 4 + wv;
  const float* s = id_tot + row * DIMc;
  for (int h = 0; h < Hh; ++h) {
    float p = 0.f;
    const float* m = W_idk + (size_t)h * DIMc;
    for (int c = ln; c < DIMc; c += 64) p += s[c] * m[c];
    for (int off = 32; off; off >>= 1) p += __shfl_xor(p, off, 64);
    if (ln == 0) {
      float lo = 0.f;
      for (int r = 0; r < 8; ++r) lo += lowk[row * 8 + r] * idk_B[h * 8 + r];
      float val = p + b_idk[h] + lo * 0.125f;
      IDK[row * Hh + h] = 1.f + tanhf(val);
    }
  }
}

// ---------------- fixup: k_m_id / v_m_id (also updates v_buf rows 0..255) ----------------
__global__ __launch_bounds__(256) void fixup_kernel(
    const float* __restrict__ kb, float* __restrict__ vb,
    const float* __restrict__ IDK, const float* __restrict__ IDV,
    float* __restrict__ kmid, float* __restrict__ vmid)
{
  int e = blockIdx.x * 256 + threadIdx.x;   // flat (b,h,t,d)
  int d  = e & 63;
  int r1 = e >> 6;
  int tt = r1 & 255;
  int r2 = r1 >> 8;
  int h  = r2 % Hh;
  int b  = r2 / Hh;
  size_t src = ((size_t)(b * Hh + h) * NNtok + tt) * Dd + d;
  float km = kb[src] * IDK[(size_t)(b * 256 + tt) * Hh + h];
  kmid[e] = km;
  float vv = vb[src] + IDV[(size_t)(b * 256 + tt) * DIMc + h * 64 + d];
  vb[src] = vv;
  vmid[e] = vv;
}

// ---------------- route softmax * proj-low * (1/R) -> coef ----------------
__global__ __launch_bounds__(256) void coef_kernel(
    const float* __restrict__ rd, const float* __restrict__ plow,
    float* __restrict__ coef)
{
  int n = blockIdx.x * 256 + threadIdx.x;
  if (n >= Bq * NNtok) return;
  float l0 = rd[n * 4 + 0], l1 = rd[n * 4 + 1], l2 = rd[n * 4 + 2], l3 = rd[n * 4 + 3];
  float m = fmaxf(fmaxf(l0, l1), fmaxf(l2, l3));
  float e0 = expf(l0 - m), e1 = expf(l1 - m), e2 = expf(l2 - m), e3 = expf(l3 - m);
  float inv = 1.f / (e0 + e1 + e2 + e3);
  float rt[4] = { e0 * inv, e1 * inv, e2 * inv, e3 * inv };
  for (int e = 0; e < 4; ++e)
    for (int r = 0; r < 8; ++r)
      coef[(size_t)n * 32 + e * 8 + r] = rt[e] * plow[(size_t)n * 32 + e * 8 + r] * 0.125f;
}

// ---------------- tiled fp32 GEMM with fused epilogues (unchanged) ----------------
__global__ __launch_bounds__(256) void gemm_ep(
    const float* __restrict__ A, const float* __restrict__ W,
    const float* __restrict__ bias, const float* __restrict__ low,
    const float* __restrict__ Bl, float* __restrict__ dst,
    int M, int N, int K, int mode,
    float* __restrict__ qb, float* __restrict__ kb, float* __restrict__ vb)
{
  __shared__ alignas(16) float As[16][68];
  __shared__ alignas(16) float Bs[16][68];
  const int t  = threadIdx.x;
  const int tx = t & 15, ty = t >> 4;
  const int bn = blockIdx.x * 64, bm = blockIdx.y * 64;
  const int am = t >> 2, ak = (t & 3) << 2;

  float acc[4][4] = {};
  for (int k0 = 0; k0 < K; k0 += 16) {
    float4 av = *(const float4*)(A + (size_t)(bm + am) * K + k0 + ak);
    float4 bv = *(const float4*)(W + (size_t)(bn + am) * K + k0 + ak);
    As[ak + 0][am] = av.x; As[ak + 1][am] = av.y; As[ak + 2][am] = av.z; As[ak + 3][am] = av.w;
    Bs[ak + 0][am] = bv.x; Bs[ak + 1][am] = bv.y; Bs[ak + 2][am] = bv.z; Bs[ak + 3][am] = bv.w;
    __syncthreads();
#pragma unroll
    for (int kk = 0; kk < 16; ++kk) {
      float4 a4 = *(const float4*)&As[kk][ty << 2];
      float4 b4 = *(const float4*)&Bs[kk][tx << 2];
      float ar[4] = { a4.x, a4.y, a4.z, a4.w };
      float br[4] = { b4.x, b4.y, b4.z, b4.w };
#pragma unroll
      for (int i = 0; i < 4; ++i)
#pragma unroll
        for (int j = 0; j < 4; ++j) acc[i][j] += ar[i] * br[j];
    }
    __syncthreads();
  }

#pragma unroll
  for (int i = 0; i < 4; ++i) {
    int mg = bm + (ty << 2) + i;
#pragma unroll
    for (int j = 0; j < 4; ++j) {
      int col = bn + (tx << 2) + j;
      float v = acc[i][j];
      if (mode == 0) {
        int g = col / DIMc, jj = col % DIMc;
        v += bias[col];
        const float* lw = low + (size_t)mg * 24 + g * 8;
        const float* bb = Bl + (size_t)g * DIMc * 8 + (size_t)jj * 8;
        float lo = 0.f;
#pragma unroll
        for (int r = 0; r < 8; ++r) lo += lw[r] * bb[r];
        v += lo * 0.125f;
        int b = mg / NNtok, tt = mg % NNtok;
        int h = jj >> 6, d = jj & 63;
        size_t idx = ((size_t)(b * Hh + h) * NNtok + tt) * Dd + d;
        if (g == 0)      qb[idx] = v * 0.125f;   // q * D^-0.5
        else if (g == 1) kb[idx] = v;
        else             vb[idx] = v;
      } else if (mode == 1) {
        v += bias[col];
        float lo = 0.f;
#pragma unroll
        for (int r = 0; r < 8; ++r) lo += low[(size_t)mg * 8 + r] * Bl[(size_t)col * 8 + r];
        v += lo * 0.125f;
        dst[(size_t)mg * N + col] = v;
      } else {
        v += bias[col];
        float lo = 0.f;
#pragma unroll
        for (int e = 0; e < 4; ++e)
#pragma unroll
          for (int r = 0; r < 8; ++r)
            lo += low[(size_t)mg * 32 + e * 8 + r] * Bl[(size_t)e * DIMc * 8 + (size_t)col * 8 + r];
        v += lo;   // coef already carries route * 1/R
        dst[(size_t)mg * N + col] = v;
      }
    }
  }
}

// ---------------- top-k attention v2: 1 block = 4 rows, 1 wave = 1 row ----------------
// Phase A: cooperative scores (K read once per 4 rows, direct from global, no LDS tile)
// ONE __syncthreads. Then per-wave (barrier-free): radix select, softmax+compact, PV.
template<int NK, int TK>
__global__ __launch_bounds__(256) void attn_topk2(
    const float* __restrict__ qbuf,
    const float* __restrict__ k0, const float* __restrict__ v0, int L0,
    const float* __restrict__ k1, const float* __restrict__ v1, int L1,
    int qrow0, int rows_per_bh,
    float* __restrict__ xo, int nofs)
{
  __shared__ float sc[4][NK];                       // scores, row per wave
  __shared__ __align__(16) char pwreg[4][TK * 8];   // per-wave: hist (1KB) then list (TK*8)

  const int t = threadIdx.x;
  const int w = t >> 6, l = t & 63;
  const int bpb = rows_per_bh >> 2;
  const int bh = blockIdx.x / bpb;
  const int rb = blockIdx.x % bpb;
  const int b = bh / Hh, h = bh % Hh;
  const int qbase = qrow0 + rb * 4;

  // ---- Phase A: scores (cooperative over 4 rows) ----
  const int mykey = (w << 4) | (l & 15);
  const int dch = (l >> 4) << 4;
  float qreg[4][16];
#pragma unroll
  for (int r = 0; r < 4; ++r) {
    const float* qp = qbuf + ((size_t)bh * NNtok + qbase + r) * Dd + dch;
#pragma unroll
    for (int i = 0; i < 4; ++i) {
      float4 qv = *(const float4*)(qp + i * 4);
      qreg[r][i * 4 + 0] = qv.x; qreg[r][i * 4 + 1] = qv.y;
      qreg[r][i * 4 + 2] = qv.z; qreg[r][i * 4 + 3] = qv.w;
    }
  }

  for (int t0 = 0; t0 < NK; t0 += 64) {
    int jg = t0 + mykey;
    const float* kp = (jg < L0) ? (k0 + ((size_t)bh * L0 + jg) * Dd + dch)
                                : (k1 + ((size_t)bh * L1 + (jg - L0)) * Dd + dch);
    float kr[16];
#pragma unroll
    for (int i = 0; i < 4; ++i) {
      float4 kv = *(const float4*)(kp + i * 4);
      kr[i * 4 + 0] = kv.x; kr[i * 4 + 1] = kv.y; kr[i * 4 + 2] = kv.z; kr[i * 4 + 3] = kv.w;
    }
    float p0 = 0, p1 = 0, p2 = 0, p3 = 0;
#pragma unroll
    for (int i = 0; i < 16; ++i) {
      p0 += kr[i] * qreg[0][i]; p1 += kr[i] * qreg[1][i];
      p2 += kr[i] * qreg[2][i]; p3 += kr[i] * qreg[3][i];
    }
    p0 += __shfl_xor(p0, 16, 64); p0 += __shfl_xor(p0, 32, 64);
    p1 += __shfl_xor(p1, 16, 64); p1 += __shfl_xor(p1, 32, 64);
    p2 += __shfl_xor(p2, 16, 64); p2 += __shfl_xor(p2, 32, 64);
    p3 += __shfl_xor(p3, 16, 64); p3 += __shfl_xor(p3, 32, 64);
    if (l < 16) {
      sc[0][t0 + mykey] = p0; sc[1][t0 + mykey] = p1;
      sc[2][t0 + mykey] = p2; sc[3][t0 + mykey] = p3;
    }
  }
  __syncthreads();   // the ONLY block barrier

  // ---- Phase B: per-wave exact radix select on row w ----
  float* s = sc[w];
  unsigned int* hist = (unsigned int*)pwreg[w];
  unsigned int prefix = 0;
  int kk = TK, ceq = 0;
#pragma unroll
  for (int p = 3; p >= 0; --p) {
#pragma unroll
    for (int z = 0; z < 4; ++z) hist[l + z * 64] = 0u;
    int sh = p * 8;
    unsigned int hi_mask = (p == 3) ? 0u : (0xFFFFFFFFu << (8 * (p + 1)));
    for (int i = l; i < NK; i += 64) {
      unsigned int u = f2k(s[i]);
      if ((u & hi_mask) == prefix) atomicAdd(&hist[(u >> sh) & 255], 1u);
    }
    // per-lane: bins 4l..4l+3; within-lane suffix
    unsigned int h0 = hist[4 * l + 0], h1 = hist[4 * l + 1],
                 h2 = hist[4 * l + 2], h3 = hist[4 * l + 3];
    unsigned int s3 = h3, s2 = h2 + s3, s1 = h1 + s2, s0 = h0 + s1;
    // cross-lane inclusive suffix scan of s0 (Kogge-Stone)
    unsigned int tsum = s0;
#pragma unroll
    for (int off = 1; off < 64; off <<= 1) {
      unsigned int other = __shfl(tsum, l + off, 64);
      tsum += (l + off < 64) ? other : 0u;
    }
    unsigned int T = tsum - s0;   // exclusive: sum over lanes > l
    unsigned int Sv0 = T + s0, Sv1 = T + s1, Sv2 = T + s2, Sv3 = T + s3, Sv4 = T;
    int fb = -1, fkk = 0, fceq = 0;
    unsigned int ukk = (unsigned int)kk;
    if (Sv0 >= ukk && Sv1 < ukk) { fb = 4 * l + 0; fkk = (int)(ukk - Sv1); fceq = (int)(Sv0 - Sv1); }
    if (Sv1 >= ukk && Sv2 < ukk) { fb = 4 * l + 1; fkk = (int)(ukk - Sv2); fceq = (int)(Sv1 - Sv2); }
    if (Sv2 >= ukk && Sv3 < ukk) { fb = 4 * l + 2; fkk = (int)(ukk - Sv3); fceq = (int)(Sv2 - Sv3); }
    if (Sv3 >= ukk && Sv4 < ukk) { fb = 4 * l + 3; fkk = (int)(ukk - Sv4); fceq = (int)(Sv3 - Sv4); }
    unsigned long long mb = __ballot(fb >= 0);
    int src = __ffsll((unsigned long long)mb) - 1;
    int bin = __shfl(fb, src, 64);
    kk      = __shfl(fkk, src, 64);
    ceq     = __shfl(fceq, src, 64);
    prefix |= ((unsigned int)bin) << sh;
  }
  const unsigned int Tkey = prefix;   // key of k-th largest
  const int need = kk;
  if (need < ceq) {                   // rare ties: keep lowest indices
    int seen = 0;
    for (int i0 = 0; i0 < NK && seen < ceq; i0 += 64) {
      int i = i0 + l;
      bool eq = (f2k(s[i]) == Tkey);
      unsigned long long m = __ballot(eq);
      int before = __popcll(m & ((1ull << l) - 1ull));
      if (eq && (seen + before) >= need) s[i] = -__builtin_inff();
      seen += __popcll(m);
    }
  }

  // ---- Phase C: softmax over selected + compaction into (idx,weight) list ----
  float mx = -__builtin_inff();
  for (int i = l; i < NK; i += 64) mx = fmaxf(mx, s[i]);
#pragma unroll
  for (int off = 32; off; off >>= 1) mx = fmaxf(mx, __shfl_xor(mx, off, 64));

  float2* list = (float2*)pwreg[w];   // overwrites hist (dead) — same wave, ordered
  float sum = 0.f;
  int pos = 0;
  for (int i0 = 0; i0 < NK; i0 += 64) {
    int i = i0 + l;
    float x = s[i];
    bool keep = (f2k(x) >= Tkey);
    float wv = keep ? __expf(x - mx) : 0.f;
    unsigned long long m = __ballot(keep);
    if (keep) {
      int ppos = pos + __popcll(m & ((1ull << l) - 1ull));
      list[ppos] = make_float2(__int_as_float(i), wv);
    }
    pos += __popcll(m);
    sum += wv;
  }
#pragma unroll
  for (int off = 32; off; off >>= 1) sum += __shfl_xor(sum, off, 64);
  const float inv = 1.f / sum;

  // ---- Phase D: PV over the TK selected keys (per-wave, lane = dim) ----
  float acc = 0.f;
  for (int i = 0; i < TK; i += 4) {
    float2 e0 = list[i], e1 = list[i + 1], e2 = list[i + 2], e3 = list[i + 3];
    int j0 = __float_as_int(e0.x), j1 = __float_as_int(e1.x),
        j2 = __float_as_int(e2.x), j3 = __float_as_int(e3.x);
    const float* p0 = (j0 < L0) ? (v0 + ((size_t)bh * L0 + j0) * Dd)
                                : (v1 + ((size_t)bh * L1 + (j0 - L0)) * Dd);
    const float* p1 = (j1 < L0) ? (v0 + ((size_t)bh * L0 + j1) * Dd)
                                : (v1 + ((size_t)bh * L1 + (j1 - L0)) * Dd);
    const float* p2 = (j2 < L0) ? (v0 + ((size_t)bh * L0 + j2) * Dd)
                                : (v1 + ((size_t)bh * L1 + (j2 - L0)) * Dd);
    const float* p3 = (j3 < L0) ? (v0 + ((size_t)bh * L0 + j3) * Dd)
                                : (v1 + ((size_t)bh * L1 + (j3 - L0)) * Dd);
    acc += e0.y * p0[l];
    acc += e1.y * p1[l];
    acc += e2.y * p2[l];
    acc += e3.y * p3[l];
  }
  int n = nofs + rb * 4 + w;
  xo[((size_t)b * NNtok + n) * DIMc + h * 64 + l] = acc * inv;
}

// ---------------- host ----------------
extern "C" void kernel_launch(void* const* d_in, const int* in_sizes, int n_in,
                              void* d_out, int out_size, void* d_ws, size_t ws_size,
                              hipStream_t stream)
{
  const float* x       = (const float*)d_in[0];
  const float* id_tot  = (const float*)d_in[1];
  const float* mem_k   = (const float*)d_in[2];
  const float* mem_v   = (const float*)d_in[3];
  const float* W_qkv   = (const float*)d_in[4];
  const float* b_qkv   = (const float*)d_in[5];
  const float* qkv_A   = (const float*)d_in[6];
  const float* qkv_B   = (const float*)d_in[7];
  const float* W_proj  = (const float*)d_in[8];
  const float* b_proj  = (const float*)d_in[9];
  const float* route_W = (const float*)d_in[10];
  const float* proj_A  = (const float*)d_in[11];
  const float* proj_B  = (const float*)d_in[12];
  const float* W_idk   = (const float*)d_in[13];
  const float* b_idk   = (const float*)d_in[14];
  const float* idk_A   = (const float*)d_in[15];
  const float* idk_B   = (const float*)d_in[16];
  const float* W_idv   = (const float*)d_in[17];
  const float* b_idv   = (const float*)d_in[18];
  const float* idv_A   = (const float*)d_in[19];
  const float* idv_B   = (const float*)d_in[20];

  float* ws   = (float*)d_ws;
  float* qb   = ws + OQ;
  float* kb   = ws + OKb;
  float* vb   = ws + OVb;
  float* xo   = ws + OXO;
  float* qlow = ws + OQL;
  float* IDK  = ws + OIDK;
  float* IDV  = ws + OIDV;
  float* lowk = ws + OLK;
  float* lowv = ws + OLV;
  float* rd   = ws + ORD;
  float* plow = ws + OPL;
  float* coef = ws + OCF;

  float* out  = (float*)d_out;
  float* kmid = out + KMID_OFF;
  float* vmid = out + VMID_OFF;

  // LoRA "down" projections
  dot_small<<<1280, 256, 0, stream>>>(x, qkv_A, qlow, 24);
  dot_small<<<256,  256, 0, stream>>>(id_tot, idk_A, lowk, 8);
  dot_small<<<256,  256, 0, stream>>>(id_tot, idv_A, lowv, 8);

  // QKV projection (+bias +lora), scatter to q/k/v; q pre-scaled by D^-0.5
  gemm_ep<<<dim3(36, 80), 256, 0, stream>>>(x, W_qkv, b_qkv, qlow, qkv_B, nullptr,
                                            5120, 2304, 768, 0, qb, kb, vb);
  // ID_V
  gemm_ep<<<dim3(12, 16), 256, 0, stream>>>(id_tot, W_idv, b_idv, lowv, idv_B, IDV,
                                            1024, 768, 768, 1, nullptr, nullptr, nullptr);
  // 1 + tanh(ID_K)
  idk_kernel<<<256, 256, 0, stream>>>(id_tot, W_idk, b_idk, lowk, idk_B, IDK);
  // k_m_id / v_m_id outputs; v_buf rows 0..255 updated in place
  fixup_kernel<<<3072, 256, 0, stream>>>(kb, vb, IDK, IDV, kmid, vmid);

  // attention over memory tokens: 256 keys, top-128
  attn_topk2<256, 128><<<3072, 256, 0, stream>>>(qb, kmid, vmid, 256,
                                                 nullptr, nullptr, 0,
                                                 0, 256, xo, 0);
  // attention over sequence tokens: mem(1280) + raw k(1280) keys, top-640
  attn_topk2<2560, 640><<<12288, 256, 0, stream>>>(qb, mem_k, mem_v, 1280,
                                                   kb, vb, 1280,
                                                   256, 1024, xo, 256);

  // routed output projection
  dot_small<<<1280, 256, 0, stream>>>(xo, route_W, rd, 4);
  dot_small<<<1280, 256, 0, stream>>>(xo, proj_A, plow, 32);
  coef_kernel<<<20, 256, 0, stream>>>(rd, plow, coef);
  gemm_ep<<<dim3(12, 80), 256, 0, stream>>>(xo, W_proj, b_proj, coef, proj_B, out,
                                            5120, 768, 768, 2, nullptr, nullptr, nullptr);
}

// Round 3
// 2800.177 us; speedup vs baseline: 1.4475x; 1.3602x over previous
//
#include <hip/hip_runtime.h>
#include <cstddef>

// ---------------- problem constants ----------------
#define Bq    4
#define Hh    12
#define Dd    64
#define NNtok 1280      // N = N_M + N_S
#define NMtok 256
#define DIMc  768

// workspace offsets (in floats)
static const size_t OQ   = 0;                    // q_buf  (B,H,N,64)
static const size_t OKb  = OQ   + 3932160;       // k_buf  (B,H,N,64)  raw k
static const size_t OVb  = OKb  + 3932160;       // v_buf  (B,H,N,64)  -> rows 0..255 become v_m_id
static const size_t OXO  = OVb  + 3932160;       // xo     (B,N,768)
static const size_t OQL  = OXO  + 3932160;       // qkv_low (5120,24)
static const size_t OIDK = OQL  + 122880;        // 1+tanh(ID_K) (B*256,12)
static const size_t OIDV = OIDK + 12288;         // ID_V   (B*256,768)
static const size_t OLK  = OIDV + 786432;        // id_lowk (1024,8)
static const size_t OLV  = OLK  + 8192;          // id_lowv (1024,8)
static const size_t ORD  = OLV  + 8192;          // route dots (5120,4)
static const size_t OPL  = ORD  + 20480;         // proj low (5120,32)
static const size_t OCF  = OPL  + 163840;        // coef (5120,32)

// d_out offsets (floats)
static const size_t KMID_OFF = 3932160;
static const size_t VMID_OFF = 4718592;

__device__ __forceinline__ unsigned int f2k(float x) {
  unsigned int u = __float_as_uint(x);
  return (u & 0x80000000u) ? ~u : (u | 0x80000000u);  // monotone float->uint
}

// ---------------- small row-dot kernel ----------------
__global__ __launch_bounds__(256) void dot_small(
    const float* __restrict__ src, const float* __restrict__ mat,
    float* __restrict__ dst, int nout)
{
  int wv = threadIdx.x >> 6, ln = threadIdx.x & 63;
  size_t row = (size_t)blockIdx.x * 4 + wv;
  const float* s = src + row * DIMc;
  for (int o = 0; o < nout; ++o) {
    float p = 0.f;
    const float* m = mat + (size_t)o * DIMc;
    for (int c = ln; c < DIMc; c += 64) p += s[c] * m[c];
    for (int off = 32; off; off >>= 1) p += __shfl_xor(p, off, 64);
    if (ln == 0) dst[row * nout + o] = p;
  }
}

// ---------------- ID_K: 1+tanh(lora1(id_total, W_idk,...)) as (B*256, 12) ----------------
__global__ __launch_bounds__(256) void idk_kernel(
    const float* __restrict__ id_tot, const float* __restrict__ W_idk,
    const float* __restrict__ b_idk, const float* __restrict__ lowk,
    const float* __restrict__ idk_B, float* __restrict__ IDK)
{
  int wv = threadIdx.x >> 6, ln = threadIdx.x & 63;
  size_t row = (size_t)blockIdx.x * 4 + wv;
  const float* s = id_tot + row * DIMc;
  for (int h = 0; h < Hh; ++h) {
    float p = 0.f;
    const float* m = W_idk + (size_t)h * DIMc;
    for (int c = ln; c < DIMc; c += 64) p += s[c] * m[c];
    for (int off = 32; off; off >>= 1) p += __shfl_xor(p, off, 64);
    if (ln == 0) {
      float lo = 0.f;
      for (int r = 0; r < 8; ++r) lo += lowk[row * 8 + r] * idk_B[h * 8 + r];
      float val = p + b_idk[h] + lo * 0.125f;
      IDK[row * Hh + h] = 1.f + tanhf(val);
    }
  }
}

// ---------------- fixup: k_m_id / v_m_id (also updates v_buf rows 0..255) ----------------
__global__ __launch_bounds__(256) void fixup_kernel(
    const float* __restrict__ kb, float* __restrict__ vb,
    const float* __restrict__ IDK, const float* __restrict__ IDV,
    float* __restrict__ kmid, float* __restrict__ vmid)
{
  int e = blockIdx.x * 256 + threadIdx.x;   // flat (b,h,t,d)
  int d  = e & 63;
  int r1 = e >> 6;
  int tt = r1 & 255;
  int r2 = r1 >> 8;
  int h  = r2 % Hh;
  int b  = r2 / Hh;
  size_t src = ((size_t)(b * Hh + h) * NNtok + tt) * Dd + d;
  float km = kb[src] * IDK[(size_t)(b * 256 + tt) * Hh + h];
  kmid[e] = km;
  float vv = vb[src] + IDV[(size_t)(b * 256 + tt) * DIMc + h * 64 + d];
  vb[src] = vv;
  vmid[e] = vv;
}

// ---------------- route softmax * proj-low * (1/R) -> coef ----------------
__global__ __launch_bounds__(256) void coef_kernel(
    const float* __restrict__ rd, const float* __restrict__ plow,
    float* __restrict__ coef)
{
  int n = blockIdx.x * 256 + threadIdx.x;
  if (n >= Bq * NNtok) return;
  float l0 = rd[n * 4 + 0], l1 = rd[n * 4 + 1], l2 = rd[n * 4 + 2], l3 = rd[n * 4 + 3];
  float m = fmaxf(fmaxf(l0, l1), fmaxf(l2, l3));
  float e0 = expf(l0 - m), e1 = expf(l1 - m), e2 = expf(l2 - m), e3 = expf(l3 - m);
  float inv = 1.f / (e0 + e1 + e2 + e3);
  float rt[4] = { e0 * inv, e1 * inv, e2 * inv, e3 * inv };
  for (int e = 0; e < 4; ++e)
    for (int r = 0; r < 8; ++r)
      coef[(size_t)n * 32 + e * 8 + r] = rt[e] * plow[(size_t)n * 32 + e * 8 + r] * 0.125f;
}

// ---------------- tiled fp32 GEMM with fused epilogues ----------------
__global__ __launch_bounds__(256) void gemm_ep(
    const float* __restrict__ A, const float* __restrict__ W,
    const float* __restrict__ bias, const float* __restrict__ low,
    const float* __restrict__ Bl, float* __restrict__ dst,
    int M, int N, int K, int mode,
    float* __restrict__ qb, float* __restrict__ kb, float* __restrict__ vb)
{
  __shared__ alignas(16) float As[16][68];
  __shared__ alignas(16) float Bs[16][68];
  const int t  = threadIdx.x;
  const int tx = t & 15, ty = t >> 4;
  const int bn = blockIdx.x * 64, bm = blockIdx.y * 64;
  const int am = t >> 2, ak = (t & 3) << 2;

  float acc[4][4] = {};
  for (int k0 = 0; k0 < K; k0 += 16) {
    float4 av = *(const float4*)(A + (size_t)(bm + am) * K + k0 + ak);
    float4 bv = *(const float4*)(W + (size_t)(bn + am) * K + k0 + ak);
    As[ak + 0][am] = av.x; As[ak + 1][am] = av.y; As[ak + 2][am] = av.z; As[ak + 3][am] = av.w;
    Bs[ak + 0][am] = bv.x; Bs[ak + 1][am] = bv.y; Bs[ak + 2][am] = bv.z; Bs[ak + 3][am] = bv.w;
    __syncthreads();
#pragma unroll
    for (int kk = 0; kk < 16; ++kk) {
      float4 a4 = *(const float4*)&As[kk][ty << 2];
      float4 b4 = *(const float4*)&Bs[kk][tx << 2];
      float ar[4] = { a4.x, a4.y, a4.z, a4.w };
      float br[4] = { b4.x, b4.y, b4.z, b4.w };
#pragma unroll
      for (int i = 0; i < 4; ++i)
#pragma unroll
        for (int j = 0; j < 4; ++j) acc[i][j] += ar[i] * br[j];
    }
    __syncthreads();
  }

#pragma unroll
  for (int i = 0; i < 4; ++i) {
    int mg = bm + (ty << 2) + i;
#pragma unroll
    for (int j = 0; j < 4; ++j) {
      int col = bn + (tx << 2) + j;
      float v = acc[i][j];
      if (mode == 0) {
        int g = col / DIMc, jj = col % DIMc;
        v += bias[col];
        const float* lw = low + (size_t)mg * 24 + g * 8;
        const float* bb = Bl + (size_t)g * DIMc * 8 + (size_t)jj * 8;
        float lo = 0.f;
#pragma unroll
        for (int r = 0; r < 8; ++r) lo += lw[r] * bb[r];
        v += lo * 0.125f;
        int b = mg / NNtok, tt = mg % NNtok;
        int h = jj >> 6, d = jj & 63;
        size_t idx = ((size_t)(b * Hh + h) * NNtok + tt) * Dd + d;
        if (g == 0)      qb[idx] = v * 0.125f;   // q * D^-0.5
        else if (g == 1) kb[idx] = v;
        else             vb[idx] = v;
      } else if (mode == 1) {
        v += bias[col];
        float lo = 0.f;
#pragma unroll
        for (int r = 0; r < 8; ++r) lo += low[(size_t)mg * 8 + r] * Bl[(size_t)col * 8 + r];
        v += lo * 0.125f;
        dst[(size_t)mg * N + col] = v;
      } else {
        v += bias[col];
        float lo = 0.f;
#pragma unroll
        for (int e = 0; e < 4; ++e)
#pragma unroll
          for (int r = 0; r < 8; ++r)
            lo += low[(size_t)mg * 32 + e * 8 + r] * Bl[(size_t)e * DIMc * 8 + (size_t)col * 8 + r];
        v += lo;   // coef already carries route * 1/R
        dst[(size_t)mg * N + col] = v;
      }
    }
  }
}

// ---------------- top-k attention v3: dense PV, 3 blocks/CU ----------------
// Phase A: cooperative scores (register-double-buffered K), running row max.
// Phase B: per-wave exact radix select (wave w owns row w), barrier-free.
// Phase C: exp + unnormalized weights written in place into sc.
// Phase D: DENSE PV — wave w streams keys [w*NK/4,(w+1)*NK/4), coalesced V rows,
//          broadcast ds_read_b128 weights, no data-dependent addresses.
template<int NK, int TK>
__global__ __launch_bounds__(256, 3) void attn_topk3(
    const float* __restrict__ qbuf,
    const float* __restrict__ k0, const float* __restrict__ v0, int L0,
    const float* __restrict__ k1, const float* __restrict__ v1, int L1,
    int qrow0, int rows_per_bh,
    float* __restrict__ xo, int nofs)
{
  __shared__ float sc[4][NK];                 // scores -> weights
  __shared__ unsigned int hist4[4][256];      // per-wave histogram
  __shared__ float wavemax[4][4];             // [wave][row]
  __shared__ float rowinv[4];
  __shared__ float red[16][64];

  const int t = threadIdx.x;
  const int w = t >> 6, l = t & 63;
  const int bpb = rows_per_bh >> 2;
  const int bh = blockIdx.x / bpb;
  const int rb = blockIdx.x % bpb;
  const int b = bh / Hh, h = bh % Hh;
  const int qbase = qrow0 + rb * 4;

  // ---- Phase A: cooperative scores ----
  const int mykey = (w << 4) | (l & 15);
  const int dch = (l >> 4) << 4;
  float qreg[4][16];
#pragma unroll
  for (int r = 0; r < 4; ++r) {
    const float* qp = qbuf + ((size_t)bh * NNtok + qbase + r) * Dd + dch;
#pragma unroll
    for (int i = 0; i < 4; ++i) {
      float4 qv = *(const float4*)(qp + i * 4);
      qreg[r][i * 4 + 0] = qv.x; qreg[r][i * 4 + 1] = qv.y;
      qreg[r][i * 4 + 2] = qv.z; qreg[r][i * 4 + 3] = qv.w;
    }
  }

  float mx0 = -__builtin_inff(), mx1 = mx0, mx2 = mx0, mx3 = mx0;
  float kr[16];
  {
    int jg = mykey;
    const float* kp = (jg < L0) ? (k0 + ((size_t)bh * L0 + jg) * Dd + dch)
                                : (k1 + ((size_t)bh * L1 + (jg - L0)) * Dd + dch);
#pragma unroll
    for (int i = 0; i < 4; ++i) {
      float4 kv = *(const float4*)(kp + i * 4);
      kr[i * 4 + 0] = kv.x; kr[i * 4 + 1] = kv.y; kr[i * 4 + 2] = kv.z; kr[i * 4 + 3] = kv.w;
    }
  }
  for (int t0 = 0; t0 < NK; t0 += 64) {
    float krn[16];
    if (t0 + 64 < NK) {
      int jg = t0 + 64 + mykey;
      const float* kp = (jg < L0) ? (k0 + ((size_t)bh * L0 + jg) * Dd + dch)
                                  : (k1 + ((size_t)bh * L1 + (jg - L0)) * Dd + dch);
#pragma unroll
      for (int i = 0; i < 4; ++i) {
        float4 kv = *(const float4*)(kp + i * 4);
        krn[i * 4 + 0] = kv.x; krn[i * 4 + 1] = kv.y; krn[i * 4 + 2] = kv.z; krn[i * 4 + 3] = kv.w;
      }
    }
    float p0 = 0, p1 = 0, p2 = 0, p3 = 0;
#pragma unroll
    for (int i = 0; i < 16; ++i) {
      p0 += kr[i] * qreg[0][i]; p1 += kr[i] * qreg[1][i];
      p2 += kr[i] * qreg[2][i]; p3 += kr[i] * qreg[3][i];
    }
    p0 += __shfl_xor(p0, 16, 64); p0 += __shfl_xor(p0, 32, 64);
    p1 += __shfl_xor(p1, 16, 64); p1 += __shfl_xor(p1, 32, 64);
    p2 += __shfl_xor(p2, 16, 64); p2 += __shfl_xor(p2, 32, 64);
    p3 += __shfl_xor(p3, 16, 64); p3 += __shfl_xor(p3, 32, 64);
    mx0 = fmaxf(mx0, p0); mx1 = fmaxf(mx1, p1);
    mx2 = fmaxf(mx2, p2); mx3 = fmaxf(mx3, p3);
    if (l < 16) {
      sc[0][t0 + mykey] = p0; sc[1][t0 + mykey] = p1;
      sc[2][t0 + mykey] = p2; sc[3][t0 + mykey] = p3;
    }
#pragma unroll
    for (int i = 0; i < 16; ++i) kr[i] = krn[i];
  }
  // per-wave partial row maxes (all lanes hold valid scores, dup x4)
#pragma unroll
  for (int off = 8; off; off >>= 1) {
    mx0 = fmaxf(mx0, __shfl_xor(mx0, off, 64));
    mx1 = fmaxf(mx1, __shfl_xor(mx1, off, 64));
    mx2 = fmaxf(mx2, __shfl_xor(mx2, off, 64));
    mx3 = fmaxf(mx3, __shfl_xor(mx3, off, 64));
  }
  if (l == 0) {
    wavemax[w][0] = mx0; wavemax[w][1] = mx1;
    wavemax[w][2] = mx2; wavemax[w][3] = mx3;
  }
  __syncthreads();

  // ---- Phase B: per-wave exact radix select on row w ----
  float* s = sc[w];
  unsigned int* hist = hist4[w];
  unsigned int prefix = 0;
  int kk = TK, ceq = 0;
#pragma unroll
  for (int p = 3; p >= 0; --p) {
#pragma unroll
    for (int z = 0; z < 4; ++z) hist[l + z * 64] = 0u;
    int sh = p * 8;
    unsigned int hi_mask = (p == 3) ? 0u : (0xFFFFFFFFu << (8 * (p + 1)));
    for (int i = l; i < NK; i += 64) {
      unsigned int u = f2k(s[i]);
      if ((u & hi_mask) == prefix) atomicAdd(&hist[(u >> sh) & 255], 1u);
    }
    unsigned int h0 = hist[4 * l + 0], h1 = hist[4 * l + 1],
                 h2 = hist[4 * l + 2], h3 = hist[4 * l + 3];
    unsigned int s3 = h3, s2 = h2 + s3, s1 = h1 + s2, s0 = h0 + s1;
    unsigned int tsum = s0;
#pragma unroll
    for (int off = 1; off < 64; off <<= 1) {
      unsigned int other = __shfl(tsum, l + off, 64);
      tsum += (l + off < 64) ? other : 0u;
    }
    unsigned int T = tsum - s0;   // exclusive suffix: lanes > l
    unsigned int Sv0 = T + s0, Sv1 = T + s1, Sv2 = T + s2, Sv3 = T + s3, Sv4 = T;
    int fb = -1, fkk = 0, fceq = 0;
    unsigned int ukk = (unsigned int)kk;
    if (Sv0 >= ukk && Sv1 < ukk) { fb = 4 * l + 0; fkk = (int)(ukk - Sv1); fceq = (int)(Sv0 - Sv1); }
    if (Sv1 >= ukk && Sv2 < ukk) { fb = 4 * l + 1; fkk = (int)(ukk - Sv2); fceq = (int)(Sv1 - Sv2); }
    if (Sv2 >= ukk && Sv3 < ukk) { fb = 4 * l + 2; fkk = (int)(ukk - Sv3); fceq = (int)(Sv2 - Sv3); }
    if (Sv3 >= ukk && Sv4 < ukk) { fb = 4 * l + 3; fkk = (int)(ukk - Sv4); fceq = (int)(Sv3 - Sv4); }
    unsigned long long mb = __ballot(fb >= 0);
    int src = __ffsll((unsigned long long)mb) - 1;
    int bin = __shfl(fb, src, 64);
    kk      = __shfl(fkk, src, 64);
    ceq     = __shfl(fceq, src, 64);
    prefix |= ((unsigned int)bin) << sh;
  }
  const unsigned int Tkey = prefix;
  const int need = kk;
  if (need < ceq) {                   // rare ties: keep lowest indices (jax order)
    int seen = 0;
    for (int i0 = 0; i0 < NK && seen < ceq; i0 += 64) {
      int i = i0 + l;
      bool eq = (f2k(s[i]) == Tkey);
      unsigned long long m = __ballot(eq);
      int before = __popcll(m & ((1ull << l) - 1ull));
      if (eq && (seen + before) >= need) s[i] = -__builtin_inff();
      seen += __popcll(m);
    }
  }

  // ---- Phase C: exp + unnormalized weights in place ----
  {
    float m = fmaxf(fmaxf(wavemax[0][w], wavemax[1][w]),
                    fmaxf(wavemax[2][w], wavemax[3][w]));
    float sum = 0.f;
    for (int i0 = 0; i0 < NK; i0 += 64) {
      int i = i0 + l;
      float x = s[i];
      float wv = (f2k(x) >= Tkey) ? __expf(x - m) : 0.f;
      s[i] = wv;
      sum += wv;
    }
#pragma unroll
    for (int off = 32; off; off >>= 1) sum += __shfl_xor(sum, off, 64);
    if (l == 0) rowinv[w] = 1.f / sum;
  }
  __syncthreads();

  // ---- Phase D: dense PV, wave w streams its key range ----
  const int KPW = NK / 4;
  float a0 = 0, a1 = 0, a2 = 0, a3 = 0;
  for (int j = w * KPW; j < (w + 1) * KPW; j += 4) {
    float4 w0 = *(const float4*)&sc[0][j];
    float4 w1 = *(const float4*)&sc[1][j];
    float4 w2 = *(const float4*)&sc[2][j];
    float4 w3 = *(const float4*)&sc[3][j];
#pragma unroll
    for (int u = 0; u < 4; ++u) {
      int jg = j + u;
      const float* vp = (jg < L0) ? (v0 + ((size_t)bh * L0 + jg) * Dd)
                                  : (v1 + ((size_t)bh * L1 + (jg - L0)) * Dd);
      float vv = vp[l];
      float c0 = (u == 0) ? w0.x : (u == 1) ? w0.y : (u == 2) ? w0.z : w0.w;
      float c1 = (u == 0) ? w1.x : (u == 1) ? w1.y : (u == 2) ? w1.z : w1.w;
      float c2 = (u == 0) ? w2.x : (u == 1) ? w2.y : (u == 2) ? w2.z : w2.w;
      float c3 = (u == 0) ? w3.x : (u == 1) ? w3.y : (u == 2) ? w3.z : w3.w;
      a0 += c0 * vv; a1 += c1 * vv; a2 += c2 * vv; a3 += c3 * vv;
    }
  }
  red[w * 4 + 0][l] = a0;
  red[w * 4 + 1][l] = a1;
  red[w * 4 + 2][l] = a2;
  red[w * 4 + 3][l] = a3;
  __syncthreads();

  // final cross-wave reduce + normalize: thread t -> (row t>>6, dim t&63)
  {
    int r = t >> 6, d = t & 63;
    float sres = red[r][d] + red[4 + r][d] + red[8 + r][d] + red[12 + r][d];
    int n = nofs + rb * 4 + r;
    xo[((size_t)b * NNtok + n) * DIMc + h * 64 + d] = sres * rowinv[r];
  }
}

// ---------------- host ----------------
extern "C" void kernel_launch(void* const* d_in, const int* in_sizes, int n_in,
                              void* d_out, int out_size, void* d_ws, size_t ws_size,
                              hipStream_t stream)
{
  const float* x       = (const float*)d_in[0];
  const float* id_tot  = (const float*)d_in[1];
  const float* mem_k   = (const float*)d_in[2];
  const float* mem_v   = (const float*)d_in[3];
  const float* W_qkv   = (const float*)d_in[4];
  const float* b_qkv   = (const float*)d_in[5];
  const float* qkv_A   = (const float*)d_in[6];
  const float* qkv_B   = (const float*)d_in[7];
  const float* W_proj  = (const float*)d_in[8];
  const float* b_proj  = (const float*)d_in[9];
  const float* route_W = (const float*)d_in[10];
  const float* proj_A  = (const float*)d_in[11];
  const float* proj_B  = (const float*)d_in[12];
  const float* W_idk   = (const float*)d_in[13];
  const float* b_idk   = (const float*)d_in[14];
  const float* idk_A   = (const float*)d_in[15];
  const float* idk_B   = (const float*)d_in[16];
  const float* W_idv   = (const float*)d_in[17];
  const float* b_idv   = (const float*)d_in[18];
  const float* idv_A   = (const float*)d_in[19];
  const float* idv_B   = (const float*)d_in[20];

  float* ws   = (float*)d_ws;
  float* qb   = ws + OQ;
  float* kb   = ws + OKb;
  float* vb   = ws + OVb;
  float* xo   = ws + OXO;
  float* qlow = ws + OQL;
  float* IDK  = ws + OIDK;
  float* IDV  = ws + OIDV;
  float* lowk = ws + OLK;
  float* lowv = ws + OLV;
  float* rd   = ws + ORD;
  float* plow = ws + OPL;
  float* coef = ws + OCF;

  float* out  = (float*)d_out;
  float* kmid = out + KMID_OFF;
  float* vmid = out + VMID_OFF;

  // LoRA "down" projections
  dot_small<<<1280, 256, 0, stream>>>(x, qkv_A, qlow, 24);
  dot_small<<<256,  256, 0, stream>>>(id_tot, idk_A, lowk, 8);
  dot_small<<<256,  256, 0, stream>>>(id_tot, idv_A, lowv, 8);

  // QKV projection (+bias +lora), scatter to q/k/v; q pre-scaled by D^-0.5
  gemm_ep<<<dim3(36, 80), 256, 0, stream>>>(x, W_qkv, b_qkv, qlow, qkv_B, nullptr,
                                            5120, 2304, 768, 0, qb, kb, vb);
  // ID_V
  gemm_ep<<<dim3(12, 16), 256, 0, stream>>>(id_tot, W_idv, b_idv, lowv, idv_B, IDV,
                                            1024, 768, 768, 1, nullptr, nullptr, nullptr);
  // 1 + tanh(ID_K)
  idk_kernel<<<256, 256, 0, stream>>>(id_tot, W_idk, b_idk, lowk, idk_B, IDK);
  // k_m_id / v_m_id outputs; v_buf rows 0..255 updated in place
  fixup_kernel<<<3072, 256, 0, stream>>>(kb, vb, IDK, IDV, kmid, vmid);

  // attention over memory tokens: 256 keys, top-128
  attn_topk3<256, 128><<<3072, 256, 0, stream>>>(qb, kmid, vmid, 256,
                                                 nullptr, nullptr, 0,
                                                 0, 256, xo, 0);
  // attention over sequence tokens: mem(1280) + raw k(1280) keys, top-640
  attn_topk3<2560, 640><<<12288, 256, 0, stream>>>(qb, mem_k, mem_v, 1280,
                                                   kb, vb, 1280,
                                                   256, 1024, xo, 256);

  // routed output projection
  dot_small<<<1280, 256, 0, stream>>>(xo, route_W, rd, 4);
  dot_small<<<1280, 256, 0, stream>>>(xo, proj_A, plow, 32);
  coef_kernel<<<20, 256, 0, stream>>>(rd, plow, coef);
  gemm_ep<<<dim3(12, 80), 256, 0, stream>>>(xo, W_proj, b_proj, coef, proj_B, out,
                                            5120, 768, 768, 2, nullptr, nullptr, nullptr);
}

// Round 4
// 2125.449 us; speedup vs baseline: 1.9070x; 1.3175x over previous
//
#include <hip/hip_runtime.h>
#include <cstddef>

// ---------------- problem constants ----------------
#define Bq    4
#define Hh    12
#define Dd    64
#define NNtok 1280      // N = N_M + N_S
#define DIMc  768

typedef __attribute__((ext_vector_type(8))) short bf16x8;
typedef __attribute__((ext_vector_type(4))) float f32x4;

// workspace offsets (in floats)
static const size_t OKb   = 0;                   // kb    fp32 (B,H,1280,64)
static const size_t OVb   = 3932160;             // vb    fp32 (B,H,1280,64) rows0-255 -> v_m_id
static const size_t OXO   = 7864320;             // xo    fp32 (B,1280,768)
static const size_t OQL   = 11796480;            // qkv_low (5120,24)
static const size_t OIDK  = 11919360;            // 1+tanh(ID_K) (1024,12)
static const size_t OIDV  = 11931648;            // ID_V (1024,768)
static const size_t OLK   = 12718080;            // id_lowk (1024,8)
static const size_t OLV   = 12726272;            // id_lowv (1024,8)
static const size_t ORD   = 12734464;            // route dots (5120,4)
static const size_t OPL   = 12754944;            // proj low (5120,32)
static const size_t OCF   = 12918784;            // coef (5120,32)
static const size_t OQH   = 13082624;            // qh   bf16 (B,H,1280,64)
static const size_t OKFH  = 15048704;            // kfh  bf16 (B,H,2560,64)  [mem_k | k]
static const size_t OVTH  = 18980864;            // vth  bf16 (B,H,64,2560)  [mem_v | v_add_id]^T
static const size_t OKMH  = 22913024;            // kmh  bf16 (B,H,256,64)   k_m_id
static const size_t OVMTH = 23306240;            // vmth bf16 (B,H,64,256)   v_m_id^T
// end: 23699456 floats = 94.8 MB

// d_out offsets (floats)
static const size_t KMID_OFF = 3932160;
static const size_t VMID_OFF = 4718592;

__device__ __forceinline__ unsigned int f2k(float x) {
  unsigned int u = __float_as_uint(x);
  return (u & 0x80000000u) ? ~u : (u | 0x80000000u);  // monotone float->uint
}
__device__ __forceinline__ unsigned int pk_bf16(float a, float b) {  // RNE pack
  unsigned int ua = __float_as_uint(a), ub = __float_as_uint(b);
  ua += 0x7fffu + ((ua >> 16) & 1u);
  ub += 0x7fffu + ((ub >> 16) & 1u);
  return (ua >> 16) | (ub & 0xffff0000u);
}
__device__ __forceinline__ unsigned short bf16_1(float a) {
  unsigned int ua = __float_as_uint(a);
  ua += 0x7fffu + ((ua >> 16) & 1u);
  return (unsigned short)(ua >> 16);
}

// ---------------- small row-dot kernel ----------------
__global__ __launch_bounds__(256) void dot_small(
    const float* __restrict__ src, const float* __restrict__ mat,
    float* __restrict__ dst, int nout)
{
  int wv = threadIdx.x >> 6, ln = threadIdx.x & 63;
  size_t row = (size_t)blockIdx.x * 4 + wv;
  const float* s = src + row * DIMc;
  for (int o = 0; o < nout; ++o) {
    float p = 0.f;
    const float* m = mat + (size_t)o * DIMc;
    for (int c = ln; c < DIMc; c += 64) p += s[c] * m[c];
    for (int off = 32; off; off >>= 1) p += __shfl_xor(p, off, 64);
    if (ln == 0) dst[row * nout + o] = p;
  }
}

// ---------------- ID_K: 1+tanh(lora1(...)) ----------------
__global__ __launch_bounds__(256) void idk_kernel(
    const float* __restrict__ id_tot, const float* __restrict__ W_idk,
    const float* __restrict__ b_idk, const float* __restrict__ lowk,
    const float* __restrict__ idk_B, float* __restrict__ IDK)
{
  int wv = threadIdx.x >> 6, ln = threadIdx.x & 63;
  size_t row = (size_t)blockIdx.x * 4 + wv;
  const float* s = id_tot + row * DIMc;
  for (int h = 0; h < Hh; ++h) {
    float p = 0.f;
    const float* m = W_idk + (size_t)h * DIMc;
    for (int c = ln; c < DIMc; c += 64) p += s[c] * m[c];
    for (int off = 32; off; off >>= 1) p += __shfl_xor(p, off, 64);
    if (ln == 0) {
      float lo = 0.f;
      for (int r = 0; r < 8; ++r) lo += lowk[row * 8 + r] * idk_B[h * 8 + r];
      float val = p + b_idk[h] + lo * 0.125f;
      IDK[row * Hh + h] = 1.f + tanhf(val);
    }
  }
}

// ---------------- fixup: k_m_id / v_m_id ----------------
__global__ __launch_bounds__(256) void fixup_kernel(
    const float* __restrict__ kb, float* __restrict__ vb,
    const float* __restrict__ IDK, const float* __restrict__ IDV,
    float* __restrict__ kmid, float* __restrict__ vmid,
    unsigned short* __restrict__ kmh)
{
  int e = blockIdx.x * 256 + threadIdx.x;   // flat (b,h,t,d), t<256
  int d  = e & 63;
  int r1 = e >> 6;
  int tt = r1 & 255;
  int r2 = r1 >> 8;
  int h  = r2 % Hh;
  int b  = r2 / Hh;
  size_t src = ((size_t)(b * Hh + h) * NNtok + tt) * Dd + d;
  float km = kb[src] * IDK[(size_t)(b * 256 + tt) * Hh + h];
  kmid[e] = km;
  kmh[e] = bf16_1(km);
  float vv = vb[src] + IDV[(size_t)(b * 256 + tt) * DIMc + h * 64 + d];
  vb[src] = vv;
  vmid[e] = vv;
}

// ---------------- cast mem_k -> kfh rows 0..1279 (bf16) ----------------
__global__ __launch_bounds__(256) void cast_k(
    const float* __restrict__ mem_k, unsigned short* __restrict__ kfh)
{
  size_t idx = ((size_t)blockIdx.x * 256 + threadIdx.x) * 8;   // 48*81920 elems
  int bh = (int)(idx / 81920);
  int r  = (int)(idx % 81920);
  const float* s = mem_k + (size_t)bh * 81920 + r;
  float4 a = *(const float4*)s;
  float4 b = *(const float4*)(s + 4);
  uint2 w0, w1;
  w0.x = pk_bf16(a.x, a.y); w0.y = pk_bf16(a.z, a.w);
  w1.x = pk_bf16(b.x, b.y); w1.y = pk_bf16(b.z, b.w);
  unsigned int* dp = (unsigned int*)(kfh + (size_t)bh * 163840 + r);
  dp[0] = w0.x; dp[1] = w0.y; dp[2] = w1.x; dp[3] = w1.y;
}

// ---------------- transpose fp32 (rows,64) -> bf16 (64, cols) ----------------
__global__ __launch_bounds__(256) void transpose_bf16(
    const float* __restrict__ src, unsigned short* __restrict__ dst,
    int nrows, int srcBh, int dstBh, int dstCols, int colOfs)
{
  int bh = blockIdx.y;
  int idx = blockIdx.x * 256 + threadIdx.x;
  int npairs = nrows >> 1;
  if (idx >= 64 * npairs) return;
  int kp = idx % npairs, d = idx / npairs;
  const float* s = src + (size_t)bh * srcBh;
  float a = s[(size_t)(2 * kp) * 64 + d];
  float b = s[(size_t)(2 * kp + 1) * 64 + d];
  *(unsigned int*)(dst + (size_t)bh * dstBh + (size_t)d * dstCols + colOfs + 2 * kp)
      = pk_bf16(a, b);
}

// ---------------- route softmax * proj-low * (1/R) -> coef ----------------
__global__ __launch_bounds__(256) void coef_kernel(
    const float* __restrict__ rd, const float* __restrict__ plow,
    float* __restrict__ coef)
{
  int n = blockIdx.x * 256 + threadIdx.x;
  if (n >= Bq * NNtok) return;
  float l0 = rd[n * 4 + 0], l1 = rd[n * 4 + 1], l2 = rd[n * 4 + 2], l3 = rd[n * 4 + 3];
  float m = fmaxf(fmaxf(l0, l1), fmaxf(l2, l3));
  float e0 = expf(l0 - m), e1 = expf(l1 - m), e2 = expf(l2 - m), e3 = expf(l3 - m);
  float inv = 1.f / (e0 + e1 + e2 + e3);
  float rt[4] = { e0 * inv, e1 * inv, e2 * inv, e3 * inv };
  for (int e = 0; e < 4; ++e)
    for (int r = 0; r < 8; ++r)
      coef[(size_t)n * 32 + e * 8 + r] = rt[e] * plow[(size_t)n * 32 + e * 8 + r] * 0.125f;
}

// ---------------- tiled fp32 GEMM with fused epilogues ----------------
// mode 0: qkv: scatter q->qh(bf16,*0.125), k->kb(fp32)+kfh(bf16 rows1280+), v->vb
// mode 1: ID_V; mode 2: routed proj
__global__ __launch_bounds__(256) void gemm_ep(
    const float* __restrict__ A, const float* __restrict__ W,
    const float* __restrict__ bias, const float* __restrict__ low,
    const float* __restrict__ Bl, float* __restrict__ dst,
    int M, int N, int K, int mode,
    unsigned short* __restrict__ qh, float* __restrict__ kb,
    float* __restrict__ vb, unsigned short* __restrict__ kfh)
{
  __shared__ alignas(16) float As[16][68];
  __shared__ alignas(16) float Bs[16][68];
  const int t  = threadIdx.x;
  const int tx = t & 15, ty = t >> 4;
  const int bn = blockIdx.x * 64, bm = blockIdx.y * 64;
  const int am = t >> 2, ak = (t & 3) << 2;

  float acc[4][4] = {};
  for (int k0 = 0; k0 < K; k0 += 16) {
    float4 av = *(const float4*)(A + (size_t)(bm + am) * K + k0 + ak);
    float4 bv = *(const float4*)(W + (size_t)(bn + am) * K + k0 + ak);
    As[ak + 0][am] = av.x; As[ak + 1][am] = av.y; As[ak + 2][am] = av.z; As[ak + 3][am] = av.w;
    Bs[ak + 0][am] = bv.x; Bs[ak + 1][am] = bv.y; Bs[ak + 2][am] = bv.z; Bs[ak + 3][am] = bv.w;
    __syncthreads();
#pragma unroll
    for (int kk = 0; kk < 16; ++kk) {
      float4 a4 = *(const float4*)&As[kk][ty << 2];
      float4 b4 = *(const float4*)&Bs[kk][tx << 2];
      float ar[4] = { a4.x, a4.y, a4.z, a4.w };
      float br[4] = { b4.x, b4.y, b4.z, b4.w };
#pragma unroll
      for (int i = 0; i < 4; ++i)
#pragma unroll
        for (int j = 0; j < 4; ++j) acc[i][j] += ar[i] * br[j];
    }
    __syncthreads();
  }

  if (mode == 0) {
    int g   = bn / DIMc;                 // uniform per block (64 | 768)
    int jj0 = bn - g * DIMc + (tx << 2);
    int hh  = jj0 >> 6, d0 = jj0 & 63;
#pragma unroll
    for (int i = 0; i < 4; ++i) {
      int mg = bm + (ty << 2) + i;
      int bb = mg / NNtok, tt = mg % NNtok;
      float vals[4];
#pragma unroll
      for (int j = 0; j < 4; ++j) {
        int col = bn + (tx << 2) + j;
        float v = acc[i][j] + bias[col];
        const float* lw  = low + (size_t)mg * 24 + g * 8;
        const float* bbp = Bl + (size_t)g * DIMc * 8 + (size_t)(jj0 + j) * 8;
        float lo = 0.f;
#pragma unroll
        for (int r = 0; r < 8; ++r) lo += lw[r] * bbp[r];
        vals[j] = v + lo * 0.125f;
      }
      size_t idx = ((size_t)(bb * Hh + hh) * NNtok + tt) * Dd + d0;
      if (g == 0) {
        uint2 wv;
        wv.x = pk_bf16(vals[0] * 0.125f, vals[1] * 0.125f);
        wv.y = pk_bf16(vals[2] * 0.125f, vals[3] * 0.125f);
        *(uint2*)(qh + idx) = wv;
      } else if (g == 1) {
        *(float4*)(kb + idx) = make_float4(vals[0], vals[1], vals[2], vals[3]);
        size_t kidx = ((size_t)(bb * Hh + hh) * 2560 + 1280 + tt) * Dd + d0;
        uint2 wv;
        wv.x = pk_bf16(vals[0], vals[1]);
        wv.y = pk_bf16(vals[2], vals[3]);
        *(uint2*)(kfh + kidx) = wv;
      } else {
        *(float4*)(vb + idx) = make_float4(vals[0], vals[1], vals[2], vals[3]);
      }
    }
    return;
  }

#pragma unroll
  for (int i = 0; i < 4; ++i) {
    int mg = bm + (ty << 2) + i;
#pragma unroll
    for (int j = 0; j < 4; ++j) {
      int col = bn + (tx << 2) + j;
      float v = acc[i][j] + bias[col];
      if (mode == 1) {
        float lo = 0.f;
#pragma unroll
        for (int r = 0; r < 8; ++r) lo += low[(size_t)mg * 8 + r] * Bl[(size_t)col * 8 + r];
        v += lo * 0.125f;
      } else {
        float lo = 0.f;
#pragma unroll
        for (int e = 0; e < 4; ++e)
#pragma unroll
          for (int r = 0; r < 8; ++r)
            lo += low[(size_t)mg * 32 + e * 8 + r] * Bl[(size_t)e * DIMc * 8 + (size_t)col * 8 + r];
        v += lo;   // coef already carries route * 1/R
      }
      dst[(size_t)mg * N + col] = v;
    }
  }
}

// ---------------- MFMA top-k attention ----------------
// 1 block = 4 q-rows of one (b,h). Phase A: QK^T via mfma_16x16x32_bf16
// (A rows 0-3 = q, rows 4-15 zero; B-frag = row-major K direct from global).
// Radix select + softmax per wave (wave w owns row w); exp pass packs bf16
// weight pairs into the LOWER half of the score row (write ptr i/2 trails
// read ptr i). Phase D: PV via MFMA, B-frag = V^T direct from global.
template<int NK>
__global__ __launch_bounds__(256, 3) void attn_mfma(
    const unsigned short* __restrict__ qh,   // (bh,1280,64) bf16
    const unsigned short* __restrict__ kf,   // (bh,NK,64)   bf16
    const unsigned short* __restrict__ vt,   // (bh,64,NK)   bf16 (V^T)
    int TK, int qrow0, int rows_per_bh,
    float* __restrict__ xo, int nofs)
{
  constexpr int SCP = NK + 8;                // pad: row stride 2568 -> bank step 8
  __shared__ float sc[4 * SCP];              // fp32 scores; later lower half = bf16 weights
  __shared__ unsigned int hist4[4][256];
  __shared__ float rowinv[4];

  const int t = threadIdx.x, w = t >> 6, l = t & 63;
  const int bpb = rows_per_bh >> 2;
  const int bh = blockIdx.x / bpb, rb = blockIdx.x % bpb;
  const int b = bh / Hh, h = bh % Hh;
  const int qbase = qrow0 + rb * 4;
  const int m = l & 15, quad = l >> 4;

  // ---- Phase A: QK^T via MFMA ----
  bf16x8 aq0 = {0,0,0,0,0,0,0,0}, aq1 = {0,0,0,0,0,0,0,0};
  if (m < 4) {
    const unsigned short* qp = qh + ((size_t)bh * NNtok + qbase + m) * Dd + quad * 8;
    aq0 = *(const bf16x8*)qp;
    aq1 = *(const bf16x8*)(qp + 32);
  }
  const unsigned short* kbase = kf + (size_t)bh * NK * Dd;
  for (int n0 = w * 16; n0 < NK; n0 += 64) {
    const unsigned short* kp = kbase + (size_t)(n0 + m) * Dd + quad * 8;
    bf16x8 b0 = *(const bf16x8*)kp;
    bf16x8 b1 = *(const bf16x8*)(kp + 32);
    f32x4 acc = {0.f, 0.f, 0.f, 0.f};
    acc = __builtin_amdgcn_mfma_f32_16x16x32_bf16(aq0, b0, acc, 0, 0, 0);
    acc = __builtin_amdgcn_mfma_f32_16x16x32_bf16(aq1, b1, acc, 0, 0, 0);
    if (l < 16) {      // quad0 lanes hold rows 0-3 (row = reg), col = n0 + l
      sc[0 * SCP + n0 + l] = acc[0];
      sc[1 * SCP + n0 + l] = acc[1];
      sc[2 * SCP + n0 + l] = acc[2];
      sc[3 * SCP + n0 + l] = acc[3];
    }
  }
  __syncthreads();

  // ---- Phase B: per-wave exact radix select on row w ----
  float* s = sc + w * SCP;
  unsigned int* hist = hist4[w];
  unsigned int prefix = 0;
  int kk = TK, ceq = 0;
#pragma unroll
  for (int p = 3; p >= 0; --p) {
#pragma unroll
    for (int z = 0; z < 4; ++z) hist[l + z * 64] = 0u;
    int sh = p * 8;
    unsigned int hi_mask = (p == 3) ? 0u : (0xFFFFFFFFu << (8 * (p + 1)));
    for (int i = l; i < NK; i += 64) {
      unsigned int u = f2k(s[i]);
      if ((u & hi_mask) == prefix) atomicAdd(&hist[(u >> sh) & 255], 1u);
    }
    unsigned int h0 = hist[4 * l + 0], h1 = hist[4 * l + 1],
                 h2 = hist[4 * l + 2], h3 = hist[4 * l + 3];
    unsigned int s3 = h3, s2 = h2 + s3, s1 = h1 + s2, s0 = h0 + s1;
    unsigned int tsum = s0;
#pragma unroll
    for (int off = 1; off < 64; off <<= 1) {
      unsigned int other = __shfl(tsum, l + off, 64);
      tsum += (l + off < 64) ? other : 0u;
    }
    unsigned int T = tsum - s0;   // exclusive suffix: lanes > l
    unsigned int Sv0 = T + s0, Sv1 = T + s1, Sv2 = T + s2, Sv3 = T + s3, Sv4 = T;
    int fb = -1, fkk = 0, fceq = 0;
    unsigned int ukk = (unsigned int)kk;
    if (Sv0 >= ukk && Sv1 < ukk) { fb = 4 * l + 0; fkk = (int)(ukk - Sv1); fceq = (int)(Sv0 - Sv1); }
    if (Sv1 >= ukk && Sv2 < ukk) { fb = 4 * l + 1; fkk = (int)(ukk - Sv2); fceq = (int)(Sv1 - Sv2); }
    if (Sv2 >= ukk && Sv3 < ukk) { fb = 4 * l + 2; fkk = (int)(ukk - Sv3); fceq = (int)(Sv2 - Sv3); }
    if (Sv3 >= ukk && Sv4 < ukk) { fb = 4 * l + 3; fkk = (int)(ukk - Sv4); fceq = (int)(Sv3 - Sv4); }
    unsigned long long mb = __ballot(fb >= 0);
    int src = __ffsll((unsigned long long)mb) - 1;
    int bin = __shfl(fb, src, 64);
    kk      = __shfl(fkk, src, 64);
    ceq     = __shfl(fceq, src, 64);
    prefix |= ((unsigned int)bin) << sh;
  }
  const unsigned int Tkey = prefix;
  const int need = kk;
  if (need < ceq) {                   // rare ties: keep lowest indices (jax order)
    int seen = 0;
    for (int i0 = 0; i0 < NK && seen < ceq; i0 += 64) {
      int i = i0 + l;
      bool eq = (f2k(s[i]) == Tkey);
      unsigned long long mm = __ballot(eq);
      int before = __popcll(mm & ((1ull << l) - 1ull));
      if (eq && (seen + before) >= need) s[i] = -__builtin_inff();
      seen += __popcll(mm);
    }
  }

  // ---- Phase C: max, exp, pack bf16 weight-pairs into lower half of row ----
  {
    float mx = -__builtin_inff();
    for (int i0 = 0; i0 < NK; i0 += 128) {
      float2 v2 = *(const float2*)&s[i0 + 2 * l];
      mx = fmaxf(mx, fmaxf(v2.x, v2.y));
    }
#pragma unroll
    for (int off = 32; off; off >>= 1) mx = fmaxf(mx, __shfl_xor(mx, off, 64));
    float sum = 0.f;
    unsigned int* wp = (unsigned int*)s;
    for (int i0 = 0; i0 < NK; i0 += 128) {
      float2 v2 = *(const float2*)&s[i0 + 2 * l];
      float w0 = (f2k(v2.x) >= Tkey) ? __expf(v2.x - mx) : 0.f;
      float w1 = (f2k(v2.y) >= Tkey) ? __expf(v2.y - mx) : 0.f;
      wp[i0 / 2 + l] = pk_bf16(w0, w1);   // word i/2 trails read ptr i: safe
      sum += w0 + w1;
    }
#pragma unroll
    for (int off = 32; off; off >>= 1) sum += __shfl_xor(sum, off, 64);
    if (l == 0) rowinv[w] = 1.f / sum;
  }
  __syncthreads();

  // ---- Phase D: PV via MFMA; wave w handles dims [16w,16w+16) ----
  const unsigned short* vrow = vt + (size_t)bh * Dd * NK + (size_t)(w * 16 + m) * NK;
  const unsigned int* wrow = (const unsigned int*)(sc + (size_t)m * SCP);
  f32x4 o = {0.f, 0.f, 0.f, 0.f};
  for (int c = 0; c < NK / 32; ++c) {
    bf16x8 af = {0,0,0,0,0,0,0,0};
    if (m < 4) af = *(const bf16x8*)(wrow + c * 16 + quad * 4);
    bf16x8 bf = *(const bf16x8*)(vrow + c * 32 + quad * 8);
    o = __builtin_amdgcn_mfma_f32_16x16x32_bf16(af, bf, o, 0, 0, 0);
  }
  if (l < 16) {
#pragma unroll
    for (int r = 0; r < 4; ++r) {
      int n = nofs + rb * 4 + r;
      xo[((size_t)b * NNtok + n) * DIMc + h * 64 + w * 16 + l] = o[r] * rowinv[r];
    }
  }
}

// ---------------- host ----------------
extern "C" void kernel_launch(void* const* d_in, const int* in_sizes, int n_in,
                              void* d_out, int out_size, void* d_ws, size_t ws_size,
                              hipStream_t stream)
{
  const float* x       = (const float*)d_in[0];
  const float* id_tot  = (const float*)d_in[1];
  const float* mem_k   = (const float*)d_in[2];
  const float* mem_v   = (const float*)d_in[3];
  const float* W_qkv   = (const float*)d_in[4];
  const float* b_qkv   = (const float*)d_in[5];
  const float* qkv_A   = (const float*)d_in[6];
  const float* qkv_B   = (const float*)d_in[7];
  const float* W_proj  = (const float*)d_in[8];
  const float* b_proj  = (const float*)d_in[9];
  const float* route_W = (const float*)d_in[10];
  const float* proj_A  = (const float*)d_in[11];
  const float* proj_B  = (const float*)d_in[12];
  const float* W_idk   = (const float*)d_in[13];
  const float* b_idk   = (const float*)d_in[14];
  const float* idk_A   = (const float*)d_in[15];
  const float* idk_B   = (const float*)d_in[16];
  const float* W_idv   = (const float*)d_in[17];
  const float* b_idv   = (const float*)d_in[18];
  const float* idv_A   = (const float*)d_in[19];
  const float* idv_B   = (const float*)d_in[20];

  float* ws   = (float*)d_ws;
  float* kb   = ws + OKb;
  float* vb   = ws + OVb;
  float* xo   = ws + OXO;
  float* qlow = ws + OQL;
  float* IDK  = ws + OIDK;
  float* IDV  = ws + OIDV;
  float* lowk = ws + OLK;
  float* lowv = ws + OLV;
  float* rd   = ws + ORD;
  float* plow = ws + OPL;
  float* coef = ws + OCF;
  unsigned short* qh   = (unsigned short*)(ws + OQH);
  unsigned short* kfh  = (unsigned short*)(ws + OKFH);
  unsigned short* vth  = (unsigned short*)(ws + OVTH);
  unsigned short* kmh  = (unsigned short*)(ws + OKMH);
  unsigned short* vmth = (unsigned short*)(ws + OVMTH);

  float* out  = (float*)d_out;
  float* kmid = out + KMID_OFF;
  float* vmid = out + VMID_OFF;

  // bf16 staging of memory inputs (independent of GEMMs)
  cast_k<<<1920, 256, 0, stream>>>(mem_k, kfh);                         // rows 0..1279
  transpose_bf16<<<dim3(160, 48), 256, 0, stream>>>(mem_v, vth,
      1280, 81920, 163840, 2560, 0);                                    // cols 0..1279

  // LoRA "down" projections
  dot_small<<<1280, 256, 0, stream>>>(x, qkv_A, qlow, 24);
  dot_small<<<256,  256, 0, stream>>>(id_tot, idk_A, lowk, 8);
  dot_small<<<256,  256, 0, stream>>>(id_tot, idv_A, lowv, 8);

  // QKV projection: q->qh bf16 (pre-scaled), k->kb fp32 + kfh bf16, v->vb
  gemm_ep<<<dim3(36, 80), 256, 0, stream>>>(x, W_qkv, b_qkv, qlow, qkv_B, nullptr,
                                            5120, 2304, 768, 0, qh, kb, vb, kfh);
  // ID_V
  gemm_ep<<<dim3(12, 16), 256, 0, stream>>>(id_tot, W_idv, b_idv, lowv, idv_B, IDV,
                                            1024, 768, 768, 1, nullptr, nullptr, nullptr, nullptr);
  // 1 + tanh(ID_K)
  idk_kernel<<<256, 256, 0, stream>>>(id_tot, W_idk, b_idk, lowk, idk_B, IDK);
  // k_m_id / v_m_id outputs; vb rows 0-255 updated; kmh bf16
  fixup_kernel<<<3072, 256, 0, stream>>>(kb, vb, IDK, IDV, kmid, vmid, kmh);

  // V^T bf16: vb (post-fixup) -> vth cols 1280..2559; vb rows 0..255 -> vmth
  transpose_bf16<<<dim3(160, 48), 256, 0, stream>>>(vb, vth,
      1280, 81920, 163840, 2560, 1280);
  transpose_bf16<<<dim3(32, 48), 256, 0, stream>>>(vb, vmth,
      256, 81920, 16384, 256, 0);

  // attention: memory tokens (256 keys, top-128), sequence tokens (2560, top-640)
  attn_mfma<256><<<3072, 256, 0, stream>>>(qh, kmh, vmth, 128, 0, 256, xo, 0);
  attn_mfma<2560><<<12288, 256, 0, stream>>>(qh, kfh, vth, 640, 256, 1024, xo, 256);

  // routed output projection
  dot_small<<<1280, 256, 0, stream>>>(xo, route_W, rd, 4);
  dot_small<<<1280, 256, 0, stream>>>(xo, proj_A, plow, 32);
  coef_kernel<<<20, 256, 0, stream>>>(rd, plow, coef);
  gemm_ep<<<dim3(12, 80), 256, 0, stream>>>(xo, W_proj, b_proj, coef, proj_B, out,
                                            5120, 768, 768, 2, nullptr, nullptr, nullptr, nullptr);
}

// Round 5
// 1555.677 us; speedup vs baseline: 2.6055x; 1.3663x over previous
//
#include <hip/hip_runtime.h>
#include <cstddef>

// ---------------- problem constants ----------------
#define Bq    4
#define Hh    12
#define Dd    64
#define NNtok 1280
#define DIMc  768
#define KAUG  800      // 768 + 32 augmented-K for fused LoRA

typedef __attribute__((ext_vector_type(8))) short bf16x8;
typedef __attribute__((ext_vector_type(4))) float f32x4;

// workspace offsets (floats)
static const size_t OVb   = 0;                   // vb fp32 (B,H,1280,64); rows 0-255 -> v_add_id
static const size_t OXO   = 3932160;             // xo fp32 (B,1280,768)
static const size_t OQL   = 7864320;             // qkv low (5120,24)
static const size_t OIDK  = 7987200;             // 1+tanh(ID_K) (1024,12)
static const size_t OIDV  = 7999488;             // ID_V (1024,768)
static const size_t OLK   = 8785920;             // id_lowk (1024,8)
static const size_t OLV   = 8794112;             // id_lowv (1024,8)
static const size_t ORD   = 8802304;             // route dots (5120,4)
static const size_t OPL   = 8822784;             // proj low (5120,32)
static const size_t OCF   = 8986624;             // coef (5120,32)
static const size_t OQH   = 9150464;             // qh bf16 (B,H,1280,64)
static const size_t OKFH  = 11116544;            // kfh bf16 (B,H,2560,64) [mem_k|k]
static const size_t OVTH  = 15048704;            // vth bf16 (B,H,64,2560)
static const size_t OKMH  = 18980864;            // kmh bf16 (B,H,256,64)
static const size_t OVMTH = 19374080;            // vmth bf16 (B,H,64,256)
static const size_t OAa   = 19767296;            // A_aug bf16 (5120,800)  (shared qkv/proj)
static const size_t OWa   = 21815296;            // W_aug bf16 (2304,800)  (shared qkv/proj)
// end 22736896 floats = 90.9 MB

// d_out offsets (floats)
static const size_t KMID_OFF = 3932160;
static const size_t VMID_OFF = 4718592;

__device__ __forceinline__ unsigned int f2k16(unsigned int h) {
  return (h & 0x8000u) ? ((~h) & 0xFFFFu) : (h | 0x8000u);  // monotone bf16->u16
}
__device__ __forceinline__ unsigned int pk_bf16(float a, float b) {  // RNE pack
  unsigned int ua = __float_as_uint(a), ub = __float_as_uint(b);
  ua += 0x7fffu + ((ua >> 16) & 1u);
  ub += 0x7fffu + ((ub >> 16) & 1u);
  return (ua >> 16) | (ub & 0xffff0000u);
}
__device__ __forceinline__ unsigned short bf16_1(float a) {
  unsigned int ua = __float_as_uint(a);
  ua += 0x7fffu + ((ua >> 16) & 1u);
  return (unsigned short)(ua >> 16);
}
__device__ __forceinline__ float bf2f(unsigned int h) {
  return __uint_as_float(h << 16);
}

// ---------------- small row-dot kernel ----------------
__global__ __launch_bounds__(256) void dot_small(
    const float* __restrict__ src, const float* __restrict__ mat,
    float* __restrict__ dst, int nout)
{
  int wv = threadIdx.x >> 6, ln = threadIdx.x & 63;
  size_t row = (size_t)blockIdx.x * 4 + wv;
  const float* s = src + row * DIMc;
  for (int o = 0; o < nout; ++o) {
    float p = 0.f;
    const float* m = mat + (size_t)o * DIMc;
    for (int c = ln; c < DIMc; c += 64) p += s[c] * m[c];
    for (int off = 32; off; off >>= 1) p += __shfl_xor(p, off, 64);
    if (ln == 0) dst[row * nout + o] = p;
  }
}

// ---------------- ID_K: 1+tanh(lora1(...)) ----------------
__global__ __launch_bounds__(256) void idk_kernel(
    const float* __restrict__ id_tot, const float* __restrict__ W_idk,
    const float* __restrict__ b_idk, const float* __restrict__ lowk,
    const float* __restrict__ idk_B, float* __restrict__ IDK)
{
  int wv = threadIdx.x >> 6, ln = threadIdx.x & 63;
  size_t row = (size_t)blockIdx.x * 4 + wv;
  const float* s = id_tot + row * DIMc;
  for (int h = 0; h < Hh; ++h) {
    float p = 0.f;
    const float* m = W_idk + (size_t)h * DIMc;
    for (int c = ln; c < DIMc; c += 64) p += s[c] * m[c];
    for (int off = 32; off; off >>= 1) p += __shfl_xor(p, off, 64);
    if (ln == 0) {
      float lo = 0.f;
      for (int r = 0; r < 8; ++r) lo += lowk[row * 8 + r] * idk_B[h * 8 + r];
      IDK[row * Hh + h] = 1.f + tanhf(p + b_idk[h] + lo * 0.125f);
    }
  }
}

// ---------------- fixup: kmid holds raw k; multiply by IDK in place; v add IDV ----------------
__global__ __launch_bounds__(256) void fixup_kernel(
    float* __restrict__ vb, const float* __restrict__ IDK,
    const float* __restrict__ IDV, float* __restrict__ kmid,
    float* __restrict__ vmid, unsigned short* __restrict__ kmh)
{
  int e = blockIdx.x * 256 + threadIdx.x;   // flat (b,h,tt,d), tt<256
  int d  = e & 63;
  int r1 = e >> 6;
  int tt = r1 & 255;
  int r2 = r1 >> 8;
  int h  = r2 % Hh;
  int b  = r2 / Hh;
  float km = kmid[e] * IDK[(size_t)(b * 256 + tt) * Hh + h];
  kmid[e] = km;
  kmh[e] = bf16_1(km);
  size_t src = ((size_t)(b * Hh + h) * NNtok + tt) * Dd + d;
  float vv = vb[src] + IDV[(size_t)(b * 256 + tt) * DIMc + h * 64 + d];
  vb[src] = vv;
  vmid[e] = vv;
}

// ---------------- cast mem_k -> kfh rows 0..1279 (bf16) ----------------
__global__ __launch_bounds__(256) void cast_k(
    const float* __restrict__ mem_k, unsigned short* __restrict__ kfh)
{
  size_t idx = ((size_t)blockIdx.x * 256 + threadIdx.x) * 8;
  int bh = (int)(idx / 81920);
  int r  = (int)(idx % 81920);
  const float* s = mem_k + (size_t)bh * 81920 + r;
  float4 a = *(const float4*)s;
  float4 b = *(const float4*)(s + 4);
  unsigned int* dp = (unsigned int*)(kfh + (size_t)bh * 163840 + r);
  dp[0] = pk_bf16(a.x, a.y); dp[1] = pk_bf16(a.z, a.w);
  dp[2] = pk_bf16(b.x, b.y); dp[3] = pk_bf16(b.z, b.w);
}

// ---------------- LDS-tiled transpose: fp32 (rows,64) -> bf16 (64, cols) ----------------
__global__ __launch_bounds__(256) void transpose_tile(
    const float* __restrict__ src, unsigned short* __restrict__ dst,
    int srcBh, int dstBh, int dstCols, int colOfs)
{
  __shared__ float tl[64][65];
  int bh = blockIdx.y;
  int t0 = blockIdx.x * 64;
  int t = threadIdx.x;
  const float* sb = src + (size_t)bh * srcBh + (size_t)t0 * 64;
#pragma unroll
  for (int p = 0; p < 4; ++p) {
    int flat = p * 256 + t;
    int r = flat >> 4, c4 = (flat & 15) << 2;
    float4 v = *(const float4*)(sb + r * 64 + c4);
    tl[r][c4 + 0] = v.x; tl[r][c4 + 1] = v.y;
    tl[r][c4 + 2] = v.z; tl[r][c4 + 3] = v.w;
  }
  __syncthreads();
  unsigned short* db = dst + (size_t)bh * dstBh + colOfs + t0;
#pragma unroll
  for (int p = 0; p < 8; ++p) {
    int flat = p * 256 + t;
    int d = flat >> 5, u = flat & 31;
    *(unsigned int*)(db + (size_t)d * dstCols + 2 * u) = pk_bf16(tl[2 * u][d], tl[2 * u + 1][d]);
  }
}

// ---------------- route softmax * proj-low * (1/R) -> coef ----------------
__global__ __launch_bounds__(256) void coef_kernel(
    const float* __restrict__ rd, const float* __restrict__ plow,
    float* __restrict__ coef)
{
  int n = blockIdx.x * 256 + threadIdx.x;
  if (n >= Bq * NNtok) return;
  float l0 = rd[n * 4 + 0], l1 = rd[n * 4 + 1], l2 = rd[n * 4 + 2], l3 = rd[n * 4 + 3];
  float m = fmaxf(fmaxf(l0, l1), fmaxf(l2, l3));
  float e0 = expf(l0 - m), e1 = expf(l1 - m), e2 = expf(l2 - m), e3 = expf(l3 - m);
  float inv = 1.f / (e0 + e1 + e2 + e3);
  float rt[4] = { e0 * inv, e1 * inv, e2 * inv, e3 * inv };
  for (int e = 0; e < 4; ++e)
    for (int r = 0; r < 8; ++r)
      coef[(size_t)n * 32 + e * 8 + r] = rt[e] * plow[(size_t)n * 32 + e * 8 + r] * 0.125f;
}

// ---------------- pack A_aug: [main(768) | extra(extraN) | 0pad] -> bf16 (M,800) ----------------
__global__ __launch_bounds__(256) void cast_pack(
    const float* __restrict__ mainp, const float* __restrict__ extra,
    unsigned short* __restrict__ dst, int extraN)
{
  int idx = blockIdx.x * 256 + threadIdx.x;    // 5120*100 groups of 8
  int row = idx / 100, c8 = (idx % 100) * 8;
  unsigned int w[4];
  if (c8 < 768) {
    const float* s = mainp + (size_t)row * 768 + c8;
    float4 a = *(const float4*)s;
    float4 b = *(const float4*)(s + 4);
    w[0] = pk_bf16(a.x, a.y); w[1] = pk_bf16(a.z, a.w);
    w[2] = pk_bf16(b.x, b.y); w[3] = pk_bf16(b.z, b.w);
  } else {
    float v[8];
#pragma unroll
    for (int j = 0; j < 8; ++j) {
      int e = c8 - 768 + j;
      v[j] = (e < extraN) ? extra[(size_t)row * extraN + e] : 0.f;
    }
    w[0] = pk_bf16(v[0], v[1]); w[1] = pk_bf16(v[2], v[3]);
    w[2] = pk_bf16(v[4], v[5]); w[3] = pk_bf16(v[6], v[7]);
  }
  *(uint4*)(dst + (size_t)row * KAUG + c8) = make_uint4(w[0], w[1], w[2], w[3]);
}

// ---------------- W_aug builders ----------------
__global__ __launch_bounds__(256) void cast_w_qkv(
    const float* __restrict__ W, const float* __restrict__ qkvB,
    unsigned short* __restrict__ dst)
{
  int idx = blockIdx.x * 256 + threadIdx.x;    // 2304*400 uint pairs
  int row = idx / 400, cp = idx % 400, c = cp * 2;
  float a, b;
  if (c < 768) {
    a = W[(size_t)row * 768 + c]; b = W[(size_t)row * 768 + c + 1];
  } else {
    int g = row / 768, jj = row % 768;
    int e0 = c - 768, e1 = e0 + 1;
    a = (e0 < 24 && (e0 >> 3) == g) ? qkvB[(size_t)g * 6144 + jj * 8 + (e0 & 7)] * 0.125f : 0.f;
    b = (e1 < 24 && (e1 >> 3) == g) ? qkvB[(size_t)g * 6144 + jj * 8 + (e1 & 7)] * 0.125f : 0.f;
  }
  *(unsigned int*)(dst + (size_t)row * KAUG + c) = pk_bf16(a, b);
}

__global__ __launch_bounds__(256) void cast_w_proj(
    const float* __restrict__ W, const float* __restrict__ projB,
    unsigned short* __restrict__ dst)
{
  int idx = blockIdx.x * 256 + threadIdx.x;    // 768*400
  int row = idx / 400, cp = idx % 400, c = cp * 2;
  float a, b;
  if (c < 768) {
    a = W[(size_t)row * 768 + c]; b = W[(size_t)row * 768 + c + 1];
  } else {
    int e0 = c - 768, e1 = e0 + 1;
    a = projB[(size_t)(e0 >> 3) * 6144 + row * 8 + (e0 & 7)];
    b = projB[(size_t)(e1 >> 3) * 6144 + row * 8 + (e1 & 7)];
  }
  *(unsigned int*)(dst + (size_t)row * KAUG + c) = pk_bf16(a, b);
}

// ---------------- MFMA GEMM: C = A_aug @ W_aug^T + bias, K=800 ----------------
// mode 0: qkv scatter (q->qh*0.125, k->kfh + kmid(tt<256), v->vb); mode 2: dst row-major
__global__ __launch_bounds__(256) void gemm_mfma(
    const unsigned short* __restrict__ A, const unsigned short* __restrict__ W,
    const float* __restrict__ bias, int mode, float* __restrict__ dst,
    unsigned short* __restrict__ qh, float* __restrict__ kmid,
    float* __restrict__ vb, unsigned short* __restrict__ kfh)
{
  const int t = threadIdx.x, w = t >> 6, l = t & 63;
  const int m = l & 15, quad = l >> 4;
  const int bm = blockIdx.y * 128 + (w >> 1) * 64;
  const int bn = blockIdx.x * 128 + (w & 1) * 64;
  f32x4 acc[4][4] = {};
  const unsigned short* Ab = A + (size_t)(bm + m) * KAUG;
  const unsigned short* Wb = W + (size_t)(bn + m) * KAUG;
  for (int kk = 0; kk < KAUG; kk += 32) {
    bf16x8 af[4], bf[4];
#pragma unroll
    for (int i = 0; i < 4; ++i) af[i] = *(const bf16x8*)(Ab + (size_t)i * 16 * KAUG + kk + quad * 8);
#pragma unroll
    for (int j = 0; j < 4; ++j) bf[j] = *(const bf16x8*)(Wb + (size_t)j * 16 * KAUG + kk + quad * 8);
#pragma unroll
    for (int i = 0; i < 4; ++i)
#pragma unroll
      for (int j = 0; j < 4; ++j)
        acc[i][j] = __builtin_amdgcn_mfma_f32_16x16x32_bf16(af[i], bf[j], acc[i][j], 0, 0, 0);
  }

  float bj[4];
#pragma unroll
  for (int j = 0; j < 4; ++j) bj[j] = bias[bn + j * 16 + m];

  if (mode == 2) {
#pragma unroll
    for (int i = 0; i < 4; ++i)
#pragma unroll
      for (int r = 0; r < 4; ++r) {
        int row = bm + i * 16 + quad * 4 + r;
#pragma unroll
        for (int j = 0; j < 4; ++j)
          dst[(size_t)row * 768 + bn + j * 16 + m] = acc[i][j][r] + bj[j];
      }
    return;
  }
  // mode 0
  int g = (blockIdx.x * 128) / DIMc;           // uniform per block
#pragma unroll
  for (int j = 0; j < 4; ++j) {
    int col = bn + j * 16 + m;
    int jj = col - g * DIMc, hh = jj >> 6, d = jj & 63;
#pragma unroll
    for (int i = 0; i < 4; ++i)
#pragma unroll
      for (int r = 0; r < 4; ++r) {
        int row = bm + i * 16 + quad * 4 + r;
        int bb = row / NNtok, tt = row % NNtok;
        float v = acc[i][j][r] + bj[j];
        if (g == 0) {
          qh[((size_t)(bb * Hh + hh) * NNtok + tt) * Dd + d] = bf16_1(v * 0.125f);
        } else if (g == 1) {
          kfh[((size_t)(bb * Hh + hh) * 2560 + 1280 + tt) * Dd + d] = bf16_1(v);
          if (tt < 256) kmid[((size_t)(bb * Hh + hh) * 256 + tt) * Dd + d] = v;
        } else {
          vb[((size_t)(bb * Hh + hh) * NNtok + tt) * Dd + d] = v;
        }
      }
  }
}

// ---------------- fp32 GEMM for ID_V (small) ----------------
__global__ __launch_bounds__(256) void gemm_idv(
    const float* __restrict__ A, const float* __restrict__ W,
    const float* __restrict__ bias, const float* __restrict__ low,
    const float* __restrict__ Bl, float* __restrict__ dst)
{
  __shared__ alignas(16) float As[16][68];
  __shared__ alignas(16) float Bs[16][68];
  const int t  = threadIdx.x;
  const int tx = t & 15, ty = t >> 4;
  const int bn = blockIdx.x * 64, bm = blockIdx.y * 64;
  const int am = t >> 2, ak = (t & 3) << 2;
  float acc[4][4] = {};
  for (int k0 = 0; k0 < 768; k0 += 16) {
    float4 av = *(const float4*)(A + (size_t)(bm + am) * 768 + k0 + ak);
    float4 bv = *(const float4*)(W + (size_t)(bn + am) * 768 + k0 + ak);
    As[ak + 0][am] = av.x; As[ak + 1][am] = av.y; As[ak + 2][am] = av.z; As[ak + 3][am] = av.w;
    Bs[ak + 0][am] = bv.x; Bs[ak + 1][am] = bv.y; Bs[ak + 2][am] = bv.z; Bs[ak + 3][am] = bv.w;
    __syncthreads();
#pragma unroll
    for (int kk = 0; kk < 16; ++kk) {
      float4 a4 = *(const float4*)&As[kk][ty << 2];
      float4 b4 = *(const float4*)&Bs[kk][tx << 2];
      float ar[4] = { a4.x, a4.y, a4.z, a4.w };
      float br[4] = { b4.x, b4.y, b4.z, b4.w };
#pragma unroll
      for (int i = 0; i < 4; ++i)
#pragma unroll
        for (int j = 0; j < 4; ++j) acc[i][j] += ar[i] * br[j];
    }
    __syncthreads();
  }
#pragma unroll
  for (int i = 0; i < 4; ++i) {
    int mg = bm + (ty << 2) + i;
#pragma unroll
    for (int j = 0; j < 4; ++j) {
      int col = bn + (tx << 2) + j;
      float v = acc[i][j] + bias[col];
      float lo = 0.f;
#pragma unroll
      for (int r = 0; r < 8; ++r) lo += low[(size_t)mg * 8 + r] * Bl[(size_t)col * 8 + r];
      dst[(size_t)mg * 768 + col] = v + lo * 0.125f;
    }
  }
}

// ---------------- radix helper: select bin from per-wave 256-bin hist ----------------
__device__ __forceinline__ void radix_sel(
    unsigned int* hist, int l, int& kk, int& ceq, unsigned int& bin)
{
  unsigned int h0 = hist[4 * l + 0], h1 = hist[4 * l + 1],
               h2 = hist[4 * l + 2], h3 = hist[4 * l + 3];
  unsigned int s3 = h3, s2 = h2 + s3, s1 = h1 + s2, s0 = h0 + s1;
  unsigned int tsum = s0;
#pragma unroll
  for (int off = 1; off < 64; off <<= 1) {
    unsigned int other = __shfl(tsum, l + off, 64);
    tsum += (l + off < 64) ? other : 0u;
  }
  unsigned int T = tsum - s0;   // suffix over lanes > l
  unsigned int Sv0 = T + s0, Sv1 = T + s1, Sv2 = T + s2, Sv3 = T + s3, Sv4 = T;
  int fb = -1, fkk = 0, fceq = 0;
  unsigned int ukk = (unsigned int)kk;
  if (Sv0 >= ukk && Sv1 < ukk) { fb = 4 * l + 0; fkk = (int)(ukk - Sv1); fceq = (int)(Sv0 - Sv1); }
  if (Sv1 >= ukk && Sv2 < ukk) { fb = 4 * l + 1; fkk = (int)(ukk - Sv2); fceq = (int)(Sv1 - Sv2); }
  if (Sv2 >= ukk && Sv3 < ukk) { fb = 4 * l + 2; fkk = (int)(ukk - Sv3); fceq = (int)(Sv2 - Sv3); }
  if (Sv3 >= ukk && Sv4 < ukk) { fb = 4 * l + 3; fkk = (int)(ukk - Sv4); fceq = (int)(Sv3 - Sv4); }
  unsigned long long mb = __ballot(fb >= 0);
  int src = __ffsll(mb) - 1;
  bin = (unsigned int)__shfl(fb, src, 64);
  kk  = __shfl(fkk, src, 64);
  ceq = __shfl(fceq, src, 64);
}

// ---------------- MFMA top-k attention, bf16 scores, 2-pass radix ----------------
template<int NK>
__global__ __launch_bounds__(256, 6) void attn_mfma2(
    const unsigned short* __restrict__ qh,   // (bh,1280,64) bf16
    const unsigned short* __restrict__ kf,   // (bh,NK,64)   bf16
    const unsigned short* __restrict__ vt,   // (bh,64,NK)   bf16 (V^T)
    int TK, int qrow0, int rows_per_bh,
    float* __restrict__ xo, int nofs)
{
  __shared__ alignas(16) unsigned short sc16[4][NK];  // bf16 scores -> bf16 weights
  __shared__ unsigned int hist4[4][256];
  __shared__ float wavemax[4][4];                     // [wave][row]
  __shared__ float rowinv[4];

  const int t = threadIdx.x, w = t >> 6, l = t & 63;
  const int bpb = rows_per_bh >> 2;
  const int bh = blockIdx.x / bpb, rb = blockIdx.x % bpb;
  const int b = bh / Hh, h = bh % Hh;
  const int qbase = qrow0 + rb * 4;
  const int m = l & 15, quad = l >> 4;

  // ---- Phase A: QK^T via MFMA (A rows 0-3 = q), running max, bf16 store ----
  bf16x8 aq0 = {0,0,0,0,0,0,0,0}, aq1 = {0,0,0,0,0,0,0,0};
  if (m < 4) {
    const unsigned short* qp = qh + ((size_t)bh * NNtok + qbase + m) * Dd + quad * 8;
    aq0 = *(const bf16x8*)qp;
    aq1 = *(const bf16x8*)(qp + 32);
  }
  float mx[4] = { -3.0e38f, -3.0e38f, -3.0e38f, -3.0e38f };
  const unsigned short* kbase = kf + (size_t)bh * NK * Dd;
  for (int n0 = w * 16; n0 < NK; n0 += 64) {
    const unsigned short* kp = kbase + (size_t)(n0 + m) * Dd + quad * 8;
    bf16x8 b0 = *(const bf16x8*)kp;
    bf16x8 b1 = *(const bf16x8*)(kp + 32);
    f32x4 acc = {0.f, 0.f, 0.f, 0.f};
    acc = __builtin_amdgcn_mfma_f32_16x16x32_bf16(aq0, b0, acc, 0, 0, 0);
    acc = __builtin_amdgcn_mfma_f32_16x16x32_bf16(aq1, b1, acc, 0, 0, 0);
    if (l < 16) {
#pragma unroll
      for (int r = 0; r < 4; ++r) {
        float v = acc[r];
        mx[r] = fmaxf(mx[r], v);
        sc16[r][n0 + l] = bf16_1(v);
      }
    }
  }
#pragma unroll
  for (int off = 1; off < 16; off <<= 1)
#pragma unroll
    for (int r = 0; r < 4; ++r) mx[r] = fmaxf(mx[r], __shfl_xor(mx[r], off, 64));
  if (l == 0) {
#pragma unroll
    for (int r = 0; r < 4; ++r) wavemax[w][r] = mx[r];
  }
  __syncthreads();

  // ---- Phase B: per-wave 2-pass radix select on 16-bit keys (wave w = row w) ----
  unsigned short* s = sc16[w];
  unsigned int* sp = (unsigned int*)s;
  unsigned int* hist = hist4[w];
  constexpr int NW = NK / 2;
  int kk = TK, ceq = 0;
  unsigned int b1bin, b2bin;
  // pass 1: bits [15:8]
#pragma unroll
  for (int z = 0; z < 4; ++z) hist[l + z * 64] = 0u;
  for (int i = l; i < NW; i += 64) {
    unsigned int pr = sp[i];
    atomicAdd(&hist[f2k16(pr & 0xffffu) >> 8], 1u);
    atomicAdd(&hist[f2k16(pr >> 16) >> 8], 1u);
  }
  radix_sel(hist, l, kk, ceq, b1bin);
  // pass 2: bits [7:0] among prefix matches
#pragma unroll
  for (int z = 0; z < 4; ++z) hist[l + z * 64] = 0u;
  for (int i = l; i < NW; i += 64) {
    unsigned int pr = sp[i];
    unsigned int k0 = f2k16(pr & 0xffffu), k1 = f2k16(pr >> 16);
    if ((k0 >> 8) == b1bin) atomicAdd(&hist[k0 & 255u], 1u);
    if ((k1 >> 8) == b1bin) atomicAdd(&hist[k1 & 255u], 1u);
  }
  radix_sel(hist, l, kk, ceq, b2bin);
  const unsigned int Tkey = (b1bin << 8) | b2bin;
  const int need = kk;
  if (need < ceq) {    // ties at threshold: keep lowest indices
    int seen = 0;
    for (int i0 = 0; i0 < NW && seen < ceq; i0 += 64) {
      int i = i0 + l;
      unsigned int pr = sp[i];
      bool eq0 = (f2k16(pr & 0xffffu) == Tkey);
      bool eq1 = (f2k16(pr >> 16) == Tkey);
      unsigned long long m0 = __ballot(eq0), m1 = __ballot(eq1);
      unsigned long long below = (1ull << l) - 1ull;
      int before = __popcll(m0 & below) + __popcll(m1 & below);
      if (eq0 && (seen + before) >= need) s[2 * i] = 0xFF80u;          // bf16 -inf
      if (eq1 && (seen + before + (eq0 ? 1 : 0)) >= need) s[2 * i + 1] = 0xFF80u;
      seen += __popcll(m0) + __popcll(m1);
    }
  }

  // ---- Phase C: exp over selected, bf16 weights in place ----
  {
    float rm = fmaxf(fmaxf(wavemax[0][w], wavemax[1][w]),
                     fmaxf(wavemax[2][w], wavemax[3][w]));
    float sum = 0.f;
    for (int i = l; i < NW; i += 64) {
      unsigned int pr = sp[i];
      unsigned int h0 = pr & 0xffffu, h1 = pr >> 16;
      float w0 = (f2k16(h0) >= Tkey) ? __expf(bf2f(h0) - rm) : 0.f;
      float w1 = (f2k16(h1) >= Tkey) ? __expf(bf2f(h1) - rm) : 0.f;
      sp[i] = pk_bf16(w0, w1);
      sum += w0 + w1;
    }
#pragma unroll
    for (int off = 32; off; off >>= 1) sum += __shfl_xor(sum, off, 64);
    if (l == 0) rowinv[w] = 1.f / sum;
  }
  __syncthreads();

  // ---- Phase D: PV via MFMA; wave w -> dims [16w,16w+16) ----
  const unsigned short* vrow = vt + (size_t)bh * Dd * NK + (size_t)(w * 16 + m) * NK;
  f32x4 o = {0.f, 0.f, 0.f, 0.f};
  for (int c = 0; c < NK / 32; ++c) {
    bf16x8 af = {0,0,0,0,0,0,0,0};
    if (m < 4) af = *(const bf16x8*)&sc16[m][c * 32 + quad * 8];
    bf16x8 bf = *(const bf16x8*)(vrow + c * 32 + quad * 8);
    o = __builtin_amdgcn_mfma_f32_16x16x32_bf16(af, bf, o, 0, 0, 0);
  }
  if (l < 16) {
#pragma unroll
    for (int r = 0; r < 4; ++r) {
      int n = nofs + rb * 4 + r;
      xo[((size_t)b * NNtok + n) * DIMc + h * 64 + w * 16 + l] = o[r] * rowinv[r];
    }
  }
}

// ---------------- host ----------------
extern "C" void kernel_launch(void* const* d_in, const int* in_sizes, int n_in,
                              void* d_out, int out_size, void* d_ws, size_t ws_size,
                              hipStream_t stream)
{
  const float* x       = (const float*)d_in[0];
  const float* id_tot  = (const float*)d_in[1];
  const float* mem_k   = (const float*)d_in[2];
  const float* mem_v   = (const float*)d_in[3];
  const float* W_qkv   = (const float*)d_in[4];
  const float* b_qkv   = (const float*)d_in[5];
  const float* qkv_A   = (const float*)d_in[6];
  const float* qkv_B   = (const float*)d_in[7];
  const float* W_proj  = (const float*)d_in[8];
  const float* b_proj  = (const float*)d_in[9];
  const float* route_W = (const float*)d_in[10];
  const float* proj_A  = (const float*)d_in[11];
  const float* proj_B  = (const float*)d_in[12];
  const float* W_idk   = (const float*)d_in[13];
  const float* b_idk   = (const float*)d_in[14];
  const float* idk_A   = (const float*)d_in[15];
  const float* idk_B   = (const float*)d_in[16];
  const float* W_idv   = (const float*)d_in[17];
  const float* b_idv   = (const float*)d_in[18];
  const float* idv_A   = (const float*)d_in[19];
  const float* idv_B   = (const float*)d_in[20];

  float* ws   = (float*)d_ws;
  float* vb   = ws + OVb;
  float* xo   = ws + OXO;
  float* qlow = ws + OQL;
  float* IDK  = ws + OIDK;
  float* IDV  = ws + OIDV;
  float* lowk = ws + OLK;
  float* lowv = ws + OLV;
  float* rd   = ws + ORD;
  float* plow = ws + OPL;
  float* coef = ws + OCF;
  unsigned short* qh   = (unsigned short*)(ws + OQH);
  unsigned short* kfh  = (unsigned short*)(ws + OKFH);
  unsigned short* vth  = (unsigned short*)(ws + OVTH);
  unsigned short* kmh  = (unsigned short*)(ws + OKMH);
  unsigned short* vmth = (unsigned short*)(ws + OVMTH);
  unsigned short* Aa   = (unsigned short*)(ws + OAa);
  unsigned short* Wa   = (unsigned short*)(ws + OWa);

  float* out  = (float*)d_out;
  float* kmid = out + KMID_OFF;
  float* vmid = out + VMID_OFF;

  // bf16 staging of memory inputs
  cast_k<<<1920, 256, 0, stream>>>(mem_k, kfh);
  transpose_tile<<<dim3(20, 48), 256, 0, stream>>>(mem_v, vth, 81920, 163840, 2560, 0);

  // LoRA downs
  dot_small<<<1280, 256, 0, stream>>>(x, qkv_A, qlow, 24);
  dot_small<<<256,  256, 0, stream>>>(id_tot, idk_A, lowk, 8);
  dot_small<<<256,  256, 0, stream>>>(id_tot, idv_A, lowv, 8);

  // QKV via MFMA with augmented K (fused LoRA)
  cast_w_qkv<<<3600, 256, 0, stream>>>(W_qkv, qkv_B, Wa);
  cast_pack<<<2000, 256, 0, stream>>>(x, qlow, Aa, 24);
  gemm_mfma<<<dim3(18, 40), 256, 0, stream>>>(Aa, Wa, b_qkv, 0, nullptr,
                                              qh, kmid, vb, kfh);
  // ID_V (fp32), ID_K
  gemm_idv<<<dim3(12, 16), 256, 0, stream>>>(id_tot, W_idv, b_idv, lowv, idv_B, IDV);
  idk_kernel<<<256, 256, 0, stream>>>(id_tot, W_idk, b_idk, lowk, idk_B, IDK);
  // outputs k_m_id / v_m_id; vb rows 0-255 updated in place
  fixup_kernel<<<3072, 256, 0, stream>>>(vb, IDK, IDV, kmid, vmid, kmh);

  // V^T bf16 staging (post-fixup)
  transpose_tile<<<dim3(20, 48), 256, 0, stream>>>(vb, vth, 81920, 163840, 2560, 1280);
  transpose_tile<<<dim3(4, 48), 256, 0, stream>>>(vb, vmth, 81920, 16384, 256, 0);

  // attention
  attn_mfma2<256><<<3072, 256, 0, stream>>>(qh, kmh, vmth, 128, 0, 256, xo, 0);
  attn_mfma2<2560><<<12288, 256, 0, stream>>>(qh, kfh, vth, 640, 256, 1024, xo, 256);

  // routed output projection via MFMA with augmented K
  dot_small<<<1280, 256, 0, stream>>>(xo, route_W, rd, 4);
  dot_small<<<1280, 256, 0, stream>>>(xo, proj_A, plow, 32);
  coef_kernel<<<20, 256, 0, stream>>>(rd, plow, coef);
  cast_w_proj<<<1200, 256, 0, stream>>>(W_proj, proj_B, Wa);
  cast_pack<<<2000, 256, 0, stream>>>(xo, coef, Aa, 32);
  gemm_mfma<<<dim3(6, 40), 256, 0, stream>>>(Aa, Wa, b_proj, 2, out,
                                             nullptr, nullptr, nullptr, nullptr);
}

// Round 6
// 1382.638 us; speedup vs baseline: 2.9315x; 1.1252x over previous
//
#include <hip/hip_runtime.h>
#include <cstddef>

// ---------------- problem constants ----------------
#define Bq    4
#define Hh    12
#define Dd    64
#define NNtok 1280
#define DIMc  768
#define KAUG  800      // 768 + 32 augmented-K for fused LoRA
#define NBH   48       // Bq*Hh

typedef __attribute__((ext_vector_type(8))) short bf16x8;
typedef __attribute__((ext_vector_type(4))) float f32x4;

// workspace offsets (floats)
static const size_t OVb   = 0;                   // vb fp32 (B,H,1280,64); rows 0-255 -> v_add_id
static const size_t OXO   = 3932160;             // xo fp32 (B,1280,768)
static const size_t OQL   = 7864320;             // qkv low (5120,24)
static const size_t OIDK  = 7987200;             // 1+tanh(ID_K) (1024,12)
static const size_t OIDV  = 7999488;             // ID_V (1024,768)
static const size_t OLK   = 8785920;             // id_lowk (1024,8)
static const size_t OLV   = 8794112;             // id_lowv (1024,8)
static const size_t ORD   = 8802304;             // route dots (5120,4)
static const size_t OPL   = 8822784;             // proj low (5120,32)
static const size_t OQH   = 8986624;             // qh bf16 (B,H,1280,64)
static const size_t OKFH  = 10952704;            // kfh bf16 (B,H,2560,64) [mem_k|k]
static const size_t OVTH  = 14884864;            // vth bf16 (B,H,64,2560)
static const size_t OKMH  = 18817024;            // kmh bf16 (B,H,256,64)
static const size_t OVMTH = 19210240;            // vmth bf16 (B,H,64,256)
static const size_t OAa   = 19603456;            // A_aug bf16 (5120,800)
static const size_t OWa   = 21651456;            // W_aug qkv bf16 (2304,800)
static const size_t OWa2  = 22573056;            // W_aug proj bf16 (768,800)
// end 22880256 floats = 91.5 MB

// d_out offsets (floats)
static const size_t KMID_OFF = 3932160;
static const size_t VMID_OFF = 4718592;

__device__ __forceinline__ unsigned int pk_bf16(float a, float b) {  // RNE pack
  unsigned int ua = __float_as_uint(a), ub = __float_as_uint(b);
  ua += 0x7fffu + ((ua >> 16) & 1u);
  ub += 0x7fffu + ((ub >> 16) & 1u);
  return (ua >> 16) | (ub & 0xffff0000u);
}
__device__ __forceinline__ unsigned short bf16_1(float a) {
  unsigned int ua = __float_as_uint(a);
  ua += 0x7fffu + ((ua >> 16) & 1u);
  return (unsigned short)(ua >> 16);
}
__device__ __forceinline__ float bf2f(unsigned int h) {
  return __uint_as_float(h << 16);
}

// ---------------- prep: cast_k | transpose(mem_v) | cast_w_qkv | cast_w_proj ----------------
__global__ __launch_bounds__(256) void prep(
    const float* __restrict__ mem_k, const float* __restrict__ mem_v,
    const float* __restrict__ W_qkv, const float* __restrict__ qkvB,
    const float* __restrict__ W_proj, const float* __restrict__ projB,
    unsigned short* __restrict__ kfh, unsigned short* __restrict__ vth,
    unsigned short* __restrict__ Wa, unsigned short* __restrict__ Wa2)
{
  __shared__ float tl[64][65];
  const int blk = blockIdx.x, t = threadIdx.x;
  if (blk < 1920) {                       // cast mem_k -> kfh rows 0..1279
    size_t idx = ((size_t)blk * 256 + t) * 8;
    int bh = (int)(idx / 81920);
    int r  = (int)(idx % 81920);
    const float* s = mem_k + (size_t)bh * 81920 + r;
    float4 a = *(const float4*)s;
    float4 b = *(const float4*)(s + 4);
    unsigned int* dp = (unsigned int*)(kfh + (size_t)bh * 163840 + r);
    dp[0] = pk_bf16(a.x, a.y); dp[1] = pk_bf16(a.z, a.w);
    dp[2] = pk_bf16(b.x, b.y); dp[3] = pk_bf16(b.z, b.w);
  } else if (blk < 2880) {                // transpose mem_v -> vth cols 0..1279
    int b2 = blk - 1920;
    int bh = b2 / 20, t0 = (b2 % 20) * 64;
    const float* sb = mem_v + (size_t)bh * 81920 + (size_t)t0 * 64;
#pragma unroll
    for (int p = 0; p < 4; ++p) {
      int flat = p * 256 + t;
      int r = flat >> 4, c4 = (flat & 15) << 2;
      float4 v = *(const float4*)(sb + r * 64 + c4);
      tl[r][c4 + 0] = v.x; tl[r][c4 + 1] = v.y;
      tl[r][c4 + 2] = v.z; tl[r][c4 + 3] = v.w;
    }
    __syncthreads();
    unsigned short* db = vth + (size_t)bh * 163840 + t0;
#pragma unroll
    for (int p = 0; p < 8; ++p) {
      int flat = p * 256 + t;
      int d = flat >> 5, u = flat & 31;
      *(unsigned int*)(db + (size_t)d * 2560 + 2 * u) = pk_bf16(tl[2 * u][d], tl[2 * u + 1][d]);
    }
  } else if (blk < 6480) {                // W_aug qkv
    int idx = (blk - 2880) * 256 + t;     // 2304*400 uint pairs
    int row = idx / 400, c = (idx % 400) * 2;
    float a, b;
    if (c < 768) {
      a = W_qkv[(size_t)row * 768 + c]; b = W_qkv[(size_t)row * 768 + c + 1];
    } else {
      int g = row / 768, jj = row % 768;
      int e0 = c - 768, e1 = e0 + 1;
      a = (e0 < 24 && (e0 >> 3) == g) ? qkvB[(size_t)g * 6144 + jj * 8 + (e0 & 7)] * 0.125f : 0.f;
      b = (e1 < 24 && (e1 >> 3) == g) ? qkvB[(size_t)g * 6144 + jj * 8 + (e1 & 7)] * 0.125f : 0.f;
    }
    *(unsigned int*)(Wa + (size_t)row * KAUG + c) = pk_bf16(a, b);
  } else {                                // W_aug proj
    int idx = (blk - 6480) * 256 + t;     // 768*400
    int row = idx / 400, c = (idx % 400) * 2;
    float a, b;
    if (c < 768) {
      a = W_proj[(size_t)row * 768 + c]; b = W_proj[(size_t)row * 768 + c + 1];
    } else {
      int e0 = c - 768, e1 = e0 + 1;
      a = projB[(size_t)(e0 >> 3) * 6144 + row * 8 + (e0 & 7)];
      b = projB[(size_t)(e1 >> 3) * 6144 + row * 8 + (e1 & 7)];
    }
    *(unsigned int*)(Wa2 + (size_t)row * KAUG + c) = pk_bf16(a, b);
  }
}

// ---------------- small row-dot kernel ----------------
__global__ __launch_bounds__(256) void dot_small(
    const float* __restrict__ src, const float* __restrict__ mat,
    float* __restrict__ dst, int nout)
{
  int wv = threadIdx.x >> 6, ln = threadIdx.x & 63;
  size_t row = (size_t)blockIdx.x * 4 + wv;
  const float* s = src + row * DIMc;
  for (int o = 0; o < nout; ++o) {
    float p = 0.f;
    const float* m = mat + (size_t)o * DIMc;
    for (int c = ln; c < DIMc; c += 64) p += s[c] * m[c];
    for (int off = 32; off; off >>= 1) p += __shfl_xor(p, off, 64);
    if (ln == 0) dst[row * nout + o] = p;
  }
}

// ---------------- fused id lora downs: lowk(8) + lowv(8) ----------------
__global__ __launch_bounds__(256) void dot_id(
    const float* __restrict__ id_tot, const float* __restrict__ idkA,
    const float* __restrict__ idvA, float* __restrict__ lowk,
    float* __restrict__ lowv)
{
  int wv = threadIdx.x >> 6, ln = threadIdx.x & 63;
  size_t row = (size_t)blockIdx.x * 4 + wv;
  const float* s = id_tot + row * DIMc;
  for (int o = 0; o < 8; ++o) {
    float p = 0.f, q = 0.f;
    const float* m1 = idkA + (size_t)o * DIMc;
    const float* m2 = idvA + (size_t)o * DIMc;
    for (int c = ln; c < DIMc; c += 64) { p += s[c] * m1[c]; q += s[c] * m2[c]; }
    for (int off = 32; off; off >>= 1) { p += __shfl_xor(p, off, 64); q += __shfl_xor(q, off, 64); }
    if (ln == 0) { lowk[row * 8 + o] = p; lowv[row * 8 + o] = q; }
  }
}

// ---------------- fused route+plow dots ----------------
__global__ __launch_bounds__(256) void dot_rp(
    const float* __restrict__ xo, const float* __restrict__ routeW,
    const float* __restrict__ projA, float* __restrict__ rd,
    float* __restrict__ plow)
{
  int wv = threadIdx.x >> 6, ln = threadIdx.x & 63;
  size_t row = (size_t)blockIdx.x * 4 + wv;
  const float* s = xo + row * DIMc;
  float xr[12];
#pragma unroll
  for (int i = 0; i < 12; ++i) xr[i] = s[ln + i * 64];
  for (int o = 0; o < 4; ++o) {
    float p = 0.f;
    const float* m = routeW + (size_t)o * DIMc;
#pragma unroll
    for (int i = 0; i < 12; ++i) p += xr[i] * m[ln + i * 64];
    for (int off = 32; off; off >>= 1) p += __shfl_xor(p, off, 64);
    if (ln == 0) rd[row * 4 + o] = p;
  }
  for (int o = 0; o < 32; ++o) {
    float p = 0.f;
    const float* m = projA + (size_t)o * DIMc;
#pragma unroll
    for (int i = 0; i < 12; ++i) p += xr[i] * m[ln + i * 64];
    for (int off = 32; off; off >>= 1) p += __shfl_xor(p, off, 64);
    if (ln == 0) plow[row * 32 + o] = p;
  }
}

// ---------------- ID_K: 1+tanh(lora1(...)) ----------------
__global__ __launch_bounds__(256) void idk_kernel(
    const float* __restrict__ id_tot, const float* __restrict__ W_idk,
    const float* __restrict__ b_idk, const float* __restrict__ lowk,
    const float* __restrict__ idk_B, float* __restrict__ IDK)
{
  int wv = threadIdx.x >> 6, ln = threadIdx.x & 63;
  size_t row = (size_t)blockIdx.x * 4 + wv;
  const float* s = id_tot + row * DIMc;
  for (int h = 0; h < Hh; ++h) {
    float p = 0.f;
    const float* m = W_idk + (size_t)h * DIMc;
    for (int c = ln; c < DIMc; c += 64) p += s[c] * m[c];
    for (int off = 32; off; off >>= 1) p += __shfl_xor(p, off, 64);
    if (ln == 0) {
      float lo = 0.f;
      for (int r = 0; r < 8; ++r) lo += lowk[row * 8 + r] * idk_B[h * 8 + r];
      IDK[row * Hh + h] = 1.f + tanhf(p + b_idk[h] + lo * 0.125f);
    }
  }
}

// ---------------- fixup: kmid holds raw k; multiply by IDK in place; v add IDV ----------------
__global__ __launch_bounds__(256) void fixup_kernel(
    float* __restrict__ vb, const float* __restrict__ IDK,
    const float* __restrict__ IDV, float* __restrict__ kmid,
    float* __restrict__ vmid, unsigned short* __restrict__ kmh)
{
  int e = blockIdx.x * 256 + threadIdx.x;   // flat (b,h,tt,d), tt<256
  int d  = e & 63;
  int r1 = e >> 6;
  int tt = r1 & 255;
  int r2 = r1 >> 8;
  int h  = r2 % Hh;
  int b  = r2 / Hh;
  float km = kmid[e] * IDK[(size_t)(b * 256 + tt) * Hh + h];
  kmid[e] = km;
  kmh[e] = bf16_1(km);
  size_t src = ((size_t)(b * Hh + h) * NNtok + tt) * Dd + d;
  float vv = vb[src] + IDV[(size_t)(b * 256 + tt) * DIMc + h * 64 + d];
  vb[src] = vv;
  vmid[e] = vv;
}

// ---------------- post-fixup transposes: vb -> vth cols 1280.. | vb rows0-255 -> vmth ----------------
__global__ __launch_bounds__(256) void transpose_post(
    const float* __restrict__ vb, unsigned short* __restrict__ vth,
    unsigned short* __restrict__ vmth)
{
  __shared__ float tl[64][65];
  const int blk = blockIdx.x, t = threadIdx.x;
  int bh, t0, dstCols, colOfs;
  unsigned short* dstp;
  size_t dstBh;
  if (blk < 960) { bh = blk / 20; t0 = (blk % 20) * 64; dstp = vth; dstBh = 163840; dstCols = 2560; colOfs = 1280; }
  else { int b2 = blk - 960; bh = b2 / 4; t0 = (b2 % 4) * 64; dstp = vmth; dstBh = 16384; dstCols = 256; colOfs = 0; }
  const float* sb = vb + (size_t)bh * 81920 + (size_t)t0 * 64;
#pragma unroll
  for (int p = 0; p < 4; ++p) {
    int flat = p * 256 + t;
    int r = flat >> 4, c4 = (flat & 15) << 2;
    float4 v = *(const float4*)(sb + r * 64 + c4);
    tl[r][c4 + 0] = v.x; tl[r][c4 + 1] = v.y;
    tl[r][c4 + 2] = v.z; tl[r][c4 + 3] = v.w;
  }
  __syncthreads();
  unsigned short* db = dstp + (size_t)bh * dstBh + colOfs + t0;
#pragma unroll
  for (int p = 0; p < 8; ++p) {
    int flat = p * 256 + t;
    int d = flat >> 5, u = flat & 31;
    *(unsigned int*)(db + (size_t)d * dstCols + 2 * u) = pk_bf16(tl[2 * u][d], tl[2 * u + 1][d]);
  }
}

// ---------------- pack A_aug for qkv: [x | qlow | 0] -> bf16 (5120,800) ----------------
__global__ __launch_bounds__(256) void cast_pack(
    const float* __restrict__ mainp, const float* __restrict__ extra,
    unsigned short* __restrict__ dst, int extraN)
{
  int idx = blockIdx.x * 256 + threadIdx.x;    // 5120*100 groups of 8
  int row = idx / 100, c8 = (idx % 100) * 8;
  unsigned int w[4];
  if (c8 < 768) {
    const float* s = mainp + (size_t)row * 768 + c8;
    float4 a = *(const float4*)s;
    float4 b = *(const float4*)(s + 4);
    w[0] = pk_bf16(a.x, a.y); w[1] = pk_bf16(a.z, a.w);
    w[2] = pk_bf16(b.x, b.y); w[3] = pk_bf16(b.z, b.w);
  } else {
    float v[8];
#pragma unroll
    for (int j = 0; j < 8; ++j) {
      int e = c8 - 768 + j;
      v[j] = (e < extraN) ? extra[(size_t)row * extraN + e] : 0.f;
    }
    w[0] = pk_bf16(v[0], v[1]); w[1] = pk_bf16(v[2], v[3]);
    w[2] = pk_bf16(v[4], v[5]); w[3] = pk_bf16(v[6], v[7]);
  }
  *(uint4*)(dst + (size_t)row * KAUG + c8) = make_uint4(w[0], w[1], w[2], w[3]);
}

// ---------------- pack A_aug for proj: coef computed inline (softmax(rd)*plow/8) ----------------
__global__ __launch_bounds__(256) void cast_pack_proj(
    const float* __restrict__ xo, const float* __restrict__ rd,
    const float* __restrict__ plow, unsigned short* __restrict__ dst)
{
  int idx = blockIdx.x * 256 + threadIdx.x;
  int row = idx / 100, c8 = (idx % 100) * 8;
  unsigned int w[4];
  if (c8 < 768) {
    const float* s = xo + (size_t)row * 768 + c8;
    float4 a = *(const float4*)s;
    float4 b = *(const float4*)(s + 4);
    w[0] = pk_bf16(a.x, a.y); w[1] = pk_bf16(a.z, a.w);
    w[2] = pk_bf16(b.x, b.y); w[3] = pk_bf16(b.z, b.w);
  } else {
    float l0 = rd[row * 4 + 0], l1 = rd[row * 4 + 1], l2 = rd[row * 4 + 2], l3 = rd[row * 4 + 3];
    float m = fmaxf(fmaxf(l0, l1), fmaxf(l2, l3));
    float e0 = __expf(l0 - m), e1 = __expf(l1 - m), e2 = __expf(l2 - m), e3 = __expf(l3 - m);
    float inv = 0.125f / (e0 + e1 + e2 + e3);
    float rt[4] = { e0 * inv, e1 * inv, e2 * inv, e3 * inv };
    float v[8];
#pragma unroll
    for (int j = 0; j < 8; ++j) {
      int e = c8 - 768 + j;
      v[j] = (e < 32) ? rt[e >> 3] * plow[(size_t)row * 32 + e] : 0.f;
    }
    w[0] = pk_bf16(v[0], v[1]); w[1] = pk_bf16(v[2], v[3]);
    w[2] = pk_bf16(v[4], v[5]); w[3] = pk_bf16(v[6], v[7]);
  }
  *(uint4*)(dst + (size_t)row * KAUG + c8) = make_uint4(w[0], w[1], w[2], w[3]);
}

// ---------------- MFMA GEMM: C = A_aug @ W_aug^T + bias, K=800 ----------------
__global__ __launch_bounds__(256) void gemm_mfma(
    const unsigned short* __restrict__ A, const unsigned short* __restrict__ W,
    const float* __restrict__ bias, int mode, float* __restrict__ dst,
    unsigned short* __restrict__ qh, float* __restrict__ kmid,
    float* __restrict__ vb, unsigned short* __restrict__ kfh)
{
  const int t = threadIdx.x, w = t >> 6, l = t & 63;
  const int m = l & 15, quad = l >> 4;
  const int bm = blockIdx.y * 128 + (w >> 1) * 64;
  const int bn = blockIdx.x * 128 + (w & 1) * 64;
  f32x4 acc[4][4] = {};
  const unsigned short* Ab = A + (size_t)(bm + m) * KAUG;
  const unsigned short* Wb = W + (size_t)(bn + m) * KAUG;
  for (int kk = 0; kk < KAUG; kk += 32) {
    bf16x8 af[4], bf[4];
#pragma unroll
    for (int i = 0; i < 4; ++i) af[i] = *(const bf16x8*)(Ab + (size_t)i * 16 * KAUG + kk + quad * 8);
#pragma unroll
    for (int j = 0; j < 4; ++j) bf[j] = *(const bf16x8*)(Wb + (size_t)j * 16 * KAUG + kk + quad * 8);
#pragma unroll
    for (int i = 0; i < 4; ++i)
#pragma unroll
      for (int j = 0; j < 4; ++j)
        acc[i][j] = __builtin_amdgcn_mfma_f32_16x16x32_bf16(af[i], bf[j], acc[i][j], 0, 0, 0);
  }

  float bj[4];
#pragma unroll
  for (int j = 0; j < 4; ++j) bj[j] = bias[bn + j * 16 + m];

  if (mode == 2) {
#pragma unroll
    for (int i = 0; i < 4; ++i)
#pragma unroll
      for (int r = 0; r < 4; ++r) {
        int row = bm + i * 16 + quad * 4 + r;
#pragma unroll
        for (int j = 0; j < 4; ++j)
          dst[(size_t)row * 768 + bn + j * 16 + m] = acc[i][j][r] + bj[j];
      }
    return;
  }
  int g = (blockIdx.x * 128) / DIMc;           // uniform per block
#pragma unroll
  for (int j = 0; j < 4; ++j) {
    int col = bn + j * 16 + m;
    int jj = col - g * DIMc, hh = jj >> 6, d = jj & 63;
#pragma unroll
    for (int i = 0; i < 4; ++i)
#pragma unroll
      for (int r = 0; r < 4; ++r) {
        int row = bm + i * 16 + quad * 4 + r;
        int bb = row / NNtok, tt = row % NNtok;
        float v = acc[i][j][r] + bj[j];
        if (g == 0) {
          qh[((size_t)(bb * Hh + hh) * NNtok + tt) * Dd + d] = bf16_1(v * 0.125f);
        } else if (g == 1) {
          kfh[((size_t)(bb * Hh + hh) * 2560 + 1280 + tt) * Dd + d] = bf16_1(v);
          if (tt < 256) kmid[((size_t)(bb * Hh + hh) * 256 + tt) * Dd + d] = v;
        } else {
          vb[((size_t)(bb * Hh + hh) * NNtok + tt) * Dd + d] = v;
        }
      }
  }
}

// ---------------- fp32 GEMM for ID_V ----------------
__global__ __launch_bounds__(256) void gemm_idv(
    const float* __restrict__ A, const float* __restrict__ W,
    const float* __restrict__ bias, const float* __restrict__ low,
    const float* __restrict__ Bl, float* __restrict__ dst)
{
  __shared__ alignas(16) float As[16][68];
  __shared__ alignas(16) float Bs[16][68];
  const int t  = threadIdx.x;
  const int tx = t & 15, ty = t >> 4;
  const int bn = blockIdx.x * 64, bm = blockIdx.y * 64;
  const int am = t >> 2, ak = (t & 3) << 2;
  float acc[4][4] = {};
  for (int k0 = 0; k0 < 768; k0 += 16) {
    float4 av = *(const float4*)(A + (size_t)(bm + am) * 768 + k0 + ak);
    float4 bv = *(const float4*)(W + (size_t)(bn + am) * 768 + k0 + ak);
    As[ak + 0][am] = av.x; As[ak + 1][am] = av.y; As[ak + 2][am] = av.z; As[ak + 3][am] = av.w;
    Bs[ak + 0][am] = bv.x; Bs[ak + 1][am] = bv.y; Bs[ak + 2][am] = bv.z; Bs[ak + 3][am] = bv.w;
    __syncthreads();
#pragma unroll
    for (int kk = 0; kk < 16; ++kk) {
      float4 a4 = *(const float4*)&As[kk][ty << 2];
      float4 b4 = *(const float4*)&Bs[kk][tx << 2];
      float ar[4] = { a4.x, a4.y, a4.z, a4.w };
      float br[4] = { b4.x, b4.y, b4.z, b4.w };
#pragma unroll
      for (int i = 0; i < 4; ++i)
#pragma unroll
        for (int j = 0; j < 4; ++j) acc[i][j] += ar[i] * br[j];
    }
    __syncthreads();
  }
#pragma unroll
  for (int i = 0; i < 4; ++i) {
    int mg = bm + (ty << 2) + i;
#pragma unroll
    for (int j = 0; j < 4; ++j) {
      int col = bn + (tx << 2) + j;
      float v = acc[i][j] + bias[col];
      float lo = 0.f;
#pragma unroll
      for (int r = 0; r < 8; ++r) lo += low[(size_t)mg * 8 + r] * Bl[(size_t)col * 8 + r];
      dst[(size_t)mg * 768 + col] = v + lo * 0.125f;
    }
  }
}

// ---------------- MFMA top-k attention v3: register bit-plane radix, no LDS atomics ----------------
// blockIdx = rb*48 + bh  (XCD swizzle: all blocks of one bh land on XCD bh%8)
template<int NK>
__global__ __launch_bounds__(256, 6) void attn_mfma3(
    const unsigned short* __restrict__ qh,   // (bh,1280,64) bf16
    const unsigned short* __restrict__ kf,   // (bh,NK,64)   bf16
    const unsigned short* __restrict__ vt,   // (bh,64,NK)   bf16 (V^T)
    int TK, int qrow0, float* __restrict__ xo, int nofs)
{
  constexpr int SCP = NK + 8;          // pad 8 shorts: row bank-stagger, keeps 16B align
  constexpr int W = NK / 128;          // score words per lane (2 scores/word)
  __shared__ alignas(16) unsigned short sc16[4][SCP];
  __shared__ float wavemax[4][4];
  __shared__ float rowinv[4];

  const int t = threadIdx.x, w = t >> 6, l = t & 63;
  const int bh = blockIdx.x % NBH;
  const int rb = blockIdx.x / NBH;
  const int b = bh / Hh, h = bh % Hh;
  const int qbase = qrow0 + rb * 4;
  const int m = l & 15, quad = l >> 4;

  // ---- Phase A: QK^T via MFMA (A rows 0-3 = q), running max, bf16 store ----
  bf16x8 aq0 = {0,0,0,0,0,0,0,0}, aq1 = {0,0,0,0,0,0,0,0};
  if (m < 4) {
    const unsigned short* qp = qh + ((size_t)bh * NNtok + qbase + m) * Dd + quad * 8;
    aq0 = *(const bf16x8*)qp;
    aq1 = *(const bf16x8*)(qp + 32);
  }
  float mx[4] = { -3.0e38f, -3.0e38f, -3.0e38f, -3.0e38f };
  const unsigned short* kbase = kf + (size_t)bh * NK * Dd;
  for (int n0 = w * 16; n0 < NK; n0 += 64) {
    const unsigned short* kp = kbase + (size_t)(n0 + m) * Dd + quad * 8;
    bf16x8 b0 = *(const bf16x8*)kp;
    bf16x8 b1 = *(const bf16x8*)(kp + 32);
    f32x4 acc = {0.f, 0.f, 0.f, 0.f};
    acc = __builtin_amdgcn_mfma_f32_16x16x32_bf16(aq0, b0, acc, 0, 0, 0);
    acc = __builtin_amdgcn_mfma_f32_16x16x32_bf16(aq1, b1, acc, 0, 0, 0);
    if (l < 16) {
#pragma unroll
      for (int r = 0; r < 4; ++r) {
        float v = acc[r];
        mx[r] = fmaxf(mx[r], v);
        sc16[r][n0 + l] = bf16_1(v);
      }
    }
  }
#pragma unroll
  for (int off = 1; off < 16; off <<= 1)
#pragma unroll
    for (int r = 0; r < 4; ++r) mx[r] = fmaxf(mx[r], __shfl_xor(mx[r], off, 64));
  if (l == 0) {
#pragma unroll
    for (int r = 0; r < 4; ++r) wavemax[w][r] = mx[r];
  }
  __syncthreads();

  // ---- Phase B: load row w into registers as sortable u16 keys (packed 2/word) ----
  unsigned int* sp = (unsigned int*)&sc16[w][0];
  unsigned int kw[W];
#pragma unroll
  for (int j = 0; j < W; ++j) {
    unsigned int v = sp[j * 64 + l];
    unsigned int mm = ((v >> 15) & 0x00010001u) * 0x7fffu + 0x80008000u;
    kw[j] = v ^ mm;   // bf16 -> monotone u16, both halves
  }

  // 16-pass MSB->LSB bit-plane radix: exact TK-th largest key (no LDS, no atomics)
  unsigned int prefix = 0;
  int kk = TK;
#pragma unroll 1
  for (int bit = 15; bit >= 0; --bit) {
    unsigned int hmask = (0xFFFFu << bit) & 0xFFFFu;
    unsigned int cand  = prefix | (1u << bit);
    int cnt = 0;
#pragma unroll
    for (int j = 0; j < W; ++j) {
      unsigned int k2 = kw[j];
      cnt += __popcll(__ballot((k2 & hmask) == cand));            // lo half
      cnt += __popcll(__ballot(((k2 >> 16) & hmask) == cand));    // hi half
    }
    if (cnt >= kk) prefix = cand; else kk -= cnt;
  }
  const unsigned int Tkey = prefix;
  const int need = kk;
  int ceq = 0;
#pragma unroll
  for (int j = 0; j < W; ++j) {
    unsigned int k2 = kw[j];
    ceq += __popcll(__ballot((k2 & 0xFFFFu) == Tkey));
    ceq += __popcll(__ballot((k2 >> 16) == Tkey));
  }
  if (need < ceq) {   // ties at threshold: keep lowest indices (jax order); demote in regs
    int seen = 0;
    unsigned long long below = (1ull << l) - 1ull;
#pragma unroll
    for (int j = 0; j < W; ++j) {
      unsigned int k2 = kw[j];
      bool eq0 = ((k2 & 0xFFFFu) == Tkey);
      bool eq1 = ((k2 >> 16) == Tkey);
      unsigned long long m0 = __ballot(eq0), m1 = __ballot(eq1);
      int bfr = __popcll(m0 & below) + __popcll(m1 & below);
      if (eq0 && (seen + bfr) >= need) kw[j] &= 0xFFFF0000u;
      if (eq1 && (seen + bfr + (eq0 ? 1 : 0)) >= need) kw[j] &= 0x0000FFFFu;
      seen += __popcll(m0) + __popcll(m1);
    }
  }

  // ---- Phase C: exp over selected (key >= Tkey), write bf16 weights back ----
  {
    float rm = fmaxf(fmaxf(wavemax[0][w], wavemax[1][w]),
                     fmaxf(wavemax[2][w], wavemax[3][w]));
    float sum = 0.f;
#pragma unroll
    for (int j = 0; j < W; ++j) {
      unsigned int k2 = kw[j];
      unsigned int lo = k2 & 0xFFFFu, hi = k2 >> 16;
      unsigned int mm = ((~k2 >> 15) & 0x00010001u) * 0x7fffu + 0x80008000u;
      unsigned int o2 = k2 ^ mm;   // back to bf16 bits
      float v0 = bf2f(o2 & 0xFFFFu);
      float v1 = bf2f(o2 >> 16);
      float w0 = (lo >= Tkey) ? __expf(v0 - rm) : 0.f;
      float w1 = (hi >= Tkey) ? __expf(v1 - rm) : 0.f;
      sp[j * 64 + l] = pk_bf16(w0, w1);
      sum += w0 + w1;
    }
#pragma unroll
    for (int off = 32; off; off >>= 1) sum += __shfl_xor(sum, off, 64);
    if (l == 0) rowinv[w] = 1.f / sum;
  }
  __syncthreads();

  // ---- Phase D: PV via MFMA; wave w -> dims [16w,16w+16) ----
  const unsigned short* vrow = vt + (size_t)bh * Dd * NK + (size_t)(w * 16 + m) * NK;
  f32x4 o = {0.f, 0.f, 0.f, 0.f};
  for (int c = 0; c < NK / 32; ++c) {
    bf16x8 af = {0,0,0,0,0,0,0,0};
    if (m < 4) af = *(const bf16x8*)&sc16[m][c * 32 + quad * 8];
    bf16x8 bf = *(const bf16x8*)(vrow + c * 32 + quad * 8);
    o = __builtin_amdgcn_mfma_f32_16x16x32_bf16(af, bf, o, 0, 0, 0);
  }
  if (l < 16) {
#pragma unroll
    for (int r = 0; r < 4; ++r) {
      int n = nofs + rb * 4 + r;
      xo[((size_t)b * NNtok + n) * DIMc + h * 64 + w * 16 + l] = o[r] * rowinv[r];
    }
  }
}

// ---------------- host ----------------
extern "C" void kernel_launch(void* const* d_in, const int* in_sizes, int n_in,
                              void* d_out, int out_size, void* d_ws, size_t ws_size,
                              hipStream_t stream)
{
  const float* x       = (const float*)d_in[0];
  const float* id_tot  = (const float*)d_in[1];
  const float* mem_k   = (const float*)d_in[2];
  const float* mem_v   = (const float*)d_in[3];
  const float* W_qkv   = (const float*)d_in[4];
  const float* b_qkv   = (const float*)d_in[5];
  const float* qkv_A   = (const float*)d_in[6];
  const float* qkv_B   = (const float*)d_in[7];
  const float* W_proj  = (const float*)d_in[8];
  const float* b_proj  = (const float*)d_in[9];
  const float* route_W = (const float*)d_in[10];
  const float* proj_A  = (const float*)d_in[11];
  const float* proj_B  = (const float*)d_in[12];
  const float* W_idk   = (const float*)d_in[13];
  const float* b_idk   = (const float*)d_in[14];
  const float* idk_A   = (const float*)d_in[15];
  const float* idk_B   = (const float*)d_in[16];
  const float* W_idv   = (const float*)d_in[17];
  const float* b_idv   = (const float*)d_in[18];
  const float* idv_A   = (const float*)d_in[19];
  const float* idv_B   = (const float*)d_in[20];

  float* ws   = (float*)d_ws;
  float* vb   = ws + OVb;
  float* xo   = ws + OXO;
  float* qlow = ws + OQL;
  float* IDK  = ws + OIDK;
  float* IDV  = ws + OIDV;
  float* lowk = ws + OLK;
  float* lowv = ws + OLV;
  float* rd   = ws + ORD;
  float* plow = ws + OPL;
  unsigned short* qh   = (unsigned short*)(ws + OQH);
  unsigned short* kfh  = (unsigned short*)(ws + OKFH);
  unsigned short* vth  = (unsigned short*)(ws + OVTH);
  unsigned short* kmh  = (unsigned short*)(ws + OKMH);
  unsigned short* vmth = (unsigned short*)(ws + OVMTH);
  unsigned short* Aa   = (unsigned short*)(ws + OAa);
  unsigned short* Wa   = (unsigned short*)(ws + OWa);
  unsigned short* Wa2  = (unsigned short*)(ws + OWa2);

  float* out  = (float*)d_out;
  float* kmid = out + KMID_OFF;
  float* vmid = out + VMID_OFF;

  // staging: mem_k cast, mem_v transpose, both W_aug builds — one launch
  prep<<<7680, 256, 0, stream>>>(mem_k, mem_v, W_qkv, qkv_B, W_proj, proj_B,
                                 kfh, vth, Wa, Wa2);

  // LoRA downs
  dot_small<<<1280, 256, 0, stream>>>(x, qkv_A, qlow, 24);
  dot_id<<<256, 256, 0, stream>>>(id_tot, idk_A, idv_A, lowk, lowv);

  // QKV via MFMA with augmented K (fused LoRA)
  cast_pack<<<2000, 256, 0, stream>>>(x, qlow, Aa, 24);
  gemm_mfma<<<dim3(18, 40), 256, 0, stream>>>(Aa, Wa, b_qkv, 0, nullptr,
                                              qh, kmid, vb, kfh);
  // ID_V (fp32), ID_K
  gemm_idv<<<dim3(12, 16), 256, 0, stream>>>(id_tot, W_idv, b_idv, lowv, idv_B, IDV);
  idk_kernel<<<256, 256, 0, stream>>>(id_tot, W_idk, b_idk, lowk, idk_B, IDK);
  // outputs k_m_id / v_m_id; vb rows 0-255 updated in place
  fixup_kernel<<<3072, 256, 0, stream>>>(vb, IDK, IDV, kmid, vmid, kmh);

  // V^T bf16 staging (post-fixup): vth cols 1280.. + vmth — one launch
  transpose_post<<<1152, 256, 0, stream>>>(vb, vth, vmth);

  // attention (XCD-swizzled grids: blockIdx = rb*48 + bh)
  attn_mfma3<256><<<3072, 256, 0, stream>>>(qh, kmh, vmth, 128, 0, xo, 0);
  attn_mfma3<2560><<<12288, 256, 0, stream>>>(qh, kfh, vth, 640, 256, xo, 256);

  // routed output projection: fused dots, inline-softmax pack, MFMA GEMM
  dot_rp<<<1280, 256, 0, stream>>>(xo, route_W, proj_A, rd, plow);
  cast_pack_proj<<<2000, 256, 0, stream>>>(xo, rd, plow, Aa);
  gemm_mfma<<<dim3(6, 40), 256, 0, stream>>>(Aa, Wa2, b_proj, 2, out,
                                             nullptr, nullptr, nullptr, nullptr);
}

// Round 7
// 1361.317 us; speedup vs baseline: 2.9775x; 1.0157x over previous
//
#include <hip/hip_runtime.h>
#include <cstddef>

// ---------------- problem constants ----------------
#define Bq    4
#define Hh    12
#define Dd    64
#define NNtok 1280
#define DIMc  768
#define KAUG  800      // 768 + 32 augmented-K for fused LoRA
#define NBH   48       // Bq*Hh

typedef __attribute__((ext_vector_type(8))) short bf16x8;
typedef __attribute__((ext_vector_type(4))) float f32x4;

// workspace offsets (floats)
static const size_t OVb   = 0;                   // vb fp32 (B,H,1280,64); rows 0-255 -> v_add_id
static const size_t OXO   = 3932160;             // xo fp32 (B,1280,768)
static const size_t OQL   = 7864320;             // qkv low (5120,24)
static const size_t OIDK  = 7987200;             // 1+tanh(ID_K) (1024,12)
static const size_t OIDV  = 7999488;             // ID_V (1024,768)
static const size_t OLK   = 8785920;             // id_lowk (1024,8)
static const size_t OLV   = 8794112;             // id_lowv (1024,8)
static const size_t ORD   = 8802304;             // route dots (5120,4)
static const size_t OPL   = 8822784;             // proj low (5120,32)
static const size_t OQH   = 8986624;             // qh bf16 (B,H,1280,64)
static const size_t OKFH  = 10952704;            // kfh bf16 (B,H,2560,64) [mem_k|k]
static const size_t OVTH  = 14884864;            // vth bf16 (B,H,64,2560)
static const size_t OKMH  = 18817024;            // kmh bf16 (B,H,256,64)
static const size_t OVMTH = 19210240;            // vmth bf16 (B,H,64,256)
static const size_t OAa   = 19603456;            // A_aug bf16 (5120,800)
static const size_t OWa   = 21651456;            // W_aug qkv bf16 (2304,800)
static const size_t OWa2  = 22573056;            // W_aug proj bf16 (768,800)

// d_out offsets (floats)
static const size_t KMID_OFF = 3932160;
static const size_t VMID_OFF = 4718592;

__device__ __forceinline__ unsigned int pk_bf16(float a, float b) {  // RNE pack
  unsigned int ua = __float_as_uint(a), ub = __float_as_uint(b);
  ua += 0x7fffu + ((ua >> 16) & 1u);
  ub += 0x7fffu + ((ub >> 16) & 1u);
  return (ua >> 16) | (ub & 0xffff0000u);
}
__device__ __forceinline__ unsigned short bf16_1(float a) {
  unsigned int ua = __float_as_uint(a);
  ua += 0x7fffu + ((ua >> 16) & 1u);
  return (unsigned short)(ua >> 16);
}
__device__ __forceinline__ float bf2f(unsigned int h) {
  return __uint_as_float(h << 16);
}

// ---------------- prep: cast_k | transpose(mem_v) | cast_w_qkv | cast_w_proj ----------------
__global__ __launch_bounds__(256) void prep(
    const float* __restrict__ mem_k, const float* __restrict__ mem_v,
    const float* __restrict__ W_qkv, const float* __restrict__ qkvB,
    const float* __restrict__ W_proj, const float* __restrict__ projB,
    unsigned short* __restrict__ kfh, unsigned short* __restrict__ vth,
    unsigned short* __restrict__ Wa, unsigned short* __restrict__ Wa2)
{
  __shared__ float tl[64][65];
  const int blk = blockIdx.x, t = threadIdx.x;
  if (blk < 1920) {                       // cast mem_k -> kfh rows 0..1279
    size_t idx = ((size_t)blk * 256 + t) * 8;
    int bh = (int)(idx / 81920);
    int r  = (int)(idx % 81920);
    const float* s = mem_k + (size_t)bh * 81920 + r;
    float4 a = *(const float4*)s;
    float4 b = *(const float4*)(s + 4);
    unsigned int* dp = (unsigned int*)(kfh + (size_t)bh * 163840 + r);
    dp[0] = pk_bf16(a.x, a.y); dp[1] = pk_bf16(a.z, a.w);
    dp[2] = pk_bf16(b.x, b.y); dp[3] = pk_bf16(b.z, b.w);
  } else if (blk < 2880) {                // transpose mem_v -> vth cols 0..1279
    int b2 = blk - 1920;
    int bh = b2 / 20, t0 = (b2 % 20) * 64;
    const float* sb = mem_v + (size_t)bh * 81920 + (size_t)t0 * 64;
#pragma unroll
    for (int p = 0; p < 4; ++p) {
      int flat = p * 256 + t;
      int r = flat >> 4, c4 = (flat & 15) << 2;
      float4 v = *(const float4*)(sb + r * 64 + c4);
      tl[r][c4 + 0] = v.x; tl[r][c4 + 1] = v.y;
      tl[r][c4 + 2] = v.z; tl[r][c4 + 3] = v.w;
    }
    __syncthreads();
    unsigned short* db = vth + (size_t)bh * 163840 + t0;
#pragma unroll
    for (int p = 0; p < 8; ++p) {
      int flat = p * 256 + t;
      int d = flat >> 5, u = flat & 31;
      *(unsigned int*)(db + (size_t)d * 2560 + 2 * u) = pk_bf16(tl[2 * u][d], tl[2 * u + 1][d]);
    }
  } else if (blk < 6480) {                // W_aug qkv
    int idx = (blk - 2880) * 256 + t;     // 2304*400 uint pairs
    int row = idx / 400, c = (idx % 400) * 2;
    float a, b;
    if (c < 768) {
      a = W_qkv[(size_t)row * 768 + c]; b = W_qkv[(size_t)row * 768 + c + 1];
    } else {
      int g = row / 768, jj = row % 768;
      int e0 = c - 768, e1 = e0 + 1;
      a = (e0 < 24 && (e0 >> 3) == g) ? qkvB[(size_t)g * 6144 + jj * 8 + (e0 & 7)] * 0.125f : 0.f;
      b = (e1 < 24 && (e1 >> 3) == g) ? qkvB[(size_t)g * 6144 + jj * 8 + (e1 & 7)] * 0.125f : 0.f;
    }
    *(unsigned int*)(Wa + (size_t)row * KAUG + c) = pk_bf16(a, b);
  } else {                                // W_aug proj
    int idx = (blk - 6480) * 256 + t;     // 768*400
    int row = idx / 400, c = (idx % 400) * 2;
    float a, b;
    if (c < 768) {
      a = W_proj[(size_t)row * 768 + c]; b = W_proj[(size_t)row * 768 + c + 1];
    } else {
      int e0 = c - 768, e1 = e0 + 1;
      a = projB[(size_t)(e0 >> 3) * 6144 + row * 8 + (e0 & 7)];
      b = projB[(size_t)(e1 >> 3) * 6144 + row * 8 + (e1 & 7)];
    }
    *(unsigned int*)(Wa2 + (size_t)row * KAUG + c) = pk_bf16(a, b);
  }
}

// ---------------- small row-dot kernel ----------------
__global__ __launch_bounds__(256) void dot_small(
    const float* __restrict__ src, const float* __restrict__ mat,
    float* __restrict__ dst, int nout)
{
  int wv = threadIdx.x >> 6, ln = threadIdx.x & 63;
  size_t row = (size_t)blockIdx.x * 4 + wv;
  const float* s = src + row * DIMc;
  for (int o = 0; o < nout; ++o) {
    float p = 0.f;
    const float* m = mat + (size_t)o * DIMc;
    for (int c = ln; c < DIMc; c += 64) p += s[c] * m[c];
    for (int off = 32; off; off >>= 1) p += __shfl_xor(p, off, 64);
    if (ln == 0) dst[row * nout + o] = p;
  }
}

// ---------------- fused id lora downs: lowk(8) + lowv(8) ----------------
__global__ __launch_bounds__(256) void dot_id(
    const float* __restrict__ id_tot, const float* __restrict__ idkA,
    const float* __restrict__ idvA, float* __restrict__ lowk,
    float* __restrict__ lowv)
{
  int wv = threadIdx.x >> 6, ln = threadIdx.x & 63;
  size_t row = (size_t)blockIdx.x * 4 + wv;
  const float* s = id_tot + row * DIMc;
  for (int o = 0; o < 8; ++o) {
    float p = 0.f, q = 0.f;
    const float* m1 = idkA + (size_t)o * DIMc;
    const float* m2 = idvA + (size_t)o * DIMc;
    for (int c = ln; c < DIMc; c += 64) { p += s[c] * m1[c]; q += s[c] * m2[c]; }
    for (int off = 32; off; off >>= 1) { p += __shfl_xor(p, off, 64); q += __shfl_xor(q, off, 64); }
    if (ln == 0) { lowk[row * 8 + o] = p; lowv[row * 8 + o] = q; }
  }
}

// ---------------- fused route+plow dots ----------------
__global__ __launch_bounds__(256) void dot_rp(
    const float* __restrict__ xo, const float* __restrict__ routeW,
    const float* __restrict__ projA, float* __restrict__ rd,
    float* __restrict__ plow)
{
  int wv = threadIdx.x >> 6, ln = threadIdx.x & 63;
  size_t row = (size_t)blockIdx.x * 4 + wv;
  const float* s = xo + row * DIMc;
  float xr[12];
#pragma unroll
  for (int i = 0; i < 12; ++i) xr[i] = s[ln + i * 64];
  for (int o = 0; o < 4; ++o) {
    float p = 0.f;
    const float* m = routeW + (size_t)o * DIMc;
#pragma unroll
    for (int i = 0; i < 12; ++i) p += xr[i] * m[ln + i * 64];
    for (int off = 32; off; off >>= 1) p += __shfl_xor(p, off, 64);
    if (ln == 0) rd[row * 4 + o] = p;
  }
  for (int o = 0; o < 32; ++o) {
    float p = 0.f;
    const float* m = projA + (size_t)o * DIMc;
#pragma unroll
    for (int i = 0; i < 12; ++i) p += xr[i] * m[ln + i * 64];
    for (int off = 32; off; off >>= 1) p += __shfl_xor(p, off, 64);
    if (ln == 0) plow[row * 32 + o] = p;
  }
}

// ---------------- ID_K: 1+tanh(lora1(...)) ----------------
__global__ __launch_bounds__(256) void idk_kernel(
    const float* __restrict__ id_tot, const float* __restrict__ W_idk,
    const float* __restrict__ b_idk, const float* __restrict__ lowk,
    const float* __restrict__ idk_B, float* __restrict__ IDK)
{
  int wv = threadIdx.x >> 6, ln = threadIdx.x & 63;
  size_t row = (size_t)blockIdx.x * 4 + wv;
  const float* s = id_tot + row * DIMc;
  for (int h = 0; h < Hh; ++h) {
    float p = 0.f;
    const float* m = W_idk + (size_t)h * DIMc;
    for (int c = ln; c < DIMc; c += 64) p += s[c] * m[c];
    for (int off = 32; off; off >>= 1) p += __shfl_xor(p, off, 64);
    if (ln == 0) {
      float lo = 0.f;
      for (int r = 0; r < 8; ++r) lo += lowk[row * 8 + r] * idk_B[h * 8 + r];
      IDK[row * Hh + h] = 1.f + tanhf(p + b_idk[h] + lo * 0.125f);
    }
  }
}

// ---------------- fixup: kmid holds raw k; multiply by IDK in place; v add IDV ----------------
__global__ __launch_bounds__(256) void fixup_kernel(
    float* __restrict__ vb, const float* __restrict__ IDK,
    const float* __restrict__ IDV, float* __restrict__ kmid,
    float* __restrict__ vmid, unsigned short* __restrict__ kmh)
{
  int e = blockIdx.x * 256 + threadIdx.x;   // flat (b,h,tt,d), tt<256
  int d  = e & 63;
  int r1 = e >> 6;
  int tt = r1 & 255;
  int r2 = r1 >> 8;
  int h  = r2 % Hh;
  int b  = r2 / Hh;
  float km = kmid[e] * IDK[(size_t)(b * 256 + tt) * Hh + h];
  kmid[e] = km;
  kmh[e] = bf16_1(km);
  size_t src = ((size_t)(b * Hh + h) * NNtok + tt) * Dd + d;
  float vv = vb[src] + IDV[(size_t)(b * 256 + tt) * DIMc + h * 64 + d];
  vb[src] = vv;
  vmid[e] = vv;
}

// ---------------- post-fixup transposes ----------------
__global__ __launch_bounds__(256) void transpose_post(
    const float* __restrict__ vb, unsigned short* __restrict__ vth,
    unsigned short* __restrict__ vmth)
{
  __shared__ float tl[64][65];
  const int blk = blockIdx.x, t = threadIdx.x;
  int bh, t0, dstCols, colOfs;
  unsigned short* dstp;
  size_t dstBh;
  if (blk < 960) { bh = blk / 20; t0 = (blk % 20) * 64; dstp = vth; dstBh = 163840; dstCols = 2560; colOfs = 1280; }
  else { int b2 = blk - 960; bh = b2 / 4; t0 = (b2 % 4) * 64; dstp = vmth; dstBh = 16384; dstCols = 256; colOfs = 0; }
  const float* sb = vb + (size_t)bh * 81920 + (size_t)t0 * 64;
#pragma unroll
  for (int p = 0; p < 4; ++p) {
    int flat = p * 256 + t;
    int r = flat >> 4, c4 = (flat & 15) << 2;
    float4 v = *(const float4*)(sb + r * 64 + c4);
    tl[r][c4 + 0] = v.x; tl[r][c4 + 1] = v.y;
    tl[r][c4 + 2] = v.z; tl[r][c4 + 3] = v.w;
  }
  __syncthreads();
  unsigned short* db = dstp + (size_t)bh * dstBh + colOfs + t0;
#pragma unroll
  for (int p = 0; p < 8; ++p) {
    int flat = p * 256 + t;
    int d = flat >> 5, u = flat & 31;
    *(unsigned int*)(db + (size_t)d * dstCols + 2 * u) = pk_bf16(tl[2 * u][d], tl[2 * u + 1][d]);
  }
}

// ---------------- pack A_aug for qkv ----------------
__global__ __launch_bounds__(256) void cast_pack(
    const float* __restrict__ mainp, const float* __restrict__ extra,
    unsigned short* __restrict__ dst, int extraN)
{
  int idx = blockIdx.x * 256 + threadIdx.x;    // 5120*100 groups of 8
  int row = idx / 100, c8 = (idx % 100) * 8;
  unsigned int w[4];
  if (c8 < 768) {
    const float* s = mainp + (size_t)row * 768 + c8;
    float4 a = *(const float4*)s;
    float4 b = *(const float4*)(s + 4);
    w[0] = pk_bf16(a.x, a.y); w[1] = pk_bf16(a.z, a.w);
    w[2] = pk_bf16(b.x, b.y); w[3] = pk_bf16(b.z, b.w);
  } else {
    float v[8];
#pragma unroll
    for (int j = 0; j < 8; ++j) {
      int e = c8 - 768 + j;
      v[j] = (e < extraN) ? extra[(size_t)row * extraN + e] : 0.f;
    }
    w[0] = pk_bf16(v[0], v[1]); w[1] = pk_bf16(v[2], v[3]);
    w[2] = pk_bf16(v[4], v[5]); w[3] = pk_bf16(v[6], v[7]);
  }
  *(uint4*)(dst + (size_t)row * KAUG + c8) = make_uint4(w[0], w[1], w[2], w[3]);
}

// ---------------- pack A_aug for proj (inline softmax(rd)*plow/8) ----------------
__global__ __launch_bounds__(256) void cast_pack_proj(
    const float* __restrict__ xo, const float* __restrict__ rd,
    const float* __restrict__ plow, unsigned short* __restrict__ dst)
{
  int idx = blockIdx.x * 256 + threadIdx.x;
  int row = idx / 100, c8 = (idx % 100) * 8;
  unsigned int w[4];
  if (c8 < 768) {
    const float* s = xo + (size_t)row * 768 + c8;
    float4 a = *(const float4*)s;
    float4 b = *(const float4*)(s + 4);
    w[0] = pk_bf16(a.x, a.y); w[1] = pk_bf16(a.z, a.w);
    w[2] = pk_bf16(b.x, b.y); w[3] = pk_bf16(b.z, b.w);
  } else {
    float l0 = rd[row * 4 + 0], l1 = rd[row * 4 + 1], l2 = rd[row * 4 + 2], l3 = rd[row * 4 + 3];
    float m = fmaxf(fmaxf(l0, l1), fmaxf(l2, l3));
    float e0 = __expf(l0 - m), e1 = __expf(l1 - m), e2 = __expf(l2 - m), e3 = __expf(l3 - m);
    float inv = 0.125f / (e0 + e1 + e2 + e3);
    float rt[4] = { e0 * inv, e1 * inv, e2 * inv, e3 * inv };
    float v[8];
#pragma unroll
    for (int j = 0; j < 8; ++j) {
      int e = c8 - 768 + j;
      v[j] = (e < 32) ? rt[e >> 3] * plow[(size_t)row * 32 + e] : 0.f;
    }
    w[0] = pk_bf16(v[0], v[1]); w[1] = pk_bf16(v[2], v[3]);
    w[2] = pk_bf16(v[4], v[5]); w[3] = pk_bf16(v[6], v[7]);
  }
  *(uint4*)(dst + (size_t)row * KAUG + c8) = make_uint4(w[0], w[1], w[2], w[3]);
}

// ---------------- MFMA GEMM: C = A_aug @ W_aug^T + bias, K=800 ----------------
__global__ __launch_bounds__(256) void gemm_mfma(
    const unsigned short* __restrict__ A, const unsigned short* __restrict__ W,
    const float* __restrict__ bias, int mode, float* __restrict__ dst,
    unsigned short* __restrict__ qh, float* __restrict__ kmid,
    float* __restrict__ vb, unsigned short* __restrict__ kfh)
{
  const int t = threadIdx.x, w = t >> 6, l = t & 63;
  const int m = l & 15, quad = l >> 4;
  const int bm = blockIdx.y * 128 + (w >> 1) * 64;
  const int bn = blockIdx.x * 128 + (w & 1) * 64;
  f32x4 acc[4][4] = {};
  const unsigned short* Ab = A + (size_t)(bm + m) * KAUG;
  const unsigned short* Wb = W + (size_t)(bn + m) * KAUG;
  for (int kk = 0; kk < KAUG; kk += 32) {
    bf16x8 af[4], bf[4];
#pragma unroll
    for (int i = 0; i < 4; ++i) af[i] = *(const bf16x8*)(Ab + (size_t)i * 16 * KAUG + kk + quad * 8);
#pragma unroll
    for (int j = 0; j < 4; ++j) bf[j] = *(const bf16x8*)(Wb + (size_t)j * 16 * KAUG + kk + quad * 8);
#pragma unroll
    for (int i = 0; i < 4; ++i)
#pragma unroll
      for (int j = 0; j < 4; ++j)
        acc[i][j] = __builtin_amdgcn_mfma_f32_16x16x32_bf16(af[i], bf[j], acc[i][j], 0, 0, 0);
  }

  float bj[4];
#pragma unroll
  for (int j = 0; j < 4; ++j) bj[j] = bias[bn + j * 16 + m];

  if (mode == 2) {
#pragma unroll
    for (int i = 0; i < 4; ++i)
#pragma unroll
      for (int r = 0; r < 4; ++r) {
        int row = bm + i * 16 + quad * 4 + r;
#pragma unroll
        for (int j = 0; j < 4; ++j)
          dst[(size_t)row * 768 + bn + j * 16 + m] = acc[i][j][r] + bj[j];
      }
    return;
  }
  int g = (blockIdx.x * 128) / DIMc;           // uniform per block
#pragma unroll
  for (int j = 0; j < 4; ++j) {
    int col = bn + j * 16 + m;
    int jj = col - g * DIMc, hh = jj >> 6, d = jj & 63;
#pragma unroll
    for (int i = 0; i < 4; ++i)
#pragma unroll
      for (int r = 0; r < 4; ++r) {
        int row = bm + i * 16 + quad * 4 + r;
        int bb = row / NNtok, tt = row % NNtok;
        float v = acc[i][j][r] + bj[j];
        if (g == 0) {
          qh[((size_t)(bb * Hh + hh) * NNtok + tt) * Dd + d] = bf16_1(v * 0.125f);
        } else if (g == 1) {
          kfh[((size_t)(bb * Hh + hh) * 2560 + 1280 + tt) * Dd + d] = bf16_1(v);
          if (tt < 256) kmid[((size_t)(bb * Hh + hh) * 256 + tt) * Dd + d] = v;
        } else {
          vb[((size_t)(bb * Hh + hh) * NNtok + tt) * Dd + d] = v;
        }
      }
  }
}

// ---------------- fp32 GEMM for ID_V ----------------
__global__ __launch_bounds__(256) void gemm_idv(
    const float* __restrict__ A, const float* __restrict__ W,
    const float* __restrict__ bias, const float* __restrict__ low,
    const float* __restrict__ Bl, float* __restrict__ dst)
{
  __shared__ alignas(16) float As[16][68];
  __shared__ alignas(16) float Bs[16][68];
  const int t  = threadIdx.x;
  const int tx = t & 15, ty = t >> 4;
  const int bn = blockIdx.x * 64, bm = blockIdx.y * 64;
  const int am = t >> 2, ak = (t & 3) << 2;
  float acc[4][4] = {};
  for (int k0 = 0; k0 < 768; k0 += 16) {
    float4 av = *(const float4*)(A + (size_t)(bm + am) * 768 + k0 + ak);
    float4 bv = *(const float4*)(W + (size_t)(bn + am) * 768 + k0 + ak);
    As[ak + 0][am] = av.x; As[ak + 1][am] = av.y; As[ak + 2][am] = av.z; As[ak + 3][am] = av.w;
    Bs[ak + 0][am] = bv.x; Bs[ak + 1][am] = bv.y; Bs[ak + 2][am] = bv.z; Bs[ak + 3][am] = bv.w;
    __syncthreads();
#pragma unroll
    for (int kk = 0; kk < 16; ++kk) {
      float4 a4 = *(const float4*)&As[kk][ty << 2];
      float4 b4 = *(const float4*)&Bs[kk][tx << 2];
      float ar[4] = { a4.x, a4.y, a4.z, a4.w };
      float br[4] = { b4.x, b4.y, b4.z, b4.w };
#pragma unroll
      for (int i = 0; i < 4; ++i)
#pragma unroll
        for (int j = 0; j < 4; ++j) acc[i][j] += ar[i] * br[j];
    }
    __syncthreads();
  }
#pragma unroll
  for (int i = 0; i < 4; ++i) {
    int mg = bm + (ty << 2) + i;
#pragma unroll
    for (int j = 0; j < 4; ++j) {
      int col = bn + (tx << 2) + j;
      float v = acc[i][j] + bias[col];
      float lo = 0.f;
#pragma unroll
      for (int r = 0; r < 8; ++r) lo += low[(size_t)mg * 8 + r] * Bl[(size_t)col * 8 + r];
      dst[(size_t)mg * 768 + col] = v + lo * 0.125f;
    }
  }
}

// ---------------- radix helper: select bin from per-wave 256-bin hist ----------------
__device__ __forceinline__ void radix_sel(
    unsigned int* hist, int l, int& kk, int& ceq, unsigned int& bin)
{
  unsigned int h0 = hist[4 * l + 0], h1 = hist[4 * l + 1],
               h2 = hist[4 * l + 2], h3 = hist[4 * l + 3];
  unsigned int s3 = h3, s2 = h2 + s3, s1 = h1 + s2, s0 = h0 + s1;
  unsigned int tsum = s0;
#pragma unroll
  for (int off = 1; off < 64; off <<= 1) {
    unsigned int other = __shfl(tsum, l + off, 64);
    tsum += (l + off < 64) ? other : 0u;
  }
  unsigned int T = tsum - s0;   // suffix over lanes > l
  unsigned int Sv0 = T + s0, Sv1 = T + s1, Sv2 = T + s2, Sv3 = T + s3, Sv4 = T;
  int fb = -1, fkk = 0, fceq = 0;
  unsigned int ukk = (unsigned int)kk;
  if (Sv0 >= ukk && Sv1 < ukk) { fb = 4 * l + 0; fkk = (int)(ukk - Sv1); fceq = (int)(Sv0 - Sv1); }
  if (Sv1 >= ukk && Sv2 < ukk) { fb = 4 * l + 1; fkk = (int)(ukk - Sv2); fceq = (int)(Sv1 - Sv2); }
  if (Sv2 >= ukk && Sv3 < ukk) { fb = 4 * l + 2; fkk = (int)(ukk - Sv3); fceq = (int)(Sv2 - Sv3); }
  if (Sv3 >= ukk && Sv4 < ukk) { fb = 4 * l + 3; fkk = (int)(ukk - Sv4); fceq = (int)(Sv3 - Sv4); }
  unsigned long long mb = __ballot(fb >= 0);
  int src = __ffsll(mb) - 1;
  bin = (unsigned int)__shfl(fb, src, 64);
  kk  = __shfl(fkk, src, 64);
  ceq = __shfl(fceq, src, 64);
}

// ---------------- MFMA top-k attention v4: 2-stage radix, pipelined A/D ----------------
// stage 1: 8-pass bit-plane on top byte (ballot counts, no LDS)
// stage 2: per-wave LDS histogram over prefix-matching candidates (sparse atomics)
template<int NK>
__global__ __launch_bounds__(256, 6) void attn_mfma4(
    const unsigned short* __restrict__ qh,   // (bh,1280,64) bf16
    const unsigned short* __restrict__ kf,   // (bh,NK,64)   bf16
    const unsigned short* __restrict__ vt,   // (bh,64,NK)   bf16 (V^T)
    int TK, int qrow0, float* __restrict__ xo, int nofs)
{
  constexpr int SCP = NK + 8;
  constexpr int W = NK / 128;          // score words per lane (2 scores/word)
  __shared__ alignas(16) unsigned short sc16[4][SCP];
  __shared__ unsigned int hist4[4][256];
  __shared__ float wavemax[4][4];
  __shared__ float rowinv[4];

  const int t = threadIdx.x, w = t >> 6, l = t & 63;
  const int bh = blockIdx.x % NBH;
  const int rb = blockIdx.x / NBH;
  const int b = bh / Hh, h = bh % Hh;
  const int qbase = qrow0 + rb * 4;
  const int m = l & 15, quad = l >> 4;

  // ---- Phase A: QK^T via MFMA, software-pipelined K loads ----
  bf16x8 aq0 = {0,0,0,0,0,0,0,0}, aq1 = {0,0,0,0,0,0,0,0};
  if (m < 4) {
    const unsigned short* qp = qh + ((size_t)bh * NNtok + qbase + m) * Dd + quad * 8;
    aq0 = *(const bf16x8*)qp;
    aq1 = *(const bf16x8*)(qp + 32);
  }
  float mx[4] = { -3.0e38f, -3.0e38f, -3.0e38f, -3.0e38f };
  const unsigned short* kp = kf + (size_t)bh * NK * Dd + (size_t)(w * 16 + m) * Dd + quad * 8;
  bf16x8 c0 = *(const bf16x8*)kp;
  bf16x8 c1 = *(const bf16x8*)(kp + 32);
  for (int n0 = w * 16; n0 < NK; n0 += 64) {
    kp += 64 * Dd;
    bf16x8 p0, p1;
    if (n0 + 64 < NK) {
      p0 = *(const bf16x8*)kp;
      p1 = *(const bf16x8*)(kp + 32);
    }
    f32x4 acc = {0.f, 0.f, 0.f, 0.f};
    acc = __builtin_amdgcn_mfma_f32_16x16x32_bf16(aq0, c0, acc, 0, 0, 0);
    acc = __builtin_amdgcn_mfma_f32_16x16x32_bf16(aq1, c1, acc, 0, 0, 0);
    if (l < 16) {
#pragma unroll
      for (int r = 0; r < 4; ++r) {
        float v = acc[r];
        mx[r] = fmaxf(mx[r], v);
        sc16[r][n0 + l] = bf16_1(v);
      }
    }
    c0 = p0; c1 = p1;
  }
#pragma unroll
  for (int off = 1; off < 16; off <<= 1)
#pragma unroll
    for (int r = 0; r < 4; ++r) mx[r] = fmaxf(mx[r], __shfl_xor(mx[r], off, 64));
  if (l == 0) {
#pragma unroll
    for (int r = 0; r < 4; ++r) wavemax[w][r] = mx[r];
  }
  __syncthreads();

  // ---- Phase B: load row w into regs as sortable u16 keys ----
  unsigned int* sp = (unsigned int*)&sc16[w][0];
  unsigned int kw[W];
#pragma unroll
  for (int j = 0; j < W; ++j) {
    unsigned int v = sp[j * 64 + l];
    unsigned int mm = ((v >> 15) & 0x00010001u) * 0x7fffu + 0x80008000u;
    kw[j] = v ^ mm;   // bf16 -> monotone u16, both halves
  }

  // stage 1: bit-plane on bits 15..8 (8 passes)
  unsigned int prefix = 0;
  int kk = TK;
#pragma unroll 1
  for (int bit = 15; bit >= 8; --bit) {
    unsigned int hmask = (0xFFFFu << bit) & 0xFFFFu;
    unsigned int cand  = prefix | (1u << bit);
    int cnt = 0;
#pragma unroll
    for (int j = 0; j < W; ++j) {
      unsigned int k2 = kw[j];
      cnt += __popcll(__ballot((k2 & hmask) == cand));
      cnt += __popcll(__ballot(((k2 >> 16) & hmask) == cand));
    }
    if (cnt >= kk) prefix = cand; else kk -= cnt;
  }
  // stage 2: per-wave histogram of low byte among prefix-matching candidates
  unsigned int* hist = hist4[w];
#pragma unroll
  for (int z = 0; z < 4; ++z) hist[l + z * 64] = 0u;
  const unsigned int pfx8 = prefix >> 8;
#pragma unroll
  for (int j = 0; j < W; ++j) {
    unsigned int k2 = kw[j];
    unsigned int lo = k2 & 0xFFFFu, hi = k2 >> 16;
    if ((lo >> 8) == pfx8) atomicAdd(&hist[lo & 255u], 1u);
    if ((hi >> 8) == pfx8) atomicAdd(&hist[hi & 255u], 1u);
  }
  unsigned int b2;
  int ceq = 0;
  radix_sel(hist, l, kk, ceq, b2);
  const unsigned int Tkey = prefix | b2;
  const int need = kk;
  if (need < ceq) {   // ties at threshold: keep lowest indices (jax order)
    int seen = 0;
    unsigned long long below = (1ull << l) - 1ull;
#pragma unroll
    for (int j = 0; j < W; ++j) {
      unsigned int k2 = kw[j];
      bool eq0 = ((k2 & 0xFFFFu) == Tkey);
      bool eq1 = ((k2 >> 16) == Tkey);
      unsigned long long m0 = __ballot(eq0), m1 = __ballot(eq1);
      int bfr = __popcll(m0 & below) + __popcll(m1 & below);
      if (eq0 && (seen + bfr) >= need) kw[j] &= 0xFFFF0000u;
      if (eq1 && (seen + bfr + (eq0 ? 1 : 0)) >= need) kw[j] &= 0x0000FFFFu;
      seen += __popcll(m0) + __popcll(m1);
    }
  }

  // ---- Phase C: exp over selected (key >= Tkey), write bf16 weights back ----
  {
    float rm = fmaxf(fmaxf(wavemax[0][w], wavemax[1][w]),
                     fmaxf(wavemax[2][w], wavemax[3][w]));
    float sum = 0.f;
#pragma unroll
    for (int j = 0; j < W; ++j) {
      unsigned int k2 = kw[j];
      unsigned int lo = k2 & 0xFFFFu, hi = k2 >> 16;
      unsigned int mm = ((~k2 >> 15) & 0x00010001u) * 0x7fffu + 0x80008000u;
      unsigned int o2 = k2 ^ mm;   // back to bf16 bits
      float v0 = bf2f(o2 & 0xFFFFu);
      float v1 = bf2f(o2 >> 16);
      float w0 = (lo >= Tkey) ? __expf(v0 - rm) : 0.f;
      float w1 = (hi >= Tkey) ? __expf(v1 - rm) : 0.f;
      sp[j * 64 + l] = pk_bf16(w0, w1);
      sum += w0 + w1;
    }
#pragma unroll
    for (int off = 32; off; off >>= 1) sum += __shfl_xor(sum, off, 64);
    if (l == 0) rowinv[w] = 1.f / sum;
  }
  __syncthreads();

  // ---- Phase D: PV via MFMA, pipelined V/weight loads; wave w -> dims [16w,16w+16) ----
  const unsigned short* vrow = vt + (size_t)bh * Dd * NK + (size_t)(w * 16 + m) * NK + quad * 8;
  f32x4 o = {0.f, 0.f, 0.f, 0.f};
  bf16x8 bcur = *(const bf16x8*)vrow;
  bf16x8 acur = {0,0,0,0,0,0,0,0};
  if (m < 4) acur = *(const bf16x8*)&sc16[m][quad * 8];
  for (int c = 0; c < NK / 32; ++c) {
    bf16x8 bnext, anext = {0,0,0,0,0,0,0,0};
    if (c + 1 < NK / 32) {
      bnext = *(const bf16x8*)(vrow + (c + 1) * 32);
      if (m < 4) anext = *(const bf16x8*)&sc16[m][(c + 1) * 32 + quad * 8];
    }
    o = __builtin_amdgcn_mfma_f32_16x16x32_bf16(acur, bcur, o, 0, 0, 0);
    bcur = bnext; acur = anext;
  }
  if (l < 16) {
#pragma unroll
    for (int r = 0; r < 4; ++r) {
      int n = nofs + rb * 4 + r;
      xo[((size_t)b * NNtok + n) * DIMc + h * 64 + w * 16 + l] = o[r] * rowinv[r];
    }
  }
}

// ---------------- host ----------------
extern "C" void kernel_launch(void* const* d_in, const int* in_sizes, int n_in,
                              void* d_out, int out_size, void* d_ws, size_t ws_size,
                              hipStream_t stream)
{
  const float* x       = (const float*)d_in[0];
  const float* id_tot  = (const float*)d_in[1];
  const float* mem_k   = (const float*)d_in[2];
  const float* mem_v   = (const float*)d_in[3];
  const float* W_qkv   = (const float*)d_in[4];
  const float* b_qkv   = (const float*)d_in[5];
  const float* qkv_A   = (const float*)d_in[6];
  const float* qkv_B   = (const float*)d_in[7];
  const float* W_proj  = (const float*)d_in[8];
  const float* b_proj  = (const float*)d_in[9];
  const float* route_W = (const float*)d_in[10];
  const float* proj_A  = (const float*)d_in[11];
  const float* proj_B  = (const float*)d_in[12];
  const float* W_idk   = (const float*)d_in[13];
  const float* b_idk   = (const float*)d_in[14];
  const float* idk_A   = (const float*)d_in[15];
  const float* idk_B   = (const float*)d_in[16];
  const float* W_idv   = (const float*)d_in[17];
  const float* b_idv   = (const float*)d_in[18];
  const float* idv_A   = (const float*)d_in[19];
  const float* idv_B   = (const float*)d_in[20];

  float* ws   = (float*)d_ws;
  float* vb   = ws + OVb;
  float* xo   = ws + OXO;
  float* qlow = ws + OQL;
  float* IDK  = ws + OIDK;
  float* IDV  = ws + OIDV;
  float* lowk = ws + OLK;
  float* lowv = ws + OLV;
  float* rd   = ws + ORD;
  float* plow = ws + OPL;
  unsigned short* qh   = (unsigned short*)(ws + OQH);
  unsigned short* kfh  = (unsigned short*)(ws + OKFH);
  unsigned short* vth  = (unsigned short*)(ws + OVTH);
  unsigned short* kmh  = (unsigned short*)(ws + OKMH);
  unsigned short* vmth = (unsigned short*)(ws + OVMTH);
  unsigned short* Aa   = (unsigned short*)(ws + OAa);
  unsigned short* Wa   = (unsigned short*)(ws + OWa);
  unsigned short* Wa2  = (unsigned short*)(ws + OWa2);

  float* out  = (float*)d_out;
  float* kmid = out + KMID_OFF;
  float* vmid = out + VMID_OFF;

  // staging: mem_k cast, mem_v transpose, both W_aug builds — one launch
  prep<<<7680, 256, 0, stream>>>(mem_k, mem_v, W_qkv, qkv_B, W_proj, proj_B,
                                 kfh, vth, Wa, Wa2);

  // LoRA downs
  dot_small<<<1280, 256, 0, stream>>>(x, qkv_A, qlow, 24);
  dot_id<<<256, 256, 0, stream>>>(id_tot, idk_A, idv_A, lowk, lowv);

  // QKV via MFMA with augmented K (fused LoRA)
  cast_pack<<<2000, 256, 0, stream>>>(x, qlow, Aa, 24);
  gemm_mfma<<<dim3(18, 40), 256, 0, stream>>>(Aa, Wa, b_qkv, 0, nullptr,
                                              qh, kmid, vb, kfh);
  // ID_V (fp32), ID_K
  gemm_idv<<<dim3(12, 16), 256, 0, stream>>>(id_tot, W_idv, b_idv, lowv, idv_B, IDV);
  idk_kernel<<<256, 256, 0, stream>>>(id_tot, W_idk, b_idk, lowk, idk_B, IDK);
  // outputs k_m_id / v_m_id; vb rows 0-255 updated in place
  fixup_kernel<<<3072, 256, 0, stream>>>(vb, IDK, IDV, kmid, vmid, kmh);

  // V^T bf16 staging (post-fixup)
  transpose_post<<<1152, 256, 0, stream>>>(vb, vth, vmth);

  // attention (XCD-swizzled grids: blockIdx = rb*48 + bh)
  attn_mfma4<256><<<3072, 256, 0, stream>>>(qh, kmh, vmth, 128, 0, xo, 0);
  attn_mfma4<2560><<<12288, 256, 0, stream>>>(qh, kfh, vth, 640, 256, xo, 256);

  // routed output projection
  dot_rp<<<1280, 256, 0, stream>>>(xo, route_W, proj_A, rd, plow);
  cast_pack_proj<<<2000, 256, 0, stream>>>(xo, rd, plow, Aa);
  gemm_mfma<<<dim3(6, 40), 256, 0, stream>>>(Aa, Wa2, b_proj, 2, out,
                                             nullptr, nullptr, nullptr, nullptr);
}

// Round 8
// 1022.602 us; speedup vs baseline: 3.9637x; 1.3312x over previous
//
#include <hip/hip_runtime.h>
#include <cstddef>

// ---------------- problem constants ----------------
#define Bq    4
#define Hh    12
#define Dd    64
#define NNtok 1280
#define DIMc  768
#define KAUG  800      // 768 + 32 augmented-K for fused LoRA
#define NBH   48       // Bq*Hh

typedef __attribute__((ext_vector_type(8))) short bf16x8;
typedef __attribute__((ext_vector_type(4))) float f32x4;

// workspace offsets (floats)
static const size_t OVb   = 0;                   // vb fp32 (B,H,1280,64); rows 0-255 -> v_add_id
static const size_t OXO   = 3932160;             // xo fp32 (B,1280,768)
static const size_t OQL   = 7864320;             // qkv low (5120,24)
static const size_t OIDK  = 7987200;             // 1+tanh(ID_K) (1024,12)
static const size_t OIDV  = 7999488;             // ID_V (1024,768)
static const size_t OLK   = 8785920;             // id_lowk (1024,8)
static const size_t OLV   = 8794112;             // id_lowv (1024,8)
static const size_t ORD   = 8802304;             // route dots (5120,4)
static const size_t OPL   = 8822784;             // proj low (5120,32)
static const size_t OQH   = 8986624;             // qh bf16 (B,H,1280,64)
static const size_t OKFH  = 10952704;            // kfh bf16 (B,H,2560,64) [mem_k|k]
static const size_t OVTH  = 14884864;            // vth bf16 (B,H,64,2560)
static const size_t OKMH  = 18817024;            // kmh bf16 (B,H,256,64)
static const size_t OVMTH = 19210240;            // vmth bf16 (B,H,64,256)
static const size_t OAa   = 19603456;            // A_aug bf16 (5120,800)
static const size_t OWa   = 21651456;            // W_aug qkv bf16 (2304,800)
static const size_t OWa2  = 22573056;            // W_aug proj bf16 (768,800)

// d_out offsets (floats)
static const size_t KMID_OFF = 3932160;
static const size_t VMID_OFF = 4718592;

__device__ __forceinline__ unsigned int pk_bf16(float a, float b) {  // RNE pack
  unsigned int ua = __float_as_uint(a), ub = __float_as_uint(b);
  ua += 0x7fffu + ((ua >> 16) & 1u);
  ub += 0x7fffu + ((ub >> 16) & 1u);
  return (ua >> 16) | (ub & 0xffff0000u);
}
__device__ __forceinline__ unsigned short bf16_1(float a) {
  unsigned int ua = __float_as_uint(a);
  ua += 0x7fffu + ((ua >> 16) & 1u);
  return (unsigned short)(ua >> 16);
}
__device__ __forceinline__ float bf2f(unsigned int h) {
  return __uint_as_float(h << 16);
}

// ---------------- prep: cast_k | transpose(mem_v) | cast_w_qkv | cast_w_proj ----------------
__global__ __launch_bounds__(256) void prep(
    const float* __restrict__ mem_k, const float* __restrict__ mem_v,
    const float* __restrict__ W_qkv, const float* __restrict__ qkvB,
    const float* __restrict__ W_proj, const float* __restrict__ projB,
    unsigned short* __restrict__ kfh, unsigned short* __restrict__ vth,
    unsigned short* __restrict__ Wa, unsigned short* __restrict__ Wa2)
{
  __shared__ float tl[64][65];
  const int blk = blockIdx.x, t = threadIdx.x;
  if (blk < 1920) {                       // cast mem_k -> kfh rows 0..1279
    size_t idx = ((size_t)blk * 256 + t) * 8;
    int bh = (int)(idx / 81920);
    int r  = (int)(idx % 81920);
    const float* s = mem_k + (size_t)bh * 81920 + r;
    float4 a = *(const float4*)s;
    float4 b = *(const float4*)(s + 4);
    unsigned int* dp = (unsigned int*)(kfh + (size_t)bh * 163840 + r);
    dp[0] = pk_bf16(a.x, a.y); dp[1] = pk_bf16(a.z, a.w);
    dp[2] = pk_bf16(b.x, b.y); dp[3] = pk_bf16(b.z, b.w);
  } else if (blk < 2880) {                // transpose mem_v -> vth cols 0..1279
    int b2 = blk - 1920;
    int bh = b2 / 20, t0 = (b2 % 20) * 64;
    const float* sb = mem_v + (size_t)bh * 81920 + (size_t)t0 * 64;
#pragma unroll
    for (int p = 0; p < 4; ++p) {
      int flat = p * 256 + t;
      int r = flat >> 4, c4 = (flat & 15) << 2;
      float4 v = *(const float4*)(sb + r * 64 + c4);
      tl[r][c4 + 0] = v.x; tl[r][c4 + 1] = v.y;
      tl[r][c4 + 2] = v.z; tl[r][c4 + 3] = v.w;
    }
    __syncthreads();
    unsigned short* db = vth + (size_t)bh * 163840 + t0;
#pragma unroll
    for (int p = 0; p < 8; ++p) {
      int flat = p * 256 + t;
      int d = flat >> 5, u = flat & 31;
      *(unsigned int*)(db + (size_t)d * 2560 + 2 * u) = pk_bf16(tl[2 * u][d], tl[2 * u + 1][d]);
    }
  } else if (blk < 6480) {                // W_aug qkv
    int idx = (blk - 2880) * 256 + t;     // 2304*400 uint pairs
    int row = idx / 400, c = (idx % 400) * 2;
    float a, b;
    if (c < 768) {
      a = W_qkv[(size_t)row * 768 + c]; b = W_qkv[(size_t)row * 768 + c + 1];
    } else {
      int g = row / 768, jj = row % 768;
      int e0 = c - 768, e1 = e0 + 1;
      a = (e0 < 24 && (e0 >> 3) == g) ? qkvB[(size_t)g * 6144 + jj * 8 + (e0 & 7)] * 0.125f : 0.f;
      b = (e1 < 24 && (e1 >> 3) == g) ? qkvB[(size_t)g * 6144 + jj * 8 + (e1 & 7)] * 0.125f : 0.f;
    }
    *(unsigned int*)(Wa + (size_t)row * KAUG + c) = pk_bf16(a, b);
  } else {                                // W_aug proj
    int idx = (blk - 6480) * 256 + t;     // 768*400
    int row = idx / 400, c = (idx % 400) * 2;
    float a, b;
    if (c < 768) {
      a = W_proj[(size_t)row * 768 + c]; b = W_proj[(size_t)row * 768 + c + 1];
    } else {
      int e0 = c - 768, e1 = e0 + 1;
      a = projB[(size_t)(e0 >> 3) * 6144 + row * 8 + (e0 & 7)];
      b = projB[(size_t)(e1 >> 3) * 6144 + row * 8 + (e1 & 7)];
    }
    *(unsigned int*)(Wa2 + (size_t)row * KAUG + c) = pk_bf16(a, b);
  }
}

// ---------------- small row-dot kernel ----------------
__global__ __launch_bounds__(256) void dot_small(
    const float* __restrict__ src, const float* __restrict__ mat,
    float* __restrict__ dst, int nout)
{
  int wv = threadIdx.x >> 6, ln = threadIdx.x & 63;
  size_t row = (size_t)blockIdx.x * 4 + wv;
  const float* s = src + row * DIMc;
  for (int o = 0; o < nout; ++o) {
    float p = 0.f;
    const float* m = mat + (size_t)o * DIMc;
    for (int c = ln; c < DIMc; c += 64) p += s[c] * m[c];
    for (int off = 32; off; off >>= 1) p += __shfl_xor(p, off, 64);
    if (ln == 0) dst[row * nout + o] = p;
  }
}

// ---------------- fused id lora downs: lowk(8) + lowv(8) ----------------
__global__ __launch_bounds__(256) void dot_id(
    const float* __restrict__ id_tot, const float* __restrict__ idkA,
    const float* __restrict__ idvA, float* __restrict__ lowk,
    float* __restrict__ lowv)
{
  int wv = threadIdx.x >> 6, ln = threadIdx.x & 63;
  size_t row = (size_t)blockIdx.x * 4 + wv;
  const float* s = id_tot + row * DIMc;
  for (int o = 0; o < 8; ++o) {
    float p = 0.f, q = 0.f;
    const float* m1 = idkA + (size_t)o * DIMc;
    const float* m2 = idvA + (size_t)o * DIMc;
    for (int c = ln; c < DIMc; c += 64) { p += s[c] * m1[c]; q += s[c] * m2[c]; }
    for (int off = 32; off; off >>= 1) { p += __shfl_xor(p, off, 64); q += __shfl_xor(q, off, 64); }
    if (ln == 0) { lowk[row * 8 + o] = p; lowv[row * 8 + o] = q; }
  }
}

// ---------------- fused route+plow dots ----------------
__global__ __launch_bounds__(256) void dot_rp(
    const float* __restrict__ xo, const float* __restrict__ routeW,
    const float* __restrict__ projA, float* __restrict__ rd,
    float* __restrict__ plow)
{
  int wv = threadIdx.x >> 6, ln = threadIdx.x & 63;
  size_t row = (size_t)blockIdx.x * 4 + wv;
  const float* s = xo + row * DIMc;
  float xr[12];
#pragma unroll
  for (int i = 0; i < 12; ++i) xr[i] = s[ln + i * 64];
  for (int o = 0; o < 4; ++o) {
    float p = 0.f;
    const float* m = routeW + (size_t)o * DIMc;
#pragma unroll
    for (int i = 0; i < 12; ++i) p += xr[i] * m[ln + i * 64];
    for (int off = 32; off; off >>= 1) p += __shfl_xor(p, off, 64);
    if (ln == 0) rd[row * 4 + o] = p;
  }
  for (int o = 0; o < 32; ++o) {
    float p = 0.f;
    const float* m = projA + (size_t)o * DIMc;
#pragma unroll
    for (int i = 0; i < 12; ++i) p += xr[i] * m[ln + i * 64];
    for (int off = 32; off; off >>= 1) p += __shfl_xor(p, off, 64);
    if (ln == 0) plow[row * 32 + o] = p;
  }
}

// ---------------- ID_K: 1+tanh(lora1(...)) ----------------
__global__ __launch_bounds__(256) void idk_kernel(
    const float* __restrict__ id_tot, const float* __restrict__ W_idk,
    const float* __restrict__ b_idk, const float* __restrict__ lowk,
    const float* __restrict__ idk_B, float* __restrict__ IDK)
{
  int wv = threadIdx.x >> 6, ln = threadIdx.x & 63;
  size_t row = (size_t)blockIdx.x * 4 + wv;
  const float* s = id_tot + row * DIMc;
  for (int h = 0; h < Hh; ++h) {
    float p = 0.f;
    const float* m = W_idk + (size_t)h * DIMc;
    for (int c = ln; c < DIMc; c += 64) p += s[c] * m[c];
    for (int off = 32; off; off >>= 1) p += __shfl_xor(p, off, 64);
    if (ln == 0) {
      float lo = 0.f;
      for (int r = 0; r < 8; ++r) lo += lowk[row * 8 + r] * idk_B[h * 8 + r];
      IDK[row * Hh + h] = 1.f + tanhf(p + b_idk[h] + lo * 0.125f);
    }
  }
}

// ---------------- fixup: kmid holds raw k; multiply by IDK in place; v add IDV ----------------
__global__ __launch_bounds__(256) void fixup_kernel(
    float* __restrict__ vb, const float* __restrict__ IDK,
    const float* __restrict__ IDV, float* __restrict__ kmid,
    float* __restrict__ vmid, unsigned short* __restrict__ kmh)
{
  int e = blockIdx.x * 256 + threadIdx.x;   // flat (b,h,tt,d), tt<256
  int d  = e & 63;
  int r1 = e >> 6;
  int tt = r1 & 255;
  int r2 = r1 >> 8;
  int h  = r2 % Hh;
  int b  = r2 / Hh;
  float km = kmid[e] * IDK[(size_t)(b * 256 + tt) * Hh + h];
  kmid[e] = km;
  kmh[e] = bf16_1(km);
  size_t src = ((size_t)(b * Hh + h) * NNtok + tt) * Dd + d;
  float vv = vb[src] + IDV[(size_t)(b * 256 + tt) * DIMc + h * 64 + d];
  vb[src] = vv;
  vmid[e] = vv;
}

// ---------------- post-fixup transposes ----------------
__global__ __launch_bounds__(256) void transpose_post(
    const float* __restrict__ vb, unsigned short* __restrict__ vth,
    unsigned short* __restrict__ vmth)
{
  __shared__ float tl[64][65];
  const int blk = blockIdx.x, t = threadIdx.x;
  int bh, t0, dstCols, colOfs;
  unsigned short* dstp;
  size_t dstBh;
  if (blk < 960) { bh = blk / 20; t0 = (blk % 20) * 64; dstp = vth; dstBh = 163840; dstCols = 2560; colOfs = 1280; }
  else { int b2 = blk - 960; bh = b2 / 4; t0 = (b2 % 4) * 64; dstp = vmth; dstBh = 16384; dstCols = 256; colOfs = 0; }
  const float* sb = vb + (size_t)bh * 81920 + (size_t)t0 * 64;
#pragma unroll
  for (int p = 0; p < 4; ++p) {
    int flat = p * 256 + t;
    int r = flat >> 4, c4 = (flat & 15) << 2;
    float4 v = *(const float4*)(sb + r * 64 + c4);
    tl[r][c4 + 0] = v.x; tl[r][c4 + 1] = v.y;
    tl[r][c4 + 2] = v.z; tl[r][c4 + 3] = v.w;
  }
  __syncthreads();
  unsigned short* db = dstp + (size_t)bh * dstBh + colOfs + t0;
#pragma unroll
  for (int p = 0; p < 8; ++p) {
    int flat = p * 256 + t;
    int d = flat >> 5, u = flat & 31;
    *(unsigned int*)(db + (size_t)d * dstCols + 2 * u) = pk_bf16(tl[2 * u][d], tl[2 * u + 1][d]);
  }
}

// ---------------- pack A_aug for qkv ----------------
__global__ __launch_bounds__(256) void cast_pack(
    const float* __restrict__ mainp, const float* __restrict__ extra,
    unsigned short* __restrict__ dst, int extraN)
{
  int idx = blockIdx.x * 256 + threadIdx.x;    // 5120*100 groups of 8
  int row = idx / 100, c8 = (idx % 100) * 8;
  unsigned int w[4];
  if (c8 < 768) {
    const float* s = mainp + (size_t)row * 768 + c8;
    float4 a = *(const float4*)s;
    float4 b = *(const float4*)(s + 4);
    w[0] = pk_bf16(a.x, a.y); w[1] = pk_bf16(a.z, a.w);
    w[2] = pk_bf16(b.x, b.y); w[3] = pk_bf16(b.z, b.w);
  } else {
    float v[8];
#pragma unroll
    for (int j = 0; j < 8; ++j) {
      int e = c8 - 768 + j;
      v[j] = (e < extraN) ? extra[(size_t)row * extraN + e] : 0.f;
    }
    w[0] = pk_bf16(v[0], v[1]); w[1] = pk_bf16(v[2], v[3]);
    w[2] = pk_bf16(v[4], v[5]); w[3] = pk_bf16(v[6], v[7]);
  }
  *(uint4*)(dst + (size_t)row * KAUG + c8) = make_uint4(w[0], w[1], w[2], w[3]);
}

// ---------------- pack A_aug for proj (inline softmax(rd)*plow/8) ----------------
__global__ __launch_bounds__(256) void cast_pack_proj(
    const float* __restrict__ xo, const float* __restrict__ rd,
    const float* __restrict__ plow, unsigned short* __restrict__ dst)
{
  int idx = blockIdx.x * 256 + threadIdx.x;
  int row = idx / 100, c8 = (idx % 100) * 8;
  unsigned int w[4];
  if (c8 < 768) {
    const float* s = xo + (size_t)row * 768 + c8;
    float4 a = *(const float4*)s;
    float4 b = *(const float4*)(s + 4);
    w[0] = pk_bf16(a.x, a.y); w[1] = pk_bf16(a.z, a.w);
    w[2] = pk_bf16(b.x, b.y); w[3] = pk_bf16(b.z, b.w);
  } else {
    float l0 = rd[row * 4 + 0], l1 = rd[row * 4 + 1], l2 = rd[row * 4 + 2], l3 = rd[row * 4 + 3];
    float m = fmaxf(fmaxf(l0, l1), fmaxf(l2, l3));
    float e0 = __expf(l0 - m), e1 = __expf(l1 - m), e2 = __expf(l2 - m), e3 = __expf(l3 - m);
    float inv = 0.125f / (e0 + e1 + e2 + e3);
    float rt[4] = { e0 * inv, e1 * inv, e2 * inv, e3 * inv };
    float v[8];
#pragma unroll
    for (int j = 0; j < 8; ++j) {
      int e = c8 - 768 + j;
      v[j] = (e < 32) ? rt[e >> 3] * plow[(size_t)row * 32 + e] : 0.f;
    }
    w[0] = pk_bf16(v[0], v[1]); w[1] = pk_bf16(v[2], v[3]);
    w[2] = pk_bf16(v[4], v[5]); w[3] = pk_bf16(v[6], v[7]);
  }
  *(uint4*)(dst + (size_t)row * KAUG + c8) = make_uint4(w[0], w[1], w[2], w[3]);
}

// ---------------- MFMA GEMM: C = A_aug @ W_aug^T + bias, K=800 ----------------
__global__ __launch_bounds__(256) void gemm_mfma(
    const unsigned short* __restrict__ A, const unsigned short* __restrict__ W,
    const float* __restrict__ bias, int mode, float* __restrict__ dst,
    unsigned short* __restrict__ qh, float* __restrict__ kmid,
    float* __restrict__ vb, unsigned short* __restrict__ kfh)
{
  const int t = threadIdx.x, w = t >> 6, l = t & 63;
  const int m = l & 15, quad = l >> 4;
  const int bm = blockIdx.y * 128 + (w >> 1) * 64;
  const int bn = blockIdx.x * 128 + (w & 1) * 64;
  f32x4 acc[4][4] = {};
  const unsigned short* Ab = A + (size_t)(bm + m) * KAUG;
  const unsigned short* Wb = W + (size_t)(bn + m) * KAUG;
  for (int kk = 0; kk < KAUG; kk += 32) {
    bf16x8 af[4], bf[4];
#pragma unroll
    for (int i = 0; i < 4; ++i) af[i] = *(const bf16x8*)(Ab + (size_t)i * 16 * KAUG + kk + quad * 8);
#pragma unroll
    for (int j = 0; j < 4; ++j) bf[j] = *(const bf16x8*)(Wb + (size_t)j * 16 * KAUG + kk + quad * 8);
#pragma unroll
    for (int i = 0; i < 4; ++i)
#pragma unroll
      for (int j = 0; j < 4; ++j)
        acc[i][j] = __builtin_amdgcn_mfma_f32_16x16x32_bf16(af[i], bf[j], acc[i][j], 0, 0, 0);
  }

  float bj[4];
#pragma unroll
  for (int j = 0; j < 4; ++j) bj[j] = bias[bn + j * 16 + m];

  if (mode == 2) {
#pragma unroll
    for (int i = 0; i < 4; ++i)
#pragma unroll
      for (int r = 0; r < 4; ++r) {
        int row = bm + i * 16 + quad * 4 + r;
#pragma unroll
        for (int j = 0; j < 4; ++j)
          dst[(size_t)row * 768 + bn + j * 16 + m] = acc[i][j][r] + bj[j];
      }
    return;
  }
  int g = (blockIdx.x * 128) / DIMc;           // uniform per block
#pragma unroll
  for (int j = 0; j < 4; ++j) {
    int col = bn + j * 16 + m;
    int jj = col - g * DIMc, hh = jj >> 6, d = jj & 63;
#pragma unroll
    for (int i = 0; i < 4; ++i)
#pragma unroll
      for (int r = 0; r < 4; ++r) {
        int row = bm + i * 16 + quad * 4 + r;
        int bb = row / NNtok, tt = row % NNtok;
        float v = acc[i][j][r] + bj[j];
        if (g == 0) {
          qh[((size_t)(bb * Hh + hh) * NNtok + tt) * Dd + d] = bf16_1(v * 0.125f);
        } else if (g == 1) {
          kfh[((size_t)(bb * Hh + hh) * 2560 + 1280 + tt) * Dd + d] = bf16_1(v);
          if (tt < 256) kmid[((size_t)(bb * Hh + hh) * 256 + tt) * Dd + d] = v;
        } else {
          vb[((size_t)(bb * Hh + hh) * NNtok + tt) * Dd + d] = v;
        }
      }
  }
}

// ---------------- fp32 GEMM for ID_V ----------------
__global__ __launch_bounds__(256) void gemm_idv(
    const float* __restrict__ A, const float* __restrict__ W,
    const float* __restrict__ bias, const float* __restrict__ low,
    const float* __restrict__ Bl, float* __restrict__ dst)
{
  __shared__ alignas(16) float As[16][68];
  __shared__ alignas(16) float Bs[16][68];
  const int t  = threadIdx.x;
  const int tx = t & 15, ty = t >> 4;
  const int bn = blockIdx.x * 64, bm = blockIdx.y * 64;
  const int am = t >> 2, ak = (t & 3) << 2;
  float acc[4][4] = {};
  for (int k0 = 0; k0 < 768; k0 += 16) {
    float4 av = *(const float4*)(A + (size_t)(bm + am) * 768 + k0 + ak);
    float4 bv = *(const float4*)(W + (size_t)(bn + am) * 768 + k0 + ak);
    As[ak + 0][am] = av.x; As[ak + 1][am] = av.y; As[ak + 2][am] = av.z; As[ak + 3][am] = av.w;
    Bs[ak + 0][am] = bv.x; Bs[ak + 1][am] = bv.y; Bs[ak + 2][am] = bv.z; Bs[ak + 3][am] = bv.w;
    __syncthreads();
#pragma unroll
    for (int kk = 0; kk < 16; ++kk) {
      float4 a4 = *(const float4*)&As[kk][ty << 2];
      float4 b4 = *(const float4*)&Bs[kk][tx << 2];
      float ar[4] = { a4.x, a4.y, a4.z, a4.w };
      float br[4] = { b4.x, b4.y, b4.z, b4.w };
#pragma unroll
      for (int i = 0; i < 4; ++i)
#pragma unroll
        for (int j = 0; j < 4; ++j) acc[i][j] += ar[i] * br[j];
    }
    __syncthreads();
  }
#pragma unroll
  for (int i = 0; i < 4; ++i) {
    int mg = bm + (ty << 2) + i;
#pragma unroll
    for (int j = 0; j < 4; ++j) {
      int col = bn + (tx << 2) + j;
      float v = acc[i][j] + bias[col];
      float lo = 0.f;
#pragma unroll
      for (int r = 0; r < 8; ++r) lo += low[(size_t)mg * 8 + r] * Bl[(size_t)col * 8 + r];
      dst[(size_t)mg * 768 + col] = v + lo * 0.125f;
    }
  }
}

// ---------------- radix helper: select bin from per-wave 256-bin hist ----------------
__device__ __forceinline__ void radix_sel(
    unsigned int* hist, int l, int& kk, int& ceq, unsigned int& bin)
{
  unsigned int h0 = hist[4 * l + 0], h1 = hist[4 * l + 1],
               h2 = hist[4 * l + 2], h3 = hist[4 * l + 3];
  unsigned int s3 = h3, s2 = h2 + s3, s1 = h1 + s2, s0 = h0 + s1;
  unsigned int tsum = s0;
#pragma unroll
  for (int off = 1; off < 64; off <<= 1) {
    unsigned int other = __shfl(tsum, l + off, 64);
    tsum += (l + off < 64) ? other : 0u;
  }
  unsigned int T = tsum - s0;   // suffix over lanes > l
  unsigned int Sv0 = T + s0, Sv1 = T + s1, Sv2 = T + s2, Sv3 = T + s3, Sv4 = T;
  int fb = -1, fkk = 0, fceq = 0;
  unsigned int ukk = (unsigned int)kk;
  if (Sv0 >= ukk && Sv1 < ukk) { fb = 4 * l + 0; fkk = (int)(ukk - Sv1); fceq = (int)(Sv0 - Sv1); }
  if (Sv1 >= ukk && Sv2 < ukk) { fb = 4 * l + 1; fkk = (int)(ukk - Sv2); fceq = (int)(Sv1 - Sv2); }
  if (Sv2 >= ukk && Sv3 < ukk) { fb = 4 * l + 2; fkk = (int)(ukk - Sv3); fceq = (int)(Sv2 - Sv3); }
  if (Sv3 >= ukk && Sv4 < ukk) { fb = 4 * l + 3; fkk = (int)(ukk - Sv4); fceq = (int)(Sv3 - Sv4); }
  unsigned long long mb = __ballot(fb >= 0);
  int src = __ffsll(mb) - 1;
  bin = (unsigned int)__shfl(fb, src, 64);
  kk  = __shfl(fkk, src, 64);
  ceq = __shfl(fceq, src, 64);
}

// ---------------- MFMA top-k attention v5: 8 q-rows per block (half K/V traffic) ----------------
// Phase A: QK^T with A rows 0-7 = q rows (quads 0,1 carry results).
// Phase B/C: wave w radix-selects rows 2w, 2w+1 serially (2-stage radix).
// Phase D: PV with A rows 0-7 = weight rows.
template<int NK>
__global__ __launch_bounds__(256, 3) void attn_mfma5(
    const unsigned short* __restrict__ qh,   // (bh,1280,64) bf16
    const unsigned short* __restrict__ kf,   // (bh,NK,64)   bf16
    const unsigned short* __restrict__ vt,   // (bh,64,NK)   bf16 (V^T)
    int TK, int qrow0, float* __restrict__ xo, int nofs)
{
  constexpr int SCP = NK + 8;
  constexpr int W = NK / 128;          // score words per lane per row
  __shared__ alignas(16) unsigned short sc16[8][SCP];
  __shared__ unsigned int hist4[4][256];
  __shared__ float wavemax[4][8];
  __shared__ float rowinv[8];

  const int t = threadIdx.x, w = t >> 6, l = t & 63;
  const int bh = blockIdx.x % NBH;
  const int rb = blockIdx.x / NBH;
  const int b = bh / Hh, h = bh % Hh;
  const int qbase = qrow0 + rb * 8;
  const int m = l & 15, quad = l >> 4;

  // ---- Phase A: QK^T via MFMA (A rows 0-7 = q), pipelined K, running max ----
  bf16x8 aq0 = {0,0,0,0,0,0,0,0}, aq1 = {0,0,0,0,0,0,0,0};
  if (m < 8) {
    const unsigned short* qp = qh + ((size_t)bh * NNtok + qbase + m) * Dd + quad * 8;
    aq0 = *(const bf16x8*)qp;
    aq1 = *(const bf16x8*)(qp + 32);
  }
  float mx[4] = { -3.0e38f, -3.0e38f, -3.0e38f, -3.0e38f };  // rows quad*4+r
  const unsigned short* kp = kf + (size_t)bh * NK * Dd + (size_t)(w * 16 + m) * Dd + quad * 8;
  bf16x8 c0 = *(const bf16x8*)kp;
  bf16x8 c1 = *(const bf16x8*)(kp + 32);
  for (int n0 = w * 16; n0 < NK; n0 += 64) {
    kp += 64 * Dd;
    bf16x8 p0, p1;
    if (n0 + 64 < NK) {
      p0 = *(const bf16x8*)kp;
      p1 = *(const bf16x8*)(kp + 32);
    }
    f32x4 acc = {0.f, 0.f, 0.f, 0.f};
    acc = __builtin_amdgcn_mfma_f32_16x16x32_bf16(aq0, c0, acc, 0, 0, 0);
    acc = __builtin_amdgcn_mfma_f32_16x16x32_bf16(aq1, c1, acc, 0, 0, 0);
    if (quad < 2) {      // lanes 0-31 hold rows 0-7 (row = quad*4+reg), col = n0+m
#pragma unroll
      for (int r = 0; r < 4; ++r) {
        float v = acc[r];
        mx[r] = fmaxf(mx[r], v);
        sc16[quad * 4 + r][n0 + m] = bf16_1(v);
      }
    }
    c0 = p0; c1 = p1;
  }
#pragma unroll
  for (int off = 1; off < 16; off <<= 1)
#pragma unroll
    for (int r = 0; r < 4; ++r) mx[r] = fmaxf(mx[r], __shfl_xor(mx[r], off, 64));
  if (l == 0) {
#pragma unroll
    for (int r = 0; r < 4; ++r) wavemax[w][r] = mx[r];
  }
  if (l == 16) {
#pragma unroll
    for (int r = 0; r < 4; ++r) wavemax[w][4 + r] = mx[r];
  }
  __syncthreads();

  // ---- Phase B/C: wave w selects rows 2w, 2w+1 (serial) ----
  for (int sub = 0; sub < 2; ++sub) {
    const int row = w * 2 + sub;
    unsigned int* sp = (unsigned int*)&sc16[row][0];
    unsigned int kw[W];
#pragma unroll
    for (int j = 0; j < W; ++j) {
      unsigned int v = sp[j * 64 + l];
      unsigned int mm = ((v >> 15) & 0x00010001u) * 0x7fffu + 0x80008000u;
      kw[j] = v ^ mm;   // bf16 -> monotone u16, both halves
    }
    // stage 1: bit-plane on bits 15..8
    unsigned int prefix = 0;
    int kk = TK;
#pragma unroll 1
    for (int bit = 15; bit >= 8; --bit) {
      unsigned int hmask = (0xFFFFu << bit) & 0xFFFFu;
      unsigned int cand  = prefix | (1u << bit);
      int cnt = 0;
#pragma unroll
      for (int j = 0; j < W; ++j) {
        unsigned int k2 = kw[j];
        cnt += __popcll(__ballot((k2 & hmask) == cand));
        cnt += __popcll(__ballot(((k2 >> 16) & hmask) == cand));
      }
      if (cnt >= kk) prefix = cand; else kk -= cnt;
    }
    // stage 2: per-wave histogram of low byte among prefix-matching candidates
    unsigned int* hist = hist4[w];
#pragma unroll
    for (int z = 0; z < 4; ++z) hist[l + z * 64] = 0u;
    const unsigned int pfx8 = prefix >> 8;
#pragma unroll
    for (int j = 0; j < W; ++j) {
      unsigned int k2 = kw[j];
      unsigned int lo = k2 & 0xFFFFu, hi = k2 >> 16;
      if ((lo >> 8) == pfx8) atomicAdd(&hist[lo & 255u], 1u);
      if ((hi >> 8) == pfx8) atomicAdd(&hist[hi & 255u], 1u);
    }
    unsigned int b2;
    int ceq = 0;
    radix_sel(hist, l, kk, ceq, b2);
    const unsigned int Tkey = prefix | b2;
    const int need = kk;
    if (need < ceq) {   // ties at threshold: keep lowest indices (jax order)
      int seen = 0;
      unsigned long long below = (1ull << l) - 1ull;
#pragma unroll
      for (int j = 0; j < W; ++j) {
        unsigned int k2 = kw[j];
        bool eq0 = ((k2 & 0xFFFFu) == Tkey);
        bool eq1 = ((k2 >> 16) == Tkey);
        unsigned long long m0 = __ballot(eq0), m1 = __ballot(eq1);
        int bfr = __popcll(m0 & below) + __popcll(m1 & below);
        if (eq0 && (seen + bfr) >= need) kw[j] &= 0xFFFF0000u;
        if (eq1 && (seen + bfr + (eq0 ? 1 : 0)) >= need) kw[j] &= 0x0000FFFFu;
        seen += __popcll(m0) + __popcll(m1);
      }
    }
    // exp over selected, bf16 weights back in place
    float rm = fmaxf(fmaxf(wavemax[0][row], wavemax[1][row]),
                     fmaxf(wavemax[2][row], wavemax[3][row]));
    float sum = 0.f;
#pragma unroll
    for (int j = 0; j < W; ++j) {
      unsigned int k2 = kw[j];
      unsigned int lo = k2 & 0xFFFFu, hi = k2 >> 16;
      unsigned int mm = ((~k2 >> 15) & 0x00010001u) * 0x7fffu + 0x80008000u;
      unsigned int o2 = k2 ^ mm;   // back to bf16 bits
      float v0 = bf2f(o2 & 0xFFFFu);
      float v1 = bf2f(o2 >> 16);
      float w0 = (lo >= Tkey) ? __expf(v0 - rm) : 0.f;
      float w1 = (hi >= Tkey) ? __expf(v1 - rm) : 0.f;
      sp[j * 64 + l] = pk_bf16(w0, w1);
      sum += w0 + w1;
    }
#pragma unroll
    for (int off = 32; off; off >>= 1) sum += __shfl_xor(sum, off, 64);
    if (l == 0) rowinv[row] = 1.f / sum;
  }
  __syncthreads();

  // ---- Phase D: PV via MFMA (A rows 0-7 = weights), pipelined; wave w -> dims [16w,16w+16) ----
  const unsigned short* vrow = vt + (size_t)bh * Dd * NK + (size_t)(w * 16 + m) * NK + quad * 8;
  f32x4 o = {0.f, 0.f, 0.f, 0.f};
  bf16x8 bcur = *(const bf16x8*)vrow;
  bf16x8 acur = {0,0,0,0,0,0,0,0};
  if (m < 8) acur = *(const bf16x8*)&sc16[m][quad * 8];
  for (int c = 0; c < NK / 32; ++c) {
    bf16x8 bnext, anext = {0,0,0,0,0,0,0,0};
    if (c + 1 < NK / 32) {
      bnext = *(const bf16x8*)(vrow + (c + 1) * 32);
      if (m < 8) anext = *(const bf16x8*)&sc16[m][(c + 1) * 32 + quad * 8];
    }
    o = __builtin_amdgcn_mfma_f32_16x16x32_bf16(acur, bcur, o, 0, 0, 0);
    bcur = bnext; acur = anext;
  }
  if (quad < 2) {
#pragma unroll
    for (int r = 0; r < 4; ++r) {
      int row = quad * 4 + r;
      int n = nofs + rb * 8 + row;
      xo[((size_t)b * NNtok + n) * DIMc + h * 64 + w * 16 + m] = o[r] * rowinv[row];
    }
  }
}

// ---------------- host ----------------
extern "C" void kernel_launch(void* const* d_in, const int* in_sizes, int n_in,
                              void* d_out, int out_size, void* d_ws, size_t ws_size,
                              hipStream_t stream)
{
  const float* x       = (const float*)d_in[0];
  const float* id_tot  = (const float*)d_in[1];
  const float* mem_k   = (const float*)d_in[2];
  const float* mem_v   = (const float*)d_in[3];
  const float* W_qkv   = (const float*)d_in[4];
  const float* b_qkv   = (const float*)d_in[5];
  const float* qkv_A   = (const float*)d_in[6];
  const float* qkv_B   = (const float*)d_in[7];
  const float* W_proj  = (const float*)d_in[8];
  const float* b_proj  = (const float*)d_in[9];
  const float* route_W = (const float*)d_in[10];
  const float* proj_A  = (const float*)d_in[11];
  const float* proj_B  = (const float*)d_in[12];
  const float* W_idk   = (const float*)d_in[13];
  const float* b_idk   = (const float*)d_in[14];
  const float* idk_A   = (const float*)d_in[15];
  const float* idk_B   = (const float*)d_in[16];
  const float* W_idv   = (const float*)d_in[17];
  const float* b_idv   = (const float*)d_in[18];
  const float* idv_A   = (const float*)d_in[19];
  const float* idv_B   = (const float*)d_in[20];

  float* ws   = (float*)d_ws;
  float* vb   = ws + OVb;
  float* xo   = ws + OXO;
  float* qlow = ws + OQL;
  float* IDK  = ws + OIDK;
  float* IDV  = ws + OIDV;
  float* lowk = ws + OLK;
  float* lowv = ws + OLV;
  float* rd   = ws + ORD;
  float* plow = ws + OPL;
  unsigned short* qh   = (unsigned short*)(ws + OQH);
  unsigned short* kfh  = (unsigned short*)(ws + OKFH);
  unsigned short* vth  = (unsigned short*)(ws + OVTH);
  unsigned short* kmh  = (unsigned short*)(ws + OKMH);
  unsigned short* vmth = (unsigned short*)(ws + OVMTH);
  unsigned short* Aa   = (unsigned short*)(ws + OAa);
  unsigned short* Wa   = (unsigned short*)(ws + OWa);
  unsigned short* Wa2  = (unsigned short*)(ws + OWa2);

  float* out  = (float*)d_out;
  float* kmid = out + KMID_OFF;
  float* vmid = out + VMID_OFF;

  // staging: mem_k cast, mem_v transpose, both W_aug builds — one launch
  prep<<<7680, 256, 0, stream>>>(mem_k, mem_v, W_qkv, qkv_B, W_proj, proj_B,
                                 kfh, vth, Wa, Wa2);

  // LoRA downs
  dot_small<<<1280, 256, 0, stream>>>(x, qkv_A, qlow, 24);
  dot_id<<<256, 256, 0, stream>>>(id_tot, idk_A, idv_A, lowk, lowv);

  // QKV via MFMA with augmented K (fused LoRA)
  cast_pack<<<2000, 256, 0, stream>>>(x, qlow, Aa, 24);
  gemm_mfma<<<dim3(18, 40), 256, 0, stream>>>(Aa, Wa, b_qkv, 0, nullptr,
                                              qh, kmid, vb, kfh);
  // ID_V (fp32), ID_K
  gemm_idv<<<dim3(12, 16), 256, 0, stream>>>(id_tot, W_idv, b_idv, lowv, idv_B, IDV);
  idk_kernel<<<256, 256, 0, stream>>>(id_tot, W_idk, b_idk, lowk, idk_B, IDK);
  // outputs k_m_id / v_m_id; vb rows 0-255 updated in place
  fixup_kernel<<<3072, 256, 0, stream>>>(vb, IDK, IDV, kmid, vmid, kmh);

  // V^T bf16 staging (post-fixup)
  transpose_post<<<1152, 256, 0, stream>>>(vb, vth, vmth);

  // attention: 8 rows/block (XCD-swizzled: blockIdx = rb*48 + bh)
  attn_mfma5<256><<<1536, 256, 0, stream>>>(qh, kmh, vmth, 128, 0, xo, 0);
  attn_mfma5<2560><<<6144, 256, 0, stream>>>(qh, kfh, vth, 640, 256, xo, 256);

  // routed output projection
  dot_rp<<<1280, 256, 0, stream>>>(xo, route_W, proj_A, rd, plow);
  cast_pack_proj<<<2000, 256, 0, stream>>>(xo, rd, plow, Aa);
  gemm_mfma<<<dim3(6, 40), 256, 0, stream>>>(Aa, Wa2, b_proj, 2, out,
                                             nullptr, nullptr, nullptr, nullptr);
}